// Round 9
// baseline (690.800 us; speedup 1.0000x reference)
//
#include <hip/hip_runtime.h>
#include <hip/hip_bf16.h>
#include <float.h>

#define B_ 4
#define N_ 1024
#define H_ 16
#define DH_ 64
#define NM_ 4
#define J_ 1028          // N_ + NM_
#define KR_ 1056         // padded kn/vc rows
#define IT_ 2            // i rows per attention block
#define JST 1064         // sd row stride (halves)
#define TOPK_ 64
#define QKSCALE 10.0f

typedef __attribute__((ext_vector_type(8))) short short8;
typedef __attribute__((ext_vector_type(4))) float f32x4;
typedef __attribute__((ext_vector_type(8))) unsigned short ushort8;
typedef __attribute__((ext_vector_type(4))) unsigned int u32x4;
typedef _Float16 half8 __attribute__((ext_vector_type(8)));

__device__ __forceinline__ unsigned short f2b(float f){
  union { float f; unsigned int i; } c; c.f = f;
  unsigned int r = c.i + 0x7FFFu + ((c.i >> 16) & 1u);   // RNE
  return (unsigned short)(r >> 16);
}
__device__ __forceinline__ unsigned short f2h(float f){
  return __builtin_bit_cast(unsigned short, (_Float16)f);
}
__device__ __forceinline__ float h2f(unsigned short u){
  return (float)__builtin_bit_cast(_Float16, u);
}
// order-preserving u16 key <-> f16 bits
__device__ __forceinline__ unsigned int h2key(unsigned int u){
  return (u & 0x8000u) ? (~u & 0xFFFFu) : (u | 0x8000u);
}
__device__ __forceinline__ float key2f(unsigned int k){
  unsigned int u = (k & 0x8000u) ? (k & 0x7FFFu) : (~k & 0xFFFFu);
  return h2f((unsigned short)u);
}

// ---------------- fused f32 -> bf16 convert: x + 5 weights in one launch ----------------
__global__ void k_cvtAll(const float* __restrict__ x,  const float* __restrict__ wq,
                         const float* __restrict__ wk, const float* __restrict__ wv,
                         const float* __restrict__ wg, const float* __restrict__ wo,
                         unsigned short* __restrict__ xb,  unsigned short* __restrict__ wqb,
                         unsigned short* __restrict__ wkb, unsigned short* __restrict__ wvb,
                         unsigned short* __restrict__ wgb, unsigned short* __restrict__ wob){
  const int NX = 4096 * 1024, NW = 1024 * 1024;
  int i = blockIdx.x * 256 + threadIdx.x;
  int st = gridDim.x * 256;
  for (; i < NX + 5 * NW; i += st){
    if (i < NX){ xb[i] = f2b(x[i]); }
    else {
      int k = i - NX;
      int which = k >> 20, off = k & (NW - 1);
      const float* s = which == 0 ? wq : which == 1 ? wk : which == 2 ? wv : which == 3 ? wg : wo;
      unsigned short* d = which == 0 ? wqb : which == 1 ? wkb : which == 2 ? wvb : which == 3 ? wgb : wob;
      d[off] = f2b(s[off]);
    }
  }
}

// ---------------- memory-slot prep + zero padding rows ----------------
__global__ __launch_bounds__(256) void k_mem(const float* __restrict__ mk, const float* __restrict__ mv,
                                             unsigned short* __restrict__ kn, unsigned short* __restrict__ vc){
  int h = blockIdx.x * 4 + (threadIdx.x >> 6);   // 0..15
  int d = threadIdx.x & 63;
  unsigned short kh[4], vh[4];
  #pragma unroll
  for (int mm = 0; mm < 4; ++mm){
    float kv = mk[(h * 4 + mm) * 64 + d];
    float ss = kv * kv;
    #pragma unroll
    for (int off = 32; off; off >>= 1) ss += __shfl_xor(ss, off);
    kh[mm] = f2h(kv / fmaxf(sqrtf(ss), 1e-12f));
    vh[mm] = f2h(mv[(h * 4 + mm) * 64 + d]);
  }
  for (int b = 0; b < B_; ++b){
    int bg = b * 16 + h;
    #pragma unroll
    for (int mm = 0; mm < 4; ++mm){
      kn[((size_t)bg * KR_ + mm) * 64 + d] = kh[mm];
      vc[((size_t)bg * KR_ + mm) * 64 + d] = vh[mm];
    }
    for (int rr = J_; rr < KR_; ++rr){       // zero padding rows
      kn[((size_t)bg * KR_ + rr) * 64 + d] = 0;
      vc[((size_t)bg * KR_ + rr) * 64 + d] = 0;
    }
  }
}

// ---------------- V transpose: vc [bg][j][64] f16 -> vt [bg][64][1056] f16 ----------------
__global__ __launch_bounds__(256) void k_trv(const unsigned short* __restrict__ vc,
                                             unsigned short* __restrict__ vt){
  __shared__ unsigned short tile[32][72];
  const int jb = blockIdx.x;           // 0..32
  const int bg = blockIdx.y;           // 0..63
  const int t = threadIdx.x;
  {
    int r = t >> 3, d8 = (t & 7) * 8;
    ushort8 v = *(const ushort8*)(vc + ((size_t)bg * KR_ + jb * 32 + r) * 64 + d8);
    #pragma unroll
    for (int e = 0; e < 8; ++e) tile[r][d8 + e] = v[e];
  }
  __syncthreads();
  {
    int d = t >> 2, j8 = (t & 3) * 8;
    ushort8 w;
    #pragma unroll
    for (int e = 0; e < 8; ++e) w[e] = tile[j8 + e][d];
    *(ushort8*)(vt + ((size_t)bg * 64 + d) * 1056 + jb * 32 + j8) = w;
  }
}

// ---------------- bf16 MFMA GEMM 4096x1024x1024, 128x64 tile, 4 waves ----------------
// MODE 0: v -> vc f16 [bg][KR_][64] ; MODE 1: q -> qn f16 (l2norm*QKSCALE)
// MODE 2: k -> kn f16 (l2norm, KR_) ; MODE 3: gate -> sigmoid f16 ; MODE 4: f32 out
template<int MODE>
__global__ __launch_bounds__(256) void k_gemm(const unsigned short* __restrict__ A,
                                              const unsigned short* __restrict__ W,
                                              void* __restrict__ outp,
                                              const float* __restrict__ bg)
{
  __shared__ unsigned short As[128][40];
  __shared__ unsigned short Bs[64][40];
  const int t = threadIdx.x;
  const int m0 = blockIdx.y * 128, n0 = blockIdx.x * 64;
  const int l = t & 63, w = t >> 6;
  const int l15 = l & 15, l4 = l >> 4;

  f32x4 acc[2][4];
  #pragma unroll
  for (int a = 0; a < 2; ++a)
    #pragma unroll
    for (int b2 = 0; b2 < 4; ++b2) acc[a][b2] = (f32x4){0.f, 0.f, 0.f, 0.f};

  for (int k0 = 0; k0 < 1024; k0 += 32){
    #pragma unroll
    for (int cc = 0; cc < 2; ++cc){          // A tile: 128x32
      int c = t + cc * 256;
      int row = c >> 2, colc = (c & 3) * 8;
      *(ushort8*)&As[row][colc] = *(const ushort8*)&A[(m0 + row) * 1024 + k0 + colc];
    }
    {                                        // B tile: 32k x 64n
      int kk = t >> 3, nc = (t & 7) * 8;
      ushort8 vb = *(const ushort8*)&W[(k0 + kk) * 1024 + n0 + nc];
      #pragma unroll
      for (int e = 0; e < 8; ++e) Bs[nc + e][kk] = vb[e];
    }
    __syncthreads();
    short8 af[2], bfr[4];
    #pragma unroll
    for (int mf = 0; mf < 2; ++mf) af[mf]  = *(const short8*)&As[w * 32 + mf * 16 + l15][l4 * 8];
    #pragma unroll
    for (int nf = 0; nf < 4; ++nf) bfr[nf] = *(const short8*)&Bs[nf * 16 + l15][l4 * 8];
    #pragma unroll
    for (int mf = 0; mf < 2; ++mf)
      #pragma unroll
      for (int nf = 0; nf < 4; ++nf)
        acc[mf][nf] = __builtin_amdgcn_mfma_f32_16x16x32_bf16(af[mf], bfr[nf], acc[mf][nf], 0, 0, 0);
    __syncthreads();
  }

  const int hcol = n0 >> 6;
  #pragma unroll
  for (int mf = 0; mf < 2; ++mf){
    #pragma unroll
    for (int r = 0; r < 4; ++r){
      int row = m0 + w * 32 + mf * 16 + l4 * 4 + r;
      float rn = 1.f;
      if (MODE == 1 || MODE == 2){
        float ss = 0.f;
        #pragma unroll
        for (int nf = 0; nf < 4; ++nf) ss += acc[mf][nf][r] * acc[mf][nf][r];
        #pragma unroll
        for (int off = 1; off < 16; off <<= 1) ss += __shfl_xor(ss, off);
        rn = 1.f / fmaxf(sqrtf(ss), 1e-12f);
        if (MODE == 1) rn *= QKSCALE;
      }
      #pragma unroll
      for (int nf = 0; nf < 4; ++nf){
        int col = n0 + nf * 16 + l15;
        float v = acc[mf][nf][r];
        if (MODE == 4){
          ((float*)outp)[row * 1024 + col] = v;
        } else if (MODE == 3){
          float g = v + bg[col];
          ((unsigned short*)outp)[row * 1024 + col] = f2h(1.f / (1.f + __expf(-g)));
        } else {
          int bb = row >> 10, ii = row & 1023;
          int d = nf * 16 + l15;
          if (MODE == 1)
            ((unsigned short*)outp)[((bb * H_ + hcol) * N_ + ii) * DH_ + d] = f2h(v * rn);
          else // MODE 0 (rn=1) and MODE 2: padded KR_ layout
            ((unsigned short*)outp)[((size_t)(bb * H_ + hcol) * KR_ + NM_ + ii) * DH_ + d] = f2h(v * rn);
        }
      }
    }
  }
}

// ---------------- fused attention, all-MFMA: 512 thr (8 waves) per (b, 2-i tile) ----------------
// 2 blocks/CU (LDS ~70KB) -> cross-block phase overlap. XCD-swizzled: b fixed per XCD.
__global__ __launch_bounds__(512, 4) void k_attnM(
  const unsigned short* __restrict__ qn, const unsigned short* __restrict__ kn,
  const unsigned short* __restrict__ vt, const float* __restrict__ wpre,
  const float* __restrict__ wpost, const float* __restrict__ hsc,
  const unsigned short* __restrict__ gate, unsigned short* __restrict__ aout)
{
  __shared__ unsigned short sd[16 * IT_ * JST];  // [head][i][j] f16: raw -> premixed -> attn
  __shared__ unsigned short wpre16[16 * 32];     // Wpre f16, zero-padded K=32
  __shared__ unsigned short wpost16[16 * 32];    // Wpost f16, zero-padded K=32

  const int blk = blockIdx.x;
  const int b = (blk >> 1) & 3;                  // fixed per XCD pair (blk%8 -> XCD)
  const int idx = ((blk >> 3) << 1) | (blk & 1); // 0..511, ascending within XCD
  const int it = 511 - idx;                      // big tiles first
  const int i0 = it * IT_;
  const int nAmax = i0 + IT_ + 4;                // max per-row nA
  const int nJtA = (nAmax + 15) >> 4;            // 16-tiles for dots/premix
  const int nJtE = (nAmax + 31) >> 5;            // 32-tiles for PV
  const int nJtD = nJtE * 2;                     // 16-tiles for postmix (covers E's reach)
  const int t = threadIdx.x;
  const int w = t >> 6, l = t & 63;
  const int l15 = l & 15, l4 = l >> 4;

  if (t < 256){
    int h = t >> 4, g = t & 15;
    wpre16[h * 32 + g]       = f2h(wpre[h * 16 + g]);
    wpre16[h * 32 + 16 + g]  = 0;
    wpost16[h * 32 + g]      = f2h(wpost[h * 16 + g]);
    wpost16[h * 32 + 16 + g] = 0;
  }
  __syncthreads();

  // ---- phase A: raw dots via MFMA; F1 = K rows (j), F2 = q rows (i, dup) ----
  for (int g = 0; g < 16; ++g){
    const int bg = b * 16 + g;
    const unsigned short* qb = qn + ((size_t)bg * N_ + i0 + (l15 & 1)) * 64 + l4 * 8;
    half8 qf0 = *(const half8*)(qb);
    half8 qf1 = *(const half8*)(qb + 32);
    const unsigned short* kb0 = kn + (size_t)bg * KR_ * 64 + (size_t)l15 * 64 + l4 * 8;
    for (int jt = w; jt < nJtA; jt += 8){
      const unsigned short* kb = kb0 + (size_t)jt * 16 * 64;
      half8 kf0 = *(const half8*)(kb);
      half8 kf1 = *(const half8*)(kb + 32);
      f32x4 acc = (f32x4){0.f, 0.f, 0.f, 0.f};
      acc = __builtin_amdgcn_mfma_f32_16x16x32_f16(kf0, qf0, acc, 0, 0, 0);
      acc = __builtin_amdgcn_mfma_f32_16x16x32_f16(kf1, qf1, acc, 0, 0, 0);
      if (l15 < IT_){
        // D: row (j-off) = l4*4+r, col (i) = l15
        unsigned int p0 = (unsigned int)f2h(acc[0]) | ((unsigned int)f2h(acc[1]) << 16);
        unsigned int p1 = (unsigned int)f2h(acc[2]) | ((unsigned int)f2h(acc[3]) << 16);
        unsigned int* dst = (unsigned int*)&sd[(g * IT_ + l15) * JST + jt * 16 + l4 * 4];
        dst[0] = p0; dst[1] = p1;
      }
    }
  }
  __syncthreads();

  // ---- phase B: W_pre premix via MFMA, in-place per (ii, jt16) patch ----
  {
    half8 wa = *(const half8*)&wpre16[l15 * 32 + l4 * 8];   // F1 row = h, k = g (0 for k>=16)
    const int ntask = IT_ * nJtA;
    for (int task = w; task < ntask; task += 8){
      const int ii = task & (IT_ - 1), jt = task >> 1;
      unsigned int fb[4] = {0u, 0u, 0u, 0u};
      if (l4 < 2){
        const unsigned short* src = &sd[((l4 * 8) * IT_ + ii) * JST + jt * 16 + l15];
        #pragma unroll
        for (int e = 0; e < 8; e += 2){
          unsigned int lo = src[(size_t)(e)     * IT_ * JST];
          unsigned int hi = src[(size_t)(e + 1) * IT_ * JST];
          fb[e >> 1] = (lo & 0xFFFFu) | (hi << 16);
        }
      }
      f32x4 acc = (f32x4){0.f, 0.f, 0.f, 0.f};
      acc = __builtin_amdgcn_mfma_f32_16x16x32_f16(wa, __builtin_bit_cast(half8, *(u32x4*)fb), acc, 0, 0, 0);
      #pragma unroll
      for (int r = 0; r < 4; ++r)
        sd[((l4 * 4 + r) * IT_ + ii) * JST + jt * 16 + l15] = f2h(acc[r]);
    }
  }
  __syncthreads();

  // ---- phase C: per-row top-64 threshold + softmax (normalized write) ----
  for (int rr = 0; rr < 4; ++rr){
    const int row = w * 4 + rr;            // 0..31
    const int g = row >> 1, ii = row & 1;
    const int nA = i0 + ii + 5;
    unsigned short* rowp = &sd[(g * IT_ + ii) * JST];
    unsigned int kw[9];
    #pragma unroll
    for (int grp = 0; grp < 9; ++grp){
      int j = grp * 128 + l * 2;
      unsigned int u = (j < JST) ? *(const unsigned int*)(rowp + j) : 0u;
      unsigned int klo = h2key(u & 0xFFFFu);
      unsigned int khi = h2key(u >> 16);
      if (j     >= nA) klo = 0u;
      if (j + 1 >= nA) khi = 0u;
      kw[grp] = klo | (khi << 16);
    }
    unsigned int kmx = 0u;
    #pragma unroll
    for (int grp = 0; grp < 9; ++grp){
      unsigned int m2 = max(kw[grp] >> 16, kw[grp] & 0xFFFFu);
      kmx = max(kmx, m2);
    }
    #pragma unroll
    for (int off = 32; off; off >>= 1) kmx = max(kmx, (unsigned int)__shfl_xor((int)kmx, off));
    const float mx = key2f(kmx);

    unsigned int T = 0u;
    if (nA > TOPK_){
      for (int bit = 15; bit >= 2; --bit){
        unsigned int Tc = T | (1u << bit);
        int c = 0;
        #pragma unroll
        for (int grp = 0; grp < 9; ++grp){
          c += __popcll(__ballot((kw[grp] & 0xFFFFu) >= Tc));
          c += __popcll(__ballot((kw[grp] >> 16) >= Tc));
        }
        if (c >= TOPK_){
          T = Tc;
          if (c == TOPK_) break;
        }
      }
    }
    if (T == 0u) T = 1u;     // excludes masked (key 0)

    float s = 0.f;
    float ev[18];
    #pragma unroll
    for (int grp = 0; grp < 9; ++grp){
      unsigned int klo = kw[grp] & 0xFFFFu, khi = kw[grp] >> 16;
      float elo = (klo >= T) ? __expf(key2f(klo) - mx) : 0.f;
      float ehi = (khi >= T) ? __expf(key2f(khi) - mx) : 0.f;
      ev[grp * 2] = elo; ev[grp * 2 + 1] = ehi;
      s += elo + ehi;
    }
    #pragma unroll
    for (int off = 32; off; off >>= 1) s += __shfl_xor(s, off);
    float inv = 1.f / s;
    #pragma unroll
    for (int grp = 0; grp < 9; ++grp){
      int j = grp * 128 + l * 2;
      if (j < JST)
        *(unsigned int*)(rowp + j) =
          (unsigned int)f2h(ev[grp * 2] * inv) | ((unsigned int)f2h(ev[grp * 2 + 1] * inv) << 16);
    }
  }
  __syncthreads();

  // ---- phase D: postmix via MFMA (causal-trimmed; zero cols stay zero) ----
  {
    const int ntask = IT_ * nJtD;
    for (int task = w; task < ntask; task += 8){
      const int ii = task & (IT_ - 1), jt = task >> 1;
      half8 wa = *(const half8*)&wpost16[l15 * 32 + l4 * 8];
      unsigned int fb[4] = {0u, 0u, 0u, 0u};
      if (l4 < 2){
        const unsigned short* src = &sd[((l4 * 8) * IT_ + ii) * JST + jt * 16 + l15];
        #pragma unroll
        for (int e = 0; e < 8; e += 2){
          unsigned int lo = src[(size_t)(e)     * IT_ * JST];
          unsigned int hi = src[(size_t)(e + 1) * IT_ * JST];
          fb[e >> 1] = (lo & 0xFFFFu) | (hi << 16);
        }
      }
      f32x4 acc = (f32x4){0.f, 0.f, 0.f, 0.f};
      acc = __builtin_amdgcn_mfma_f32_16x16x32_f16(wa, __builtin_bit_cast(half8, *(u32x4*)fb), acc, 0, 0, 0);
      #pragma unroll
      for (int r = 0; r < 4; ++r)
        sd[((l4 * 4 + r) * IT_ + ii) * JST + jt * 16 + l15] = f2h(acc[r]);
    }
  }
  __syncthreads();

  // ---- phase E: PV via MFMA over j (causal-trimmed); F1 = a_post rows (i, dup), F2 = V^T rows (d) ----
  for (int task = w; task < 64; task += 8){
    const int h = task >> 2, dc = task & 3;
    const int bg = b * 16 + h;
    const unsigned short* vrow = vt + ((size_t)bg * 64 + dc * 16 + l15) * 1056 + l4 * 8;
    const unsigned short* arow = &sd[(h * IT_ + (l15 & 1)) * JST + l4 * 8];
    f32x4 acc = (f32x4){0.f, 0.f, 0.f, 0.f};
    for (int jt = 0; jt < nJtE; ++jt){
      half8 af = *(const half8*)(arow + jt * 32);
      half8 vf = *(const half8*)(vrow + jt * 32);
      acc = __builtin_amdgcn_mfma_f32_16x16x32_f16(af, vf, acc, 0, 0, 0);
    }
    if (l4 == 0){
      const float hs = hsc[h];
      #pragma unroll
      for (int r = 0; r < IT_; ++r){
        const int irow = (b << 10) | (i0 + r);
        const size_t o = (size_t)irow * 1024 + h * 64 + dc * 16 + l15;
        aout[o] = f2b(acc[r] * hs * h2f(gate[o]));
      }
    }
  }
}

// ---------------- host ----------------
extern "C" void kernel_launch(void* const* d_in, const int* in_sizes, int n_in,
                              void* d_out, int out_size, void* d_ws, size_t ws_size,
                              hipStream_t stream) {
  const float* x     = (const float*)d_in[0];
  const float* Wq    = (const float*)d_in[1];
  const float* Wk    = (const float*)d_in[2];
  const float* Wv    = (const float*)d_in[3];
  const float* Wpre  = (const float*)d_in[4];
  const float* Wpost = (const float*)d_in[5];
  const float* mk    = (const float*)d_in[6];
  const float* mv    = (const float*)d_in[7];
  const float* hsc   = (const float*)d_in[8];
  const float* Wg    = (const float*)d_in[9];
  const float* bg    = (const float*)d_in[10];
  const float* Wo    = (const float*)d_in[11];
  float* out = (float*)d_out;

  char* ws = (char*)d_ws;
  size_t off = 0;
  auto alloc = [&](size_t bytes) -> void* {
    void* p = ws + off; off += (bytes + 255) & ~(size_t)255; return p;
  };
  unsigned short* xb   = (unsigned short*)alloc((size_t)4096 * 1024 * 2);
  unsigned short* wqb  = (unsigned short*)alloc((size_t)1024 * 1024 * 2);
  unsigned short* wkb  = (unsigned short*)alloc((size_t)1024 * 1024 * 2);
  unsigned short* wvb  = (unsigned short*)alloc((size_t)1024 * 1024 * 2);
  unsigned short* wgb  = (unsigned short*)alloc((size_t)1024 * 1024 * 2);
  unsigned short* wob  = (unsigned short*)alloc((size_t)1024 * 1024 * 2);
  unsigned short* qn   = (unsigned short*)alloc((size_t)B_ * H_ * N_ * DH_ * 2);   // f16
  unsigned short* kn   = (unsigned short*)alloc((size_t)B_ * H_ * KR_ * DH_ * 2);  // f16 padded
  unsigned short* vc   = (unsigned short*)alloc((size_t)B_ * H_ * KR_ * DH_ * 2);  // f16 padded
  unsigned short* vt   = (unsigned short*)alloc((size_t)B_ * H_ * DH_ * 1056 * 2); // f16 V^T
  unsigned short* gate = (unsigned short*)alloc((size_t)4096 * 1024 * 2);          // f16
  unsigned short* aout = (unsigned short*)alloc((size_t)4096 * 1024 * 2);          // bf16

  k_cvtAll<<<2048, 256, 0, stream>>>(x, Wq, Wk, Wv, Wg, Wo, xb, wqb, wkb, wvb, wgb, wob);

  k_mem<<<4, 256, 0, stream>>>(mk, mv, kn, vc);

  dim3 gg(16, 32);
  k_gemm<0><<<gg, 256, 0, stream>>>(xb, wvb, vc,   nullptr);
  k_gemm<1><<<gg, 256, 0, stream>>>(xb, wqb, qn,   nullptr);
  k_gemm<2><<<gg, 256, 0, stream>>>(xb, wkb, kn,   nullptr);
  k_gemm<3><<<gg, 256, 0, stream>>>(xb, wgb, gate, bg);

  k_trv<<<dim3(33, B_ * H_), 256, 0, stream>>>(vc, vt);

  k_attnM<<<2048, 512, 0, stream>>>(qn, kn, vt, Wpre, Wpost, hsc, gate, aout);

  k_gemm<4><<<gg, 256, 0, stream>>>(aout, wob, out, nullptr);
}

// Round 10
// 583.363 us; speedup vs baseline: 1.1842x; 1.1842x over previous
//
#include <hip/hip_runtime.h>
#include <hip/hip_bf16.h>
#include <float.h>

#define B_ 4
#define N_ 1024
#define H_ 16
#define DH_ 64
#define NM_ 4
#define J_ 1028          // N_ + NM_
#define KR_ 1056         // padded kn/vc rows
#define IT_ 4            // i rows per attention block
#define JST 1064         // sd row stride (halves); 4-row stride != 0 mod 32 banks
#define TOPK_ 64
#define QKSCALE 10.0f

typedef __attribute__((ext_vector_type(8))) short short8;
typedef __attribute__((ext_vector_type(4))) float f32x4;
typedef __attribute__((ext_vector_type(8))) unsigned short ushort8;
typedef __attribute__((ext_vector_type(4))) unsigned int u32x4;
typedef _Float16 half8 __attribute__((ext_vector_type(8)));

__device__ __forceinline__ unsigned short f2b(float f){
  union { float f; unsigned int i; } c; c.f = f;
  unsigned int r = c.i + 0x7FFFu + ((c.i >> 16) & 1u);   // RNE
  return (unsigned short)(r >> 16);
}
__device__ __forceinline__ unsigned short f2h(float f){
  return __builtin_bit_cast(unsigned short, (_Float16)f);
}
__device__ __forceinline__ float h2f(unsigned short u){
  return (float)__builtin_bit_cast(_Float16, u);
}
// order-preserving u16 key <-> f16 bits
__device__ __forceinline__ unsigned int h2key(unsigned int u){
  return (u & 0x8000u) ? (~u & 0xFFFFu) : (u | 0x8000u);
}
__device__ __forceinline__ float key2f(unsigned int k){
  unsigned int u = (k & 0x8000u) ? (k & 0x7FFFu) : (~k & 0xFFFFu);
  return h2f((unsigned short)u);
}

// ---------------- fused f32 -> bf16 convert: x + 5 weights in one launch ----------------
__global__ void k_cvtAll(const float* __restrict__ x,  const float* __restrict__ wq,
                         const float* __restrict__ wk, const float* __restrict__ wv,
                         const float* __restrict__ wg, const float* __restrict__ wo,
                         unsigned short* __restrict__ xb,  unsigned short* __restrict__ wqb,
                         unsigned short* __restrict__ wkb, unsigned short* __restrict__ wvb,
                         unsigned short* __restrict__ wgb, unsigned short* __restrict__ wob){
  const int NX = 4096 * 1024, NW = 1024 * 1024;
  int i = blockIdx.x * 256 + threadIdx.x;
  int st = gridDim.x * 256;
  for (; i < NX + 5 * NW; i += st){
    if (i < NX){ xb[i] = f2b(x[i]); }
    else {
      int k = i - NX;
      int which = k >> 20, off = k & (NW - 1);
      const float* s = which == 0 ? wq : which == 1 ? wk : which == 2 ? wv : which == 3 ? wg : wo;
      unsigned short* d = which == 0 ? wqb : which == 1 ? wkb : which == 2 ? wvb : which == 3 ? wgb : wob;
      d[off] = f2b(s[off]);
    }
  }
}

// ---------------- memory-slot prep + zero padding rows ----------------
__global__ __launch_bounds__(256) void k_mem(const float* __restrict__ mk, const float* __restrict__ mv,
                                             unsigned short* __restrict__ kn, unsigned short* __restrict__ vc){
  int h = blockIdx.x * 4 + (threadIdx.x >> 6);   // 0..15
  int d = threadIdx.x & 63;
  unsigned short kh[4], vh[4];
  #pragma unroll
  for (int mm = 0; mm < 4; ++mm){
    float kv = mk[(h * 4 + mm) * 64 + d];
    float ss = kv * kv;
    #pragma unroll
    for (int off = 32; off; off >>= 1) ss += __shfl_xor(ss, off);
    kh[mm] = f2h(kv / fmaxf(sqrtf(ss), 1e-12f));
    vh[mm] = f2h(mv[(h * 4 + mm) * 64 + d]);
  }
  for (int b = 0; b < B_; ++b){
    int bg = b * 16 + h;
    #pragma unroll
    for (int mm = 0; mm < 4; ++mm){
      kn[((size_t)bg * KR_ + mm) * 64 + d] = kh[mm];
      vc[((size_t)bg * KR_ + mm) * 64 + d] = vh[mm];
    }
    for (int rr = J_; rr < KR_; ++rr){       // zero padding rows
      kn[((size_t)bg * KR_ + rr) * 64 + d] = 0;
      vc[((size_t)bg * KR_ + rr) * 64 + d] = 0;
    }
  }
}

// ---------------- V transpose: vc [bg][j][64] f16 -> vt [bg][64][1056] f16 ----------------
__global__ __launch_bounds__(256) void k_trv(const unsigned short* __restrict__ vc,
                                             unsigned short* __restrict__ vt){
  __shared__ unsigned short tile[32][72];
  const int jb = blockIdx.x;           // 0..32
  const int bg = blockIdx.y;           // 0..63
  const int t = threadIdx.x;
  {
    int r = t >> 3, d8 = (t & 7) * 8;
    ushort8 v = *(const ushort8*)(vc + ((size_t)bg * KR_ + jb * 32 + r) * 64 + d8);
    #pragma unroll
    for (int e = 0; e < 8; ++e) tile[r][d8 + e] = v[e];
  }
  __syncthreads();
  {
    int d = t >> 2, j8 = (t & 3) * 8;
    ushort8 w;
    #pragma unroll
    for (int e = 0; e < 8; ++e) w[e] = tile[j8 + e][d];
    *(ushort8*)(vt + ((size_t)bg * 64 + d) * 1056 + jb * 32 + j8) = w;
  }
}

// ---------------- bf16 MFMA GEMM 4096x1024x1024, 128x64 tile, 4 waves ----------------
template<int MODE>
__global__ __launch_bounds__(256) void k_gemm(const unsigned short* __restrict__ A,
                                              const unsigned short* __restrict__ W,
                                              void* __restrict__ outp,
                                              const float* __restrict__ bg)
{
  __shared__ unsigned short As[128][40];
  __shared__ unsigned short Bs[64][40];
  const int t = threadIdx.x;
  const int m0 = blockIdx.y * 128, n0 = blockIdx.x * 64;
  const int l = t & 63, w = t >> 6;
  const int l15 = l & 15, l4 = l >> 4;

  f32x4 acc[2][4];
  #pragma unroll
  for (int a = 0; a < 2; ++a)
    #pragma unroll
    for (int b2 = 0; b2 < 4; ++b2) acc[a][b2] = (f32x4){0.f, 0.f, 0.f, 0.f};

  for (int k0 = 0; k0 < 1024; k0 += 32){
    #pragma unroll
    for (int cc = 0; cc < 2; ++cc){          // A tile: 128x32
      int c = t + cc * 256;
      int row = c >> 2, colc = (c & 3) * 8;
      *(ushort8*)&As[row][colc] = *(const ushort8*)&A[(m0 + row) * 1024 + k0 + colc];
    }
    {                                        // B tile: 32k x 64n
      int kk = t >> 3, nc = (t & 7) * 8;
      ushort8 vb = *(const ushort8*)&W[(k0 + kk) * 1024 + n0 + nc];
      #pragma unroll
      for (int e = 0; e < 8; ++e) Bs[nc + e][kk] = vb[e];
    }
    __syncthreads();
    short8 af[2], bfr[4];
    #pragma unroll
    for (int mf = 0; mf < 2; ++mf) af[mf]  = *(const short8*)&As[w * 32 + mf * 16 + l15][l4 * 8];
    #pragma unroll
    for (int nf = 0; nf < 4; ++nf) bfr[nf] = *(const short8*)&Bs[nf * 16 + l15][l4 * 8];
    #pragma unroll
    for (int mf = 0; mf < 2; ++mf)
      #pragma unroll
      for (int nf = 0; nf < 4; ++nf)
        acc[mf][nf] = __builtin_amdgcn_mfma_f32_16x16x32_bf16(af[mf], bfr[nf], acc[mf][nf], 0, 0, 0);
    __syncthreads();
  }

  const int hcol = n0 >> 6;
  #pragma unroll
  for (int mf = 0; mf < 2; ++mf){
    #pragma unroll
    for (int r = 0; r < 4; ++r){
      int row = m0 + w * 32 + mf * 16 + l4 * 4 + r;
      float rn = 1.f;
      if (MODE == 1 || MODE == 2){
        float ss = 0.f;
        #pragma unroll
        for (int nf = 0; nf < 4; ++nf) ss += acc[mf][nf][r] * acc[mf][nf][r];
        #pragma unroll
        for (int off = 1; off < 16; off <<= 1) ss += __shfl_xor(ss, off);
        rn = 1.f / fmaxf(sqrtf(ss), 1e-12f);
        if (MODE == 1) rn *= QKSCALE;
      }
      #pragma unroll
      for (int nf = 0; nf < 4; ++nf){
        int col = n0 + nf * 16 + l15;
        float v = acc[mf][nf][r];
        if (MODE == 4){
          ((float*)outp)[row * 1024 + col] = v;
        } else if (MODE == 3){
          float g = v + bg[col];
          ((unsigned short*)outp)[row * 1024 + col] = f2h(1.f / (1.f + __expf(-g)));
        } else {
          int bb = row >> 10, ii = row & 1023;
          int d = nf * 16 + l15;
          if (MODE == 1)
            ((unsigned short*)outp)[((bb * H_ + hcol) * N_ + ii) * DH_ + d] = f2h(v * rn);
          else // MODE 0 (rn=1) and MODE 2: padded KR_ layout
            ((unsigned short*)outp)[((size_t)(bb * H_ + hcol) * KR_ + NM_ + ii) * DH_ + d] = f2h(v * rn);
        }
      }
    }
  }
}

// ---------------- fused attention, all-MFMA: 1024 thr (16 waves) per (b, 4-i tile) ----------------
// Phase A+B fused per wave (no barrier): wave owns its j-tiles for ALL g, premixes via
// per-wave LDS scratch + 2 accumulating MFMAs. q staged in LDS. 4 block barriers total.
__global__ __launch_bounds__(1024) void k_attnM(
  const unsigned short* __restrict__ qn, const unsigned short* __restrict__ kn,
  const unsigned short* __restrict__ vt, const float* __restrict__ wpre,
  const float* __restrict__ wpost, const float* __restrict__ hsc,
  const unsigned short* __restrict__ gate, unsigned short* __restrict__ aout)
{
  __shared__ unsigned short sd[16 * IT_ * JST]; // 136,192 B: mixed -> attn (in place)
  __shared__ unsigned short scr[16 * 4 * 16 * 8]; // 16,384 B per-wave raw scratch [w][ii][j16][g8]
  __shared__ unsigned short qls[16 * 4 * 64];   // 8,192 B staged q [g][ii][d]
  __shared__ unsigned short wpreA[16 * 8];      // wpre[h][g0..7]
  __shared__ unsigned short wpreB[16 * 8];      // wpre[h][g8..15]
  __shared__ unsigned short wpost16[16 * 32];   // wpost, zero-padded K=32

  const int blk = blockIdx.x;
  const int b = (blk >> 1) & 3;                  // fixed per XCD pair (blk%8 -> XCD)
  const int idx = ((blk >> 3) << 1) | (blk & 1); // 0..255, ascending within XCD
  const int it = 255 - idx;                      // big tiles first
  const int i0 = it * IT_;
  const int nAmax = i0 + IT_ + 4;                // max per-row nA
  const int nJtA = (nAmax + 15) >> 4;            // 16-tiles for dots/premix
  const int nJtE = (nAmax + 31) >> 5;            // 32-tiles for PV
  const int nJtD = nJtE * 2;                     // 16-tiles for postmix (covers E's reach)
  const int t = threadIdx.x;
  const int w = t >> 6, l = t & 63;
  const int l15 = l & 15, l4 = l >> 4;

  if (t < 256){
    int h = t >> 4, g = t & 15;
    wpost16[h * 32 + g]      = f2h(wpost[h * 16 + g]);
    wpost16[h * 32 + 16 + g] = 0;
    if (g < 8){
      wpreA[h * 8 + g] = f2h(wpre[h * 16 + g]);
      wpreB[h * 8 + g] = f2h(wpre[h * 16 + 8 + g]);
    }
  }
  // stage q: [g][ii][d] u32 pairs, coalesced
  for (int c = t; c < 2048; c += 1024){
    int d2 = c & 31, ii = (c >> 5) & 3, g = c >> 7;
    ((unsigned int*)qls)[c] =
      *(const unsigned int*)(qn + ((size_t)(b * 16 + g) * N_ + i0 + ii) * 64 + d2 * 2);
  }
  __syncthreads();

  // ---- phase A+B fused: per wave, jt-outer / g-inner; premix via scratch, 2 acc-MFMAs ----
  {
    half8 waA = {0,0,0,0,0,0,0,0}, waB = {0,0,0,0,0,0,0,0};
    if (l4 == 0){
      waA = *(const half8*)&wpreA[l15 * 8];
      waB = *(const half8*)&wpreB[l15 * 8];
    }
    for (int jt = w; jt < nJtA; jt += 16){
      f32x4 pacc[4];
      #pragma unroll
      for (int ii = 0; ii < 4; ++ii) pacc[ii] = (f32x4){0.f, 0.f, 0.f, 0.f};
      const unsigned short* kjt = kn + ((size_t)jt * 16 + l15) * 64 + l4 * 8;
      #pragma unroll
      for (int half = 0; half < 2; ++half){
        #pragma unroll
        for (int g8 = 0; g8 < 8; ++g8){
          const int g = half * 8 + g8;
          const unsigned short* kb = kjt + (size_t)(b * 16 + g) * KR_ * 64;
          half8 kf0 = *(const half8*)(kb);
          half8 kf1 = *(const half8*)(kb + 32);
          const unsigned short* qp = &qls[(g * 4 + (l15 & 3)) * 64 + l4 * 8];
          half8 qf0 = *(const half8*)(qp);
          half8 qf1 = *(const half8*)(qp + 32);
          f32x4 acc = (f32x4){0.f, 0.f, 0.f, 0.f};
          acc = __builtin_amdgcn_mfma_f32_16x16x32_f16(kf0, qf0, acc, 0, 0, 0);
          acc = __builtin_amdgcn_mfma_f32_16x16x32_f16(kf1, qf1, acc, 0, 0, 0);
          if (l15 < 4){
            // lane holds raw[g][j = jt*16 + l4*4 + r][i = l15]
            #pragma unroll
            for (int r = 0; r < 4; ++r)
              scr[((w * 4 + l15) * 16 + l4 * 4 + r) * 8 + g8] = f2h(acc[r]);
          }
        }
        half8 wa = half ? waB : waA;
        #pragma unroll
        for (int ii = 0; ii < 4; ++ii){
          u32x4 fbv = (u32x4){0u, 0u, 0u, 0u};
          if (l4 == 0){
            const unsigned short* sp = &scr[((w * 4 + ii) * 16 + l15) * 8];
            fbv[0] = *(const unsigned int*)(sp + 0);
            fbv[1] = *(const unsigned int*)(sp + 2);
            fbv[2] = *(const unsigned int*)(sp + 4);
            fbv[3] = *(const unsigned int*)(sp + 6);
          }
          pacc[ii] = __builtin_amdgcn_mfma_f32_16x16x32_f16(
              wa, __builtin_bit_cast(half8, fbv), pacc[ii], 0, 0, 0);
        }
      }
      // write mixed[h = l4*4+r][ii][j = jt*16 + l15]
      #pragma unroll
      for (int ii = 0; ii < 4; ++ii)
        #pragma unroll
        for (int r = 0; r < 4; ++r)
          sd[((l4 * 4 + r) * IT_ + ii) * JST + jt * 16 + l15] = f2h(pacc[ii][r]);
    }
  }
  __syncthreads();

  // ---- phase C: per-row top-64 threshold + softmax (normalized write) ----
  for (int rr = 0; rr < 4; ++rr){
    const int row = w * 4 + rr;            // 0..63
    const int g = row >> 2, ii = row & 3;
    const int nA = i0 + ii + 5;
    unsigned short* rowp = &sd[(g * IT_ + ii) * JST];
    unsigned int kw[9];
    #pragma unroll
    for (int grp = 0; grp < 9; ++grp){
      int j = grp * 128 + l * 2;
      unsigned int u = (j < JST) ? *(const unsigned int*)(rowp + j) : 0u;
      unsigned int klo = h2key(u & 0xFFFFu);
      unsigned int khi = h2key(u >> 16);
      if (j     >= nA) klo = 0u;
      if (j + 1 >= nA) khi = 0u;
      kw[grp] = klo | (khi << 16);
    }
    unsigned int kmx = 0u;
    #pragma unroll
    for (int grp = 0; grp < 9; ++grp){
      unsigned int m2 = max(kw[grp] >> 16, kw[grp] & 0xFFFFu);
      kmx = max(kmx, m2);
    }
    #pragma unroll
    for (int off = 32; off; off >>= 1) kmx = max(kmx, (unsigned int)__shfl_xor((int)kmx, off));
    const float mx = key2f(kmx);

    unsigned int T = 0u;
    if (nA > TOPK_){
      for (int bit = 15; bit >= 2; --bit){
        unsigned int Tc = T | (1u << bit);
        int c = 0;
        #pragma unroll
        for (int grp = 0; grp < 9; ++grp){
          c += __popcll(__ballot((kw[grp] & 0xFFFFu) >= Tc));
          c += __popcll(__ballot((kw[grp] >> 16) >= Tc));
        }
        if (c >= TOPK_){
          T = Tc;
          if (c == TOPK_) break;
        }
      }
    }
    if (T == 0u) T = 1u;     // excludes masked (key 0)

    float s = 0.f;
    float ev[18];
    #pragma unroll
    for (int grp = 0; grp < 9; ++grp){
      unsigned int klo = kw[grp] & 0xFFFFu, khi = kw[grp] >> 16;
      float elo = (klo >= T) ? __expf(key2f(klo) - mx) : 0.f;
      float ehi = (khi >= T) ? __expf(key2f(khi) - mx) : 0.f;
      ev[grp * 2] = elo; ev[grp * 2 + 1] = ehi;
      s += elo + ehi;
    }
    #pragma unroll
    for (int off = 32; off; off >>= 1) s += __shfl_xor(s, off);
    float inv = 1.f / s;
    #pragma unroll
    for (int grp = 0; grp < 9; ++grp){
      int j = grp * 128 + l * 2;
      if (j < JST)
        *(unsigned int*)(rowp + j) =
          (unsigned int)f2h(ev[grp * 2] * inv) | ((unsigned int)f2h(ev[grp * 2 + 1] * inv) << 16);
    }
  }
  __syncthreads();

  // ---- phase D: postmix via MFMA (causal-trimmed; zero cols stay zero) ----
  {
    const int ntask = IT_ * nJtD;
    for (int task = w; task < ntask; task += 16){
      const int ii = task & (IT_ - 1), jt = task >> 2;
      half8 wa = *(const half8*)&wpost16[l15 * 32 + l4 * 8];
      unsigned int fb[4] = {0u, 0u, 0u, 0u};
      if (l4 < 2){
        const unsigned short* src = &sd[((l4 * 8) * IT_ + ii) * JST + jt * 16 + l15];
        #pragma unroll
        for (int e = 0; e < 8; e += 2){
          unsigned int lo = src[(size_t)(e)     * IT_ * JST];
          unsigned int hi = src[(size_t)(e + 1) * IT_ * JST];
          fb[e >> 1] = (lo & 0xFFFFu) | (hi << 16);
        }
      }
      f32x4 acc = (f32x4){0.f, 0.f, 0.f, 0.f};
      acc = __builtin_amdgcn_mfma_f32_16x16x32_f16(wa, __builtin_bit_cast(half8, *(u32x4*)fb), acc, 0, 0, 0);
      #pragma unroll
      for (int r = 0; r < 4; ++r)
        sd[((l4 * 4 + r) * IT_ + ii) * JST + jt * 16 + l15] = f2h(acc[r]);
    }
  }
  __syncthreads();

  // ---- phase E: PV via MFMA over j (causal-trimmed); F1 = a_post rows (i, dup), F2 = V^T rows (d) ----
  for (int task = w; task < 64; task += 16){
    const int h = task >> 2, dc = task & 3;
    const int bg = b * 16 + h;
    const unsigned short* vrow = vt + ((size_t)bg * 64 + dc * 16 + l15) * 1056 + l4 * 8;
    const unsigned short* arow = &sd[(h * IT_ + (l15 & 3)) * JST + l4 * 8];
    f32x4 acc = (f32x4){0.f, 0.f, 0.f, 0.f};
    for (int jt = 0; jt < nJtE; ++jt){
      half8 af = *(const half8*)(arow + jt * 32);
      half8 vf = *(const half8*)(vrow + jt * 32);
      acc = __builtin_amdgcn_mfma_f32_16x16x32_f16(af, vf, acc, 0, 0, 0);
    }
    if (l4 == 0){
      const float hs = hsc[h];
      #pragma unroll
      for (int r = 0; r < IT_; ++r){
        const int irow = (b << 10) | (i0 + r);
        const size_t o = (size_t)irow * 1024 + h * 64 + dc * 16 + l15;
        aout[o] = f2b(acc[r] * hs * h2f(gate[o]));
      }
    }
  }
}

// ---------------- host ----------------
extern "C" void kernel_launch(void* const* d_in, const int* in_sizes, int n_in,
                              void* d_out, int out_size, void* d_ws, size_t ws_size,
                              hipStream_t stream) {
  const float* x     = (const float*)d_in[0];
  const float* Wq    = (const float*)d_in[1];
  const float* Wk    = (const float*)d_in[2];
  const float* Wv    = (const float*)d_in[3];
  const float* Wpre  = (const float*)d_in[4];
  const float* Wpost = (const float*)d_in[5];
  const float* mk    = (const float*)d_in[6];
  const float* mv    = (const float*)d_in[7];
  const float* hsc   = (const float*)d_in[8];
  const float* Wg    = (const float*)d_in[9];
  const float* bg    = (const float*)d_in[10];
  const float* Wo    = (const float*)d_in[11];
  float* out = (float*)d_out;

  char* ws = (char*)d_ws;
  size_t off = 0;
  auto alloc = [&](size_t bytes) -> void* {
    void* p = ws + off; off += (bytes + 255) & ~(size_t)255; return p;
  };
  unsigned short* xb   = (unsigned short*)alloc((size_t)4096 * 1024 * 2);
  unsigned short* wqb  = (unsigned short*)alloc((size_t)1024 * 1024 * 2);
  unsigned short* wkb  = (unsigned short*)alloc((size_t)1024 * 1024 * 2);
  unsigned short* wvb  = (unsigned short*)alloc((size_t)1024 * 1024 * 2);
  unsigned short* wgb  = (unsigned short*)alloc((size_t)1024 * 1024 * 2);
  unsigned short* wob  = (unsigned short*)alloc((size_t)1024 * 1024 * 2);
  unsigned short* qn   = (unsigned short*)alloc((size_t)B_ * H_ * N_ * DH_ * 2);   // f16
  unsigned short* kn   = (unsigned short*)alloc((size_t)B_ * H_ * KR_ * DH_ * 2);  // f16 padded
  unsigned short* vc   = (unsigned short*)alloc((size_t)B_ * H_ * KR_ * DH_ * 2);  // f16 padded
  unsigned short* vt   = (unsigned short*)alloc((size_t)B_ * H_ * DH_ * 1056 * 2); // f16 V^T
  unsigned short* gate = (unsigned short*)alloc((size_t)4096 * 1024 * 2);          // f16
  unsigned short* aout = (unsigned short*)alloc((size_t)4096 * 1024 * 2);          // bf16

  k_cvtAll<<<2048, 256, 0, stream>>>(x, Wq, Wk, Wv, Wg, Wo, xb, wqb, wkb, wvb, wgb, wob);

  k_mem<<<4, 256, 0, stream>>>(mk, mv, kn, vc);

  dim3 gg(16, 32);
  k_gemm<0><<<gg, 256, 0, stream>>>(xb, wvb, vc,   nullptr);
  k_gemm<1><<<gg, 256, 0, stream>>>(xb, wqb, qn,   nullptr);
  k_gemm<2><<<gg, 256, 0, stream>>>(xb, wkb, kn,   nullptr);
  k_gemm<3><<<gg, 256, 0, stream>>>(xb, wgb, gate, bg);

  k_trv<<<dim3(33, B_ * H_), 256, 0, stream>>>(vc, vt);

  k_attnM<<<1024, 1024, 0, stream>>>(qn, kn, vt, Wpre, Wpost, hsc, gate, aout);

  k_gemm<4><<<gg, 256, 0, stream>>>(aout, wob, out, nullptr);
}

// Round 11
// 431.058 us; speedup vs baseline: 1.6026x; 1.3533x over previous
//
#include <hip/hip_runtime.h>
#include <hip/hip_bf16.h>
#include <float.h>

#define B_ 4
#define N_ 1024
#define H_ 16
#define DH_ 64
#define NM_ 4
#define J_ 1028          // N_ + NM_
#define KR_ 1056         // padded row space
#define IT_ 4            // i rows per attention block
#define JST 1064         // sd row stride (halves)
#define TOPK_ 64
#define QKSCALE 10.0f
// fragment-ordered K: ktF[bg][jt(66)][f(2)][l(64)][e(8)]  halves; per-bg = 66*1024 = 67584
// fragment-ordered V^T: vtF[bg][dc(4)][jtE(33)][l(64)][e(8)]; per-bg = 4*33*512 = 67584
#define KTF_BG 67584
#define VTF_DC 16896     // 33*512

typedef __attribute__((ext_vector_type(8))) short short8;
typedef __attribute__((ext_vector_type(4))) float f32x4;
typedef __attribute__((ext_vector_type(8))) unsigned short ushort8;
typedef __attribute__((ext_vector_type(4))) unsigned int u32x4;
typedef __attribute__((ext_vector_type(2))) unsigned int u32x2;
typedef _Float16 half8 __attribute__((ext_vector_type(8)));

__device__ __forceinline__ unsigned short f2b(float f){
  union { float f; unsigned int i; } c; c.f = f;
  unsigned int r = c.i + 0x7FFFu + ((c.i >> 16) & 1u);   // RNE
  return (unsigned short)(r >> 16);
}
__device__ __forceinline__ unsigned short f2h(float f){
  return __builtin_bit_cast(unsigned short, (_Float16)f);
}
__device__ __forceinline__ float h2f(unsigned short u){
  return (float)__builtin_bit_cast(_Float16, u);
}
__device__ __forceinline__ unsigned int h2key(unsigned int u){
  return (u & 0x8000u) ? (~u & 0xFFFFu) : (u | 0x8000u);
}
__device__ __forceinline__ float key2f(unsigned int k){
  unsigned int u = (k & 0x8000u) ? (k & 0x7FFFu) : (~k & 0xFFFFu);
  return h2f((unsigned short)u);
}

// ---------------- fused f32 -> bf16 convert: x + 5 weights in one launch ----------------
__global__ void k_cvtAll(const float* __restrict__ x,  const float* __restrict__ wq,
                         const float* __restrict__ wk, const float* __restrict__ wv,
                         const float* __restrict__ wg, const float* __restrict__ wo,
                         unsigned short* __restrict__ xb,  unsigned short* __restrict__ wqb,
                         unsigned short* __restrict__ wkb, unsigned short* __restrict__ wvb,
                         unsigned short* __restrict__ wgb, unsigned short* __restrict__ wob){
  const int NX = 4096 * 1024, NW = 1024 * 1024;
  int i = blockIdx.x * 256 + threadIdx.x;
  int st = gridDim.x * 256;
  for (; i < NX + 5 * NW; i += st){
    if (i < NX){ xb[i] = f2b(x[i]); }
    else {
      int k = i - NX;
      int which = k >> 20, off = k & (NW - 1);
      const float* s = which == 0 ? wq : which == 1 ? wk : which == 2 ? wv : which == 3 ? wg : wo;
      unsigned short* d = which == 0 ? wqb : which == 1 ? wkb : which == 2 ? wvb : which == 3 ? wgb : wob;
      d[off] = f2b(s[off]);
    }
  }
}

// ---------------- memory slots into ktF/vtF + zero pad tiles ----------------
__global__ __launch_bounds__(256) void k_mem(const float* __restrict__ mk, const float* __restrict__ mv,
                                             unsigned short* __restrict__ ktF, unsigned short* __restrict__ vtF){
  int h = blockIdx.x * 4 + (threadIdx.x >> 6);   // 0..15
  int d = threadIdx.x & 63;
  unsigned short kh[4], vh[4];
  #pragma unroll
  for (int mm = 0; mm < 4; ++mm){
    float kv = mk[(h * 4 + mm) * 64 + d];
    float ss = kv * kv;
    #pragma unroll
    for (int off = 32; off; off >>= 1) ss += __shfl_xor(ss, off);
    kh[mm] = f2h(kv / fmaxf(sqrtf(ss), 1e-12f));
    vh[mm] = f2h(mv[(h * 4 + mm) * 64 + d]);
  }
  for (int b = 0; b < B_; ++b){
    int bg = b * 16 + h;
    // K slots: j = mm (tile 0): ktF[bg][0][d>>5][mm + ((d>>3)&3)*16][d&7]
    #pragma unroll
    for (int mm = 0; mm < 4; ++mm)
      ktF[(size_t)bg * KTF_BG + (size_t)(d >> 5) * 512 + (mm + ((d >> 3) & 3) * 16) * 8 + (d & 7)] = kh[mm];
    // V slots: j = mm (tile 0, l4=0): vtF[bg][d>>4][0][d&15][mm]
    #pragma unroll
    for (int mm = 0; mm < 4; ++mm)
      vtF[(size_t)bg * KTF_BG + (size_t)(d >> 4) * VTF_DC + (d & 15) * 8 + mm] = vh[mm];
    // zero K pad tiles jt=64,65 (j 1024..1055; gemm later fills j 1024..1027)
    {
      unsigned int* kz = (unsigned int*)(ktF + (size_t)bg * KTF_BG + 64 * 1024);
      for (int c = d; c < 1024; c += 64) kz[c] = 0u;
    }
    // zero V pad tile jtE=32 per dc
    #pragma unroll
    for (int dc = 0; dc < 4; ++dc){
      unsigned int* vz = (unsigned int*)(vtF + (size_t)bg * KTF_BG + (size_t)dc * VTF_DC + 32 * 512);
      for (int c = d; c < 256; c += 64) vz[c] = 0u;
    }
  }
}

// ---------------- bf16 MFMA GEMM 4096x1024x1024, 128x64 tile, 4 waves ----------------
// MODE 0: v -> vtF (fragment-ordered V^T) ; MODE 1: q -> qn f16 (l2norm*QKSCALE)
// MODE 2: k -> ktF (fragment-ordered, l2norm) ; MODE 3: gate -> sigmoid f16 ; MODE 4: f32 out
template<int MODE>
__global__ __launch_bounds__(256) void k_gemm(const unsigned short* __restrict__ A,
                                              const unsigned short* __restrict__ W,
                                              void* __restrict__ outp,
                                              const float* __restrict__ bg)
{
  __shared__ unsigned short As[128][40];
  __shared__ unsigned short Bs[64][40];
  const int t = threadIdx.x;
  const int m0 = blockIdx.y * 128, n0 = blockIdx.x * 64;
  const int l = t & 63, w = t >> 6;
  const int l15 = l & 15, l4 = l >> 4;

  f32x4 acc[2][4];
  #pragma unroll
  for (int a = 0; a < 2; ++a)
    #pragma unroll
    for (int b2 = 0; b2 < 4; ++b2) acc[a][b2] = (f32x4){0.f, 0.f, 0.f, 0.f};

  for (int k0 = 0; k0 < 1024; k0 += 32){
    #pragma unroll
    for (int cc = 0; cc < 2; ++cc){          // A tile: 128x32
      int c = t + cc * 256;
      int row = c >> 2, colc = (c & 3) * 8;
      *(ushort8*)&As[row][colc] = *(const ushort8*)&A[(m0 + row) * 1024 + k0 + colc];
    }
    {                                        // B tile: 32k x 64n
      int kk = t >> 3, nc = (t & 7) * 8;
      ushort8 vb = *(const ushort8*)&W[(k0 + kk) * 1024 + n0 + nc];
      #pragma unroll
      for (int e = 0; e < 8; ++e) Bs[nc + e][kk] = vb[e];
    }
    __syncthreads();
    short8 af[2], bfr[4];
    #pragma unroll
    for (int mf = 0; mf < 2; ++mf) af[mf]  = *(const short8*)&As[w * 32 + mf * 16 + l15][l4 * 8];
    #pragma unroll
    for (int nf = 0; nf < 4; ++nf) bfr[nf] = *(const short8*)&Bs[nf * 16 + l15][l4 * 8];
    #pragma unroll
    for (int mf = 0; mf < 2; ++mf)
      #pragma unroll
      for (int nf = 0; nf < 4; ++nf)
        acc[mf][nf] = __builtin_amdgcn_mfma_f32_16x16x32_bf16(af[mf], bfr[nf], acc[mf][nf], 0, 0, 0);
    __syncthreads();
  }

  const int hcol = n0 >> 6;
  #pragma unroll
  for (int mf = 0; mf < 2; ++mf){
    if constexpr (MODE == 0){
      // V -> vtF: 4 consecutive j per acc column; one 8B store
      int row0 = m0 + w * 32 + mf * 16 + l4 * 4;
      int bb = row0 >> 10;
      int j0 = (row0 & 1023) + NM_;
      int jtE = j0 >> 5, lj = (j0 & 31) >> 3, e0 = j0 & 7;
      #pragma unroll
      for (int nf = 0; nf < 4; ++nf){
        int col = n0 + nf * 16 + l15;
        int h = col >> 6, d = col & 63;
        unsigned int lo = (unsigned int)f2h(acc[mf][nf][0]) | ((unsigned int)f2h(acc[mf][nf][1]) << 16);
        unsigned int hi = (unsigned int)f2h(acc[mf][nf][2]) | ((unsigned int)f2h(acc[mf][nf][3]) << 16);
        unsigned short* dst = (unsigned short*)outp + (size_t)(bb * 16 + h) * KTF_BG +
                              (size_t)(d >> 4) * VTF_DC + (size_t)jtE * 512 +
                              ((d & 15) + lj * 16) * 8 + e0;
        *(u32x2*)dst = (u32x2){lo, hi};
      }
    } else {
      #pragma unroll
      for (int r = 0; r < 4; ++r){
        int row = m0 + w * 32 + mf * 16 + l4 * 4 + r;
        float rn = 1.f;
        if (MODE == 1 || MODE == 2){
          float ss = 0.f;
          #pragma unroll
          for (int nf = 0; nf < 4; ++nf) ss += acc[mf][nf][r] * acc[mf][nf][r];
          #pragma unroll
          for (int off = 1; off < 16; off <<= 1) ss += __shfl_xor(ss, off);
          rn = 1.f / fmaxf(sqrtf(ss), 1e-12f);
          if (MODE == 1) rn *= QKSCALE;
        }
        #pragma unroll
        for (int nf = 0; nf < 4; ++nf){
          int col = n0 + nf * 16 + l15;
          float v = acc[mf][nf][r];
          if (MODE == 4){
            ((float*)outp)[row * 1024 + col] = v;
          } else if (MODE == 3){
            float g = v + bg[col];
            ((unsigned short*)outp)[row * 1024 + col] = f2h(1.f / (1.f + __expf(-g)));
          } else if (MODE == 1){
            int bb = row >> 10, ii = row & 1023;
            int d = nf * 16 + l15;
            ((unsigned short*)outp)[((bb * H_ + hcol) * N_ + ii) * DH_ + d] = f2h(v * rn);
          } else { // MODE 2: K -> ktF fragment order
            int bb = row >> 10;
            int j = (row & 1023) + NM_;
            int d = nf * 16 + l15;
            ((unsigned short*)outp)[(size_t)(bb * 16 + hcol) * KTF_BG + (size_t)(j >> 4) * 1024 +
                                    (size_t)(d >> 5) * 512 + ((j & 15) + ((d >> 3) & 3) * 16) * 8 + (d & 7)]
              = f2h(v * rn);
          }
        }
      }
    }
  }
}

// ---------------- fused attention, all-MFMA, fragment-ordered K/V loads ----------------
// 1024 thr (16 waves) per (b, 4-i tile); every K/V global load is lane-contiguous 1KB.
__global__ __launch_bounds__(1024) void k_attnM(
  const unsigned short* __restrict__ qn, const unsigned short* __restrict__ ktF,
  const unsigned short* __restrict__ vtF, const float* __restrict__ wpre,
  const float* __restrict__ wpost, const float* __restrict__ hsc,
  const unsigned short* __restrict__ gate, unsigned short* __restrict__ aout)
{
  __shared__ unsigned short sd[16 * IT_ * JST]; // 136,192 B: raw -> mixed -> attn
  __shared__ unsigned short qls[16 * 4 * 64];   // 8 KB staged q [g][ii][d]
  __shared__ unsigned short wpre16[16 * 32];    // Wpre, zero-padded K=32
  __shared__ unsigned short wpost16[16 * 32];   // Wpost, zero-padded K=32

  const int blk = blockIdx.x;
  const int b = (blk >> 1) & 3;                  // fixed per XCD pair (blk%8 -> XCD)
  const int idx = ((blk >> 3) << 1) | (blk & 1); // 0..255, ascending within XCD
  const int it = 255 - idx;                      // big tiles first
  const int i0 = it * IT_;
  const int nAmax = i0 + IT_ + 4;
  const int nJtA = (nAmax + 15) >> 4;
  const int nJtE = (nAmax + 31) >> 5;
  const int nJtD = nJtE * 2;
  const int t = threadIdx.x;
  const int w = t >> 6, l = t & 63;
  const int l15 = l & 15, l4 = l >> 4;

  if (t < 256){
    int h = t >> 4, g = t & 15;
    wpre16[h * 32 + g]       = f2h(wpre[h * 16 + g]);
    wpre16[h * 32 + 16 + g]  = 0;
    wpost16[h * 32 + g]      = f2h(wpost[h * 16 + g]);
    wpost16[h * 32 + 16 + g] = 0;
  }
  for (int c = t; c < 2048; c += 1024){
    int d2 = c & 31, ii = (c >> 5) & 3, g = c >> 7;
    ((unsigned int*)qls)[c] =
      *(const unsigned int*)(qn + ((size_t)(b * 16 + g) * N_ + i0 + ii) * 64 + d2 * 2);
  }
  __syncthreads();

  // ---- phase A: raw dots; K loads lane-contiguous from ktF ----
  for (int g = 0; g < 16; ++g){
    const int bg = b * 16 + g;
    const unsigned short* qp = &qls[(g * 4 + (l15 & 3)) * 64 + l4 * 8];
    half8 qf0 = *(const half8*)(qp);
    half8 qf1 = *(const half8*)(qp + 32);
    const unsigned short* kbase = ktF + (size_t)bg * KTF_BG + l * 8;
    for (int jt = w; jt < nJtA; jt += 16){
      const unsigned short* kb = kbase + (size_t)jt * 1024;
      half8 kf0 = *(const half8*)(kb);
      half8 kf1 = *(const half8*)(kb + 512);
      f32x4 acc = (f32x4){0.f, 0.f, 0.f, 0.f};
      acc = __builtin_amdgcn_mfma_f32_16x16x32_f16(kf0, qf0, acc, 0, 0, 0);
      acc = __builtin_amdgcn_mfma_f32_16x16x32_f16(kf1, qf1, acc, 0, 0, 0);
      if (l15 < IT_){
        unsigned int p0 = (unsigned int)f2h(acc[0]) | ((unsigned int)f2h(acc[1]) << 16);
        unsigned int p1 = (unsigned int)f2h(acc[2]) | ((unsigned int)f2h(acc[3]) << 16);
        unsigned int* dst = (unsigned int*)&sd[(g * IT_ + l15) * JST + jt * 16 + l4 * 4];
        dst[0] = p0; dst[1] = p1;
      }
    }
  }
  __syncthreads();

  // ---- phase B: W_pre premix via MFMA, in-place per (ii, jt16) patch ----
  {
    half8 wa = *(const half8*)&wpre16[l15 * 32 + l4 * 8];
    const int ntask = IT_ * nJtA;
    for (int task = w; task < ntask; task += 16){
      const int ii = task & (IT_ - 1), jt = task >> 2;
      unsigned int fb[4] = {0u, 0u, 0u, 0u};
      if (l4 < 2){
        const unsigned short* src = &sd[((l4 * 8) * IT_ + ii) * JST + jt * 16 + l15];
        #pragma unroll
        for (int e = 0; e < 8; e += 2){
          unsigned int lo = src[(size_t)(e)     * IT_ * JST];
          unsigned int hi = src[(size_t)(e + 1) * IT_ * JST];
          fb[e >> 1] = (lo & 0xFFFFu) | (hi << 16);
        }
      }
      f32x4 acc = (f32x4){0.f, 0.f, 0.f, 0.f};
      acc = __builtin_amdgcn_mfma_f32_16x16x32_f16(wa, __builtin_bit_cast(half8, *(u32x4*)fb), acc, 0, 0, 0);
      #pragma unroll
      for (int r = 0; r < 4; ++r)
        sd[((l4 * 4 + r) * IT_ + ii) * JST + jt * 16 + l15] = f2h(acc[r]);
    }
  }
  __syncthreads();

  // ---- phase C: per-row top-64 threshold + softmax ----
  for (int rr = 0; rr < 4; ++rr){
    const int row = w * 4 + rr;            // 0..63
    const int g = row >> 2, ii = row & 3;
    const int nA = i0 + ii + 5;
    unsigned short* rowp = &sd[(g * IT_ + ii) * JST];
    unsigned int kw[9];
    #pragma unroll
    for (int grp = 0; grp < 9; ++grp){
      int j = grp * 128 + l * 2;
      unsigned int u = (j < JST) ? *(const unsigned int*)(rowp + j) : 0u;
      unsigned int klo = h2key(u & 0xFFFFu);
      unsigned int khi = h2key(u >> 16);
      if (j     >= nA) klo = 0u;
      if (j + 1 >= nA) khi = 0u;
      kw[grp] = klo | (khi << 16);
    }
    unsigned int kmx = 0u;
    #pragma unroll
    for (int grp = 0; grp < 9; ++grp){
      unsigned int m2 = max(kw[grp] >> 16, kw[grp] & 0xFFFFu);
      kmx = max(kmx, m2);
    }
    #pragma unroll
    for (int off = 32; off; off >>= 1) kmx = max(kmx, (unsigned int)__shfl_xor((int)kmx, off));
    const float mx = key2f(kmx);

    unsigned int T = 0u;
    if (nA > TOPK_){
      for (int bit = 15; bit >= 2; --bit){
        unsigned int Tc = T | (1u << bit);
        int c = 0;
        #pragma unroll
        for (int grp = 0; grp < 9; ++grp){
          c += __popcll(__ballot((kw[grp] & 0xFFFFu) >= Tc));
          c += __popcll(__ballot((kw[grp] >> 16) >= Tc));
        }
        if (c >= TOPK_){
          T = Tc;
          if (c == TOPK_) break;
        }
      }
    }
    if (T == 0u) T = 1u;

    float s = 0.f;
    float ev[18];
    #pragma unroll
    for (int grp = 0; grp < 9; ++grp){
      unsigned int klo = kw[grp] & 0xFFFFu, khi = kw[grp] >> 16;
      float elo = (klo >= T) ? __expf(key2f(klo) - mx) : 0.f;
      float ehi = (khi >= T) ? __expf(key2f(khi) - mx) : 0.f;
      ev[grp * 2] = elo; ev[grp * 2 + 1] = ehi;
      s += elo + ehi;
    }
    #pragma unroll
    for (int off = 32; off; off >>= 1) s += __shfl_xor(s, off);
    float inv = 1.f / s;
    #pragma unroll
    for (int grp = 0; grp < 9; ++grp){
      int j = grp * 128 + l * 2;
      if (j < JST)
        *(unsigned int*)(rowp + j) =
          (unsigned int)f2h(ev[grp * 2] * inv) | ((unsigned int)f2h(ev[grp * 2 + 1] * inv) << 16);
    }
  }
  __syncthreads();

  // ---- phase D: postmix via MFMA (causal-trimmed) ----
  {
    const int ntask = IT_ * nJtD;
    for (int task = w; task < ntask; task += 16){
      const int ii = task & (IT_ - 1), jt = task >> 2;
      half8 wa = *(const half8*)&wpost16[l15 * 32 + l4 * 8];
      unsigned int fb[4] = {0u, 0u, 0u, 0u};
      if (l4 < 2){
        const unsigned short* src = &sd[((l4 * 8) * IT_ + ii) * JST + jt * 16 + l15];
        #pragma unroll
        for (int e = 0; e < 8; e += 2){
          unsigned int lo = src[(size_t)(e)     * IT_ * JST];
          unsigned int hi = src[(size_t)(e + 1) * IT_ * JST];
          fb[e >> 1] = (lo & 0xFFFFu) | (hi << 16);
        }
      }
      f32x4 acc = (f32x4){0.f, 0.f, 0.f, 0.f};
      acc = __builtin_amdgcn_mfma_f32_16x16x32_f16(wa, __builtin_bit_cast(half8, *(u32x4*)fb), acc, 0, 0, 0);
      #pragma unroll
      for (int r = 0; r < 4; ++r)
        sd[((l4 * 4 + r) * IT_ + ii) * JST + jt * 16 + l15] = f2h(acc[r]);
    }
  }
  __syncthreads();

  // ---- phase E: PV via MFMA; V loads lane-contiguous from vtF ----
  for (int task = w; task < 64; task += 16){
    const int h = task >> 2, dc = task & 3;
    const int bg = b * 16 + h;
    const unsigned short* vbase = vtF + (size_t)bg * KTF_BG + (size_t)dc * VTF_DC + l * 8;
    const unsigned short* arow = &sd[(h * IT_ + (l15 & 3)) * JST + l4 * 8];
    f32x4 acc = (f32x4){0.f, 0.f, 0.f, 0.f};
    for (int jt = 0; jt < nJtE; ++jt){
      half8 af = *(const half8*)(arow + jt * 32);
      half8 vf = *(const half8*)(vbase + (size_t)jt * 512);
      acc = __builtin_amdgcn_mfma_f32_16x16x32_f16(af, vf, acc, 0, 0, 0);
    }
    if (l4 == 0){
      const float hs = hsc[h];
      #pragma unroll
      for (int r = 0; r < IT_; ++r){
        const int irow = (b << 10) | (i0 + r);
        const size_t o = (size_t)irow * 1024 + h * 64 + dc * 16 + l15;
        aout[o] = f2b(acc[r] * hs * h2f(gate[o]));
      }
    }
  }
}

// ---------------- host ----------------
extern "C" void kernel_launch(void* const* d_in, const int* in_sizes, int n_in,
                              void* d_out, int out_size, void* d_ws, size_t ws_size,
                              hipStream_t stream) {
  const float* x     = (const float*)d_in[0];
  const float* Wq    = (const float*)d_in[1];
  const float* Wk    = (const float*)d_in[2];
  const float* Wv    = (const float*)d_in[3];
  const float* Wpre  = (const float*)d_in[4];
  const float* Wpost = (const float*)d_in[5];
  const float* mk    = (const float*)d_in[6];
  const float* mv    = (const float*)d_in[7];
  const float* hsc   = (const float*)d_in[8];
  const float* Wg    = (const float*)d_in[9];
  const float* bg    = (const float*)d_in[10];
  const float* Wo    = (const float*)d_in[11];
  float* out = (float*)d_out;

  char* ws = (char*)d_ws;
  size_t off = 0;
  auto alloc = [&](size_t bytes) -> void* {
    void* p = ws + off; off += (bytes + 255) & ~(size_t)255; return p;
  };
  unsigned short* xb   = (unsigned short*)alloc((size_t)4096 * 1024 * 2);
  unsigned short* wqb  = (unsigned short*)alloc((size_t)1024 * 1024 * 2);
  unsigned short* wkb  = (unsigned short*)alloc((size_t)1024 * 1024 * 2);
  unsigned short* wvb  = (unsigned short*)alloc((size_t)1024 * 1024 * 2);
  unsigned short* wgb  = (unsigned short*)alloc((size_t)1024 * 1024 * 2);
  unsigned short* wob  = (unsigned short*)alloc((size_t)1024 * 1024 * 2);
  unsigned short* qn   = (unsigned short*)alloc((size_t)B_ * H_ * N_ * DH_ * 2);   // f16
  unsigned short* ktF  = (unsigned short*)alloc((size_t)B_ * H_ * KTF_BG * 2);     // frag-ordered K
  unsigned short* vtF  = (unsigned short*)alloc((size_t)B_ * H_ * KTF_BG * 2);     // frag-ordered V^T
  unsigned short* gate = (unsigned short*)alloc((size_t)4096 * 1024 * 2);          // f16
  unsigned short* aout = (unsigned short*)alloc((size_t)4096 * 1024 * 2);          // bf16

  k_cvtAll<<<2048, 256, 0, stream>>>(x, Wq, Wk, Wv, Wg, Wo, xb, wqb, wkb, wvb, wgb, wob);

  k_mem<<<4, 256, 0, stream>>>(mk, mv, ktF, vtF);

  dim3 gg(16, 32);
  k_gemm<0><<<gg, 256, 0, stream>>>(xb, wvb, vtF,  nullptr);
  k_gemm<1><<<gg, 256, 0, stream>>>(xb, wqb, qn,   nullptr);
  k_gemm<2><<<gg, 256, 0, stream>>>(xb, wkb, ktF,  nullptr);
  k_gemm<3><<<gg, 256, 0, stream>>>(xb, wgb, gate, bg);

  k_attnM<<<1024, 1024, 0, stream>>>(qn, ktF, vtF, Wpre, Wpost, hsc, gate, aout);

  k_gemm<4><<<gg, 256, 0, stream>>>(aout, wob, out, nullptr);
}

// Round 12
// 397.601 us; speedup vs baseline: 1.7374x; 1.0841x over previous
//
#include <hip/hip_runtime.h>
#include <hip/hip_bf16.h>
#include <float.h>

#define B_ 4
#define N_ 1024
#define H_ 16
#define DH_ 64
#define NM_ 4
#define J_ 1028          // N_ + NM_
#define IT_ 4            // i rows per attention block
#define JST 1064         // sd row stride (halves)
#define TOPK_ 64
#define QKSCALE 10.0f
// fragment-ordered K: ktF[bg][jt(66)][f(2)][l(64)][e(8)]  halves; per-bg = 66*1024 = 67584
// fragment-ordered V^T: vtF[bg][dc(4)][jtE(33)][l(64)][e(8)]; per-bg = 4*33*512 = 67584
#define KTF_BG 67584
#define VTF_DC 16896     // 33*512

typedef __attribute__((ext_vector_type(8))) short short8;
typedef __attribute__((ext_vector_type(4))) float f32x4;
typedef __attribute__((ext_vector_type(8))) unsigned short ushort8;
typedef __attribute__((ext_vector_type(4))) unsigned int u32x4;
typedef __attribute__((ext_vector_type(2))) unsigned int u32x2;
typedef _Float16 half8 __attribute__((ext_vector_type(8)));

__device__ __forceinline__ unsigned short f2b(float f){
  union { float f; unsigned int i; } c; c.f = f;
  unsigned int r = c.i + 0x7FFFu + ((c.i >> 16) & 1u);   // RNE
  return (unsigned short)(r >> 16);
}
__device__ __forceinline__ unsigned short f2h(float f){
  return __builtin_bit_cast(unsigned short, (_Float16)f);
}
__device__ __forceinline__ float h2f(unsigned short u){
  return (float)__builtin_bit_cast(_Float16, u);
}
__device__ __forceinline__ unsigned int h2key(unsigned int u){
  return (u & 0x8000u) ? (~u & 0xFFFFu) : (u | 0x8000u);
}
__device__ __forceinline__ float key2f(unsigned int k){
  unsigned int u = (k & 0x8000u) ? (k & 0x7FFFu) : (~k & 0xFFFFu);
  return h2f((unsigned short)u);
}

// ---------------- fused f32 -> bf16 convert: x, [Wq|Wk|Wv|Wg] -> wcat (N=4096), Wo ----------------
__global__ void k_cvtAll(const float* __restrict__ x,  const float* __restrict__ wq,
                         const float* __restrict__ wk, const float* __restrict__ wv,
                         const float* __restrict__ wg, const float* __restrict__ wo,
                         unsigned short* __restrict__ xb, unsigned short* __restrict__ wcat,
                         unsigned short* __restrict__ wob){
  const int NX = 4096 * 1024, NW = 1024 * 1024;
  int i = blockIdx.x * 256 + threadIdx.x;
  int st = gridDim.x * 256;
  for (; i < NX + 5 * NW; i += st){
    if (i < NX){ xb[i] = f2b(x[i]); }
    else {
      int k = i - NX;
      int which = k >> 20, off = k & (NW - 1);
      if (which == 4){ wob[off] = f2b(wo[off]); }
      else {
        const float* s = which == 0 ? wq : which == 1 ? wk : which == 2 ? wv : wg;
        wcat[(size_t)(off >> 10) * 4096 + which * 1024 + (off & 1023)] = f2b(s[off]);
      }
    }
  }
}

// ---------------- memory slots into ktF/vtF + zero pad tiles ----------------
__global__ __launch_bounds__(256) void k_mem(const float* __restrict__ mk, const float* __restrict__ mv,
                                             unsigned short* __restrict__ ktF, unsigned short* __restrict__ vtF){
  int h = blockIdx.x * 4 + (threadIdx.x >> 6);   // 0..15
  int d = threadIdx.x & 63;
  unsigned short kh[4], vh[4];
  #pragma unroll
  for (int mm = 0; mm < 4; ++mm){
    float kv = mk[(h * 4 + mm) * 64 + d];
    float ss = kv * kv;
    #pragma unroll
    for (int off = 32; off; off >>= 1) ss += __shfl_xor(ss, off);
    kh[mm] = f2h(kv / fmaxf(sqrtf(ss), 1e-12f));
    vh[mm] = f2h(mv[(h * 4 + mm) * 64 + d]);
  }
  for (int b = 0; b < B_; ++b){
    int bg = b * 16 + h;
    #pragma unroll
    for (int mm = 0; mm < 4; ++mm)
      ktF[(size_t)bg * KTF_BG + (size_t)(d >> 5) * 512 + (mm + ((d >> 3) & 3) * 16) * 8 + (d & 7)] = kh[mm];
    #pragma unroll
    for (int mm = 0; mm < 4; ++mm)
      vtF[(size_t)bg * KTF_BG + (size_t)(d >> 4) * VTF_DC + (d & 15) * 8 + mm] = vh[mm];
    {
      unsigned int* kz = (unsigned int*)(ktF + (size_t)bg * KTF_BG + 64 * 1024);
      for (int c = d; c < 1024; c += 64) kz[c] = 0u;
    }
    #pragma unroll
    for (int dc = 0; dc < 4; ++dc){
      unsigned int* vz = (unsigned int*)(vtF + (size_t)bg * KTF_BG + (size_t)dc * VTF_DC + 32 * 512);
      for (int c = d; c < 256; c += 64) vz[c] = 0u;
    }
  }
}

// ---------------- fused QKVG GEMM: 4096x4096x1024 (wcat), 128x64 tile, per-which epilogue ----------------
__global__ __launch_bounds__(256) void k_gemmF(const unsigned short* __restrict__ A,
                                               const unsigned short* __restrict__ Wc,
                                               unsigned short* __restrict__ qn,
                                               unsigned short* __restrict__ ktF,
                                               unsigned short* __restrict__ vtF,
                                               unsigned short* __restrict__ gate,
                                               const float* __restrict__ bgv)
{
  __shared__ unsigned short As[128][40];
  __shared__ unsigned short Bs[64][40];
  const int t = threadIdx.x;
  const int m0 = blockIdx.y * 128, n0 = blockIdx.x * 64;
  const int l = t & 63, w = t >> 6;
  const int l15 = l & 15, l4 = l >> 4;

  f32x4 acc[2][4];
  #pragma unroll
  for (int a = 0; a < 2; ++a)
    #pragma unroll
    for (int b2 = 0; b2 < 4; ++b2) acc[a][b2] = (f32x4){0.f, 0.f, 0.f, 0.f};

  for (int k0 = 0; k0 < 1024; k0 += 32){
    #pragma unroll
    for (int cc = 0; cc < 2; ++cc){          // A tile: 128x32
      int c = t + cc * 256;
      int row = c >> 2, colc = (c & 3) * 8;
      *(ushort8*)&As[row][colc] = *(const ushort8*)&A[(m0 + row) * 1024 + k0 + colc];
    }
    {                                        // B tile: 32k x 64n from wcat (stride 4096)
      int kk = t >> 3, nc = (t & 7) * 8;
      ushort8 vb = *(const ushort8*)&Wc[(size_t)(k0 + kk) * 4096 + n0 + nc];
      #pragma unroll
      for (int e = 0; e < 8; ++e) Bs[nc + e][kk] = vb[e];
    }
    __syncthreads();
    short8 af[2], bfr[4];
    #pragma unroll
    for (int mf = 0; mf < 2; ++mf) af[mf]  = *(const short8*)&As[w * 32 + mf * 16 + l15][l4 * 8];
    #pragma unroll
    for (int nf = 0; nf < 4; ++nf) bfr[nf] = *(const short8*)&Bs[nf * 16 + l15][l4 * 8];
    #pragma unroll
    for (int mf = 0; mf < 2; ++mf)
      #pragma unroll
      for (int nf = 0; nf < 4; ++nf)
        acc[mf][nf] = __builtin_amdgcn_mfma_f32_16x16x32_bf16(af[mf], bfr[nf], acc[mf][nf], 0, 0, 0);
    __syncthreads();
  }

  const int which = n0 >> 10;        // 0=q 1=k 2=v 3=gate (uniform per block)
  const int ncol0 = n0 & 1023;
  const int hcol = ncol0 >> 6;
  #pragma unroll
  for (int mf = 0; mf < 2; ++mf){
    if (which == 2){
      // V -> vtF: 4 consecutive j per acc column; one 8B store
      int row0 = m0 + w * 32 + mf * 16 + l4 * 4;
      int bb = row0 >> 10;
      int j0 = (row0 & 1023) + NM_;
      int jtE = j0 >> 5, lj = (j0 & 31) >> 3, e0 = j0 & 7;
      #pragma unroll
      for (int nf = 0; nf < 4; ++nf){
        int col = ncol0 + nf * 16 + l15;
        int h = col >> 6, d = col & 63;
        unsigned int lo = (unsigned int)f2h(acc[mf][nf][0]) | ((unsigned int)f2h(acc[mf][nf][1]) << 16);
        unsigned int hi = (unsigned int)f2h(acc[mf][nf][2]) | ((unsigned int)f2h(acc[mf][nf][3]) << 16);
        unsigned short* dst = vtF + (size_t)(bb * 16 + h) * KTF_BG +
                              (size_t)(d >> 4) * VTF_DC + (size_t)jtE * 512 +
                              ((d & 15) + lj * 16) * 8 + e0;
        *(u32x2*)dst = (u32x2){lo, hi};
      }
    } else {
      #pragma unroll
      for (int r = 0; r < 4; ++r){
        int row = m0 + w * 32 + mf * 16 + l4 * 4 + r;
        float rn = 1.f;
        if (which <= 1){
          float ss = 0.f;
          #pragma unroll
          for (int nf = 0; nf < 4; ++nf) ss += acc[mf][nf][r] * acc[mf][nf][r];
          #pragma unroll
          for (int off = 1; off < 16; off <<= 1) ss += __shfl_xor(ss, off);
          rn = 1.f / fmaxf(sqrtf(ss), 1e-12f);
          if (which == 0) rn *= QKSCALE;
        }
        #pragma unroll
        for (int nf = 0; nf < 4; ++nf){
          int col = ncol0 + nf * 16 + l15;
          float v = acc[mf][nf][r];
          int bb = row >> 10, ii = row & 1023;
          if (which == 3){
            float g = v + bgv[3 * 1024 + col];
            gate[(size_t)row * 1024 + col] = f2h(1.f / (1.f + __expf(-g)));
          } else if (which == 0){
            int d = col & 63;
            qn[((size_t)(bb * H_ + hcol) * N_ + ii) * DH_ + d] = f2h(v * rn);
          } else { // which == 1: K -> ktF fragment order
            int j = ii + NM_;
            int d = col & 63;
            ktF[(size_t)(bb * 16 + hcol) * KTF_BG + (size_t)(j >> 4) * 1024 +
                (size_t)(d >> 5) * 512 + ((j & 15) + ((d >> 3) & 3) * 16) * 8 + (d & 7)]
              = f2h(v * rn);
          }
        }
      }
    }
  }
}

// ---------------- final GEMM aout x Wo -> f32 out, 128x64 tile ----------------
__global__ __launch_bounds__(256) void k_gemmO(const unsigned short* __restrict__ A,
                                               const unsigned short* __restrict__ W,
                                               float* __restrict__ outp)
{
  __shared__ unsigned short As[128][40];
  __shared__ unsigned short Bs[64][40];
  const int t = threadIdx.x;
  const int m0 = blockIdx.y * 128, n0 = blockIdx.x * 64;
  const int l = t & 63, w = t >> 6;
  const int l15 = l & 15, l4 = l >> 4;

  f32x4 acc[2][4];
  #pragma unroll
  for (int a = 0; a < 2; ++a)
    #pragma unroll
    for (int b2 = 0; b2 < 4; ++b2) acc[a][b2] = (f32x4){0.f, 0.f, 0.f, 0.f};

  for (int k0 = 0; k0 < 1024; k0 += 32){
    #pragma unroll
    for (int cc = 0; cc < 2; ++cc){
      int c = t + cc * 256;
      int row = c >> 2, colc = (c & 3) * 8;
      *(ushort8*)&As[row][colc] = *(const ushort8*)&A[(m0 + row) * 1024 + k0 + colc];
    }
    {
      int kk = t >> 3, nc = (t & 7) * 8;
      ushort8 vb = *(const ushort8*)&W[(k0 + kk) * 1024 + n0 + nc];
      #pragma unroll
      for (int e = 0; e < 8; ++e) Bs[nc + e][kk] = vb[e];
    }
    __syncthreads();
    short8 af[2], bfr[4];
    #pragma unroll
    for (int mf = 0; mf < 2; ++mf) af[mf]  = *(const short8*)&As[w * 32 + mf * 16 + l15][l4 * 8];
    #pragma unroll
    for (int nf = 0; nf < 4; ++nf) bfr[nf] = *(const short8*)&Bs[nf * 16 + l15][l4 * 8];
    #pragma unroll
    for (int mf = 0; mf < 2; ++mf)
      #pragma unroll
      for (int nf = 0; nf < 4; ++nf)
        acc[mf][nf] = __builtin_amdgcn_mfma_f32_16x16x32_bf16(af[mf], bfr[nf], acc[mf][nf], 0, 0, 0);
    __syncthreads();
  }

  #pragma unroll
  for (int mf = 0; mf < 2; ++mf)
    #pragma unroll
    for (int r = 0; r < 4; ++r){
      int row = m0 + w * 32 + mf * 16 + l4 * 4 + r;
      #pragma unroll
      for (int nf = 0; nf < 4; ++nf)
        outp[(size_t)row * 1024 + n0 + nf * 16 + l15] = acc[mf][nf][r];
    }
}

// ---------------- fused attention, all-MFMA, fragment-ordered K/V loads ----------------
__global__ __launch_bounds__(1024) void k_attnM(
  const unsigned short* __restrict__ qn, const unsigned short* __restrict__ ktF,
  const unsigned short* __restrict__ vtF, const float* __restrict__ wpre,
  const float* __restrict__ wpost, const float* __restrict__ hsc,
  const unsigned short* __restrict__ gate, unsigned short* __restrict__ aout)
{
  __shared__ unsigned short sd[16 * IT_ * JST]; // 136,192 B: raw -> mixed -> attn
  __shared__ unsigned short qls[16 * 4 * 64];   // 8 KB staged q [g][ii][d]
  __shared__ unsigned short wpre16[16 * 32];
  __shared__ unsigned short wpost16[16 * 32];

  const int blk = blockIdx.x;
  const int b = (blk >> 1) & 3;
  const int idx = ((blk >> 3) << 1) | (blk & 1);
  const int it = 255 - idx;
  const int i0 = it * IT_;
  const int nAmax = i0 + IT_ + 4;
  const int nJtA = (nAmax + 15) >> 4;
  const int nJtE = (nAmax + 31) >> 5;
  const int nJtD = nJtE * 2;
  const int jc = nJtE * 32;            // processing bound for phase C (<= 1056)
  const int t = threadIdx.x;
  const int w = t >> 6, l = t & 63;
  const int l15 = l & 15, l4 = l >> 4;

  if (t < 256){
    int h = t >> 4, g = t & 15;
    wpre16[h * 32 + g]       = f2h(wpre[h * 16 + g]);
    wpre16[h * 32 + 16 + g]  = 0;
    wpost16[h * 32 + g]      = f2h(wpost[h * 16 + g]);
    wpost16[h * 32 + 16 + g] = 0;
  }
  for (int c = t; c < 2048; c += 1024){
    int d2 = c & 31, ii = (c >> 5) & 3, g = c >> 7;
    ((unsigned int*)qls)[c] =
      *(const unsigned int*)(qn + ((size_t)(b * 16 + g) * N_ + i0 + ii) * 64 + d2 * 2);
  }
  __syncthreads();

  // ---- phase A: raw dots; K loads lane-contiguous from ktF ----
  for (int g = 0; g < 16; ++g){
    const int bg = b * 16 + g;
    const unsigned short* qp = &qls[(g * 4 + (l15 & 3)) * 64 + l4 * 8];
    half8 qf0 = *(const half8*)(qp);
    half8 qf1 = *(const half8*)(qp + 32);
    const unsigned short* kbase = ktF + (size_t)bg * KTF_BG + l * 8;
    for (int jt = w; jt < nJtA; jt += 16){
      const unsigned short* kb = kbase + (size_t)jt * 1024;
      half8 kf0 = *(const half8*)(kb);
      half8 kf1 = *(const half8*)(kb + 512);
      f32x4 acc = (f32x4){0.f, 0.f, 0.f, 0.f};
      acc = __builtin_amdgcn_mfma_f32_16x16x32_f16(kf0, qf0, acc, 0, 0, 0);
      acc = __builtin_amdgcn_mfma_f32_16x16x32_f16(kf1, qf1, acc, 0, 0, 0);
      if (l15 < IT_){
        unsigned int p0 = (unsigned int)f2h(acc[0]) | ((unsigned int)f2h(acc[1]) << 16);
        unsigned int p1 = (unsigned int)f2h(acc[2]) | ((unsigned int)f2h(acc[3]) << 16);
        unsigned int* dst = (unsigned int*)&sd[(g * IT_ + l15) * JST + jt * 16 + l4 * 4];
        dst[0] = p0; dst[1] = p1;
      }
    }
  }
  __syncthreads();

  // ---- phase B: W_pre premix via MFMA, in-place per (ii, jt16) patch ----
  {
    half8 wa = *(const half8*)&wpre16[l15 * 32 + l4 * 8];
    const int ntask = IT_ * nJtA;
    for (int task = w; task < ntask; task += 16){
      const int ii = task & (IT_ - 1), jt = task >> 2;
      unsigned int fb[4] = {0u, 0u, 0u, 0u};
      if (l4 < 2){
        const unsigned short* src = &sd[((l4 * 8) * IT_ + ii) * JST + jt * 16 + l15];
        #pragma unroll
        for (int e = 0; e < 8; e += 2){
          unsigned int lo = src[(size_t)(e)     * IT_ * JST];
          unsigned int hi = src[(size_t)(e + 1) * IT_ * JST];
          fb[e >> 1] = (lo & 0xFFFFu) | (hi << 16);
        }
      }
      f32x4 acc = (f32x4){0.f, 0.f, 0.f, 0.f};
      acc = __builtin_amdgcn_mfma_f32_16x16x32_f16(wa, __builtin_bit_cast(half8, *(u32x4*)fb), acc, 0, 0, 0);
      #pragma unroll
      for (int r = 0; r < 4; ++r)
        sd[((l4 * 4 + r) * IT_ + ii) * JST + jt * 16 + l15] = f2h(acc[r]);
    }
  }
  __syncthreads();

  // ---- phase C: per-row top-64 threshold + softmax, causal-trimmed to jc ----
  for (int rr = 0; rr < 4; ++rr){
    const int row = w * 4 + rr;            // 0..63
    const int g = row >> 2, ii = row & 3;
    const int nA = i0 + ii + 5;
    unsigned short* rowp = &sd[(g * IT_ + ii) * JST];
    unsigned int kw[9];
    #pragma unroll
    for (int grp = 0; grp < 9; ++grp){
      kw[grp] = 0u;
      if (grp * 128 < jc){
        int j = grp * 128 + l * 2;
        unsigned int u = (j < JST) ? *(const unsigned int*)(rowp + j) : 0u;
        unsigned int klo = h2key(u & 0xFFFFu);
        unsigned int khi = h2key(u >> 16);
        if (j     >= nA) klo = 0u;
        if (j + 1 >= nA) khi = 0u;
        kw[grp] = klo | (khi << 16);
      }
    }
    unsigned int kmx = 0u;
    #pragma unroll
    for (int grp = 0; grp < 9; ++grp){
      if (grp * 128 < jc){
        unsigned int m2 = max(kw[grp] >> 16, kw[grp] & 0xFFFFu);
        kmx = max(kmx, m2);
      }
    }
    #pragma unroll
    for (int off = 32; off; off >>= 1) kmx = max(kmx, (unsigned int)__shfl_xor((int)kmx, off));
    const float mx = key2f(kmx);

    unsigned int T = 0u;
    if (nA > TOPK_){
      for (int bit = 15; bit >= 2; --bit){
        unsigned int Tc = T | (1u << bit);
        int c = 0;
        #pragma unroll
        for (int grp = 0; grp < 9; ++grp){
          if (grp * 128 < jc){
            c += __popcll(__ballot((kw[grp] & 0xFFFFu) >= Tc));
            c += __popcll(__ballot((kw[grp] >> 16) >= Tc));
          }
        }
        if (c >= TOPK_){
          T = Tc;
          if (c == TOPK_) break;
        }
      }
    }
    if (T == 0u) T = 1u;

    float s = 0.f;
    float ev[18];
    #pragma unroll
    for (int grp = 0; grp < 9; ++grp){
      if (grp * 128 < jc){
        unsigned int klo = kw[grp] & 0xFFFFu, khi = kw[grp] >> 16;
        float elo = (klo >= T) ? __expf(key2f(klo) - mx) : 0.f;
        float ehi = (khi >= T) ? __expf(key2f(khi) - mx) : 0.f;
        ev[grp * 2] = elo; ev[grp * 2 + 1] = ehi;
        s += elo + ehi;
      }
    }
    #pragma unroll
    for (int off = 32; off; off >>= 1) s += __shfl_xor(s, off);
    float inv = 1.f / s;
    #pragma unroll
    for (int grp = 0; grp < 9; ++grp){
      if (grp * 128 < jc){
        int j = grp * 128 + l * 2;
        if (j < JST)
          *(unsigned int*)(rowp + j) =
            (unsigned int)f2h(ev[grp * 2] * inv) | ((unsigned int)f2h(ev[grp * 2 + 1] * inv) << 16);
      }
    }
  }
  __syncthreads();

  // ---- phase D: postmix via MFMA (causal-trimmed) ----
  {
    const int ntask = IT_ * nJtD;
    for (int task = w; task < ntask; task += 16){
      const int ii = task & (IT_ - 1), jt = task >> 2;
      half8 wa = *(const half8*)&wpost16[l15 * 32 + l4 * 8];
      unsigned int fb[4] = {0u, 0u, 0u, 0u};
      if (l4 < 2){
        const unsigned short* src = &sd[((l4 * 8) * IT_ + ii) * JST + jt * 16 + l15];
        #pragma unroll
        for (int e = 0; e < 8; e += 2){
          unsigned int lo = src[(size_t)(e)     * IT_ * JST];
          unsigned int hi = src[(size_t)(e + 1) * IT_ * JST];
          fb[e >> 1] = (lo & 0xFFFFu) | (hi << 16);
        }
      }
      f32x4 acc = (f32x4){0.f, 0.f, 0.f, 0.f};
      acc = __builtin_amdgcn_mfma_f32_16x16x32_f16(wa, __builtin_bit_cast(half8, *(u32x4*)fb), acc, 0, 0, 0);
      #pragma unroll
      for (int r = 0; r < 4; ++r)
        sd[((l4 * 4 + r) * IT_ + ii) * JST + jt * 16 + l15] = f2h(acc[r]);
    }
  }
  __syncthreads();

  // ---- phase E: PV via MFMA; V loads lane-contiguous from vtF ----
  for (int task = w; task < 64; task += 16){
    const int h = task >> 2, dc = task & 3;
    const int bg = b * 16 + h;
    const unsigned short* vbase = vtF + (size_t)bg * KTF_BG + (size_t)dc * VTF_DC + l * 8;
    const unsigned short* arow = &sd[(h * IT_ + (l15 & 3)) * JST + l4 * 8];
    f32x4 acc = (f32x4){0.f, 0.f, 0.f, 0.f};
    for (int jt = 0; jt < nJtE; ++jt){
      half8 af = *(const half8*)(arow + jt * 32);
      half8 vf = *(const half8*)(vbase + (size_t)jt * 512);
      acc = __builtin_amdgcn_mfma_f32_16x16x32_f16(af, vf, acc, 0, 0, 0);
    }
    if (l4 == 0){
      const float hs = hsc[h];
      #pragma unroll
      for (int r = 0; r < IT_; ++r){
        const int irow = (b << 10) | (i0 + r);
        const size_t o = (size_t)irow * 1024 + h * 64 + dc * 16 + l15;
        aout[o] = f2b(acc[r] * hs * h2f(gate[o]));
      }
    }
  }
}

// ---------------- host ----------------
extern "C" void kernel_launch(void* const* d_in, const int* in_sizes, int n_in,
                              void* d_out, int out_size, void* d_ws, size_t ws_size,
                              hipStream_t stream) {
  const float* x     = (const float*)d_in[0];
  const float* Wq    = (const float*)d_in[1];
  const float* Wk    = (const float*)d_in[2];
  const float* Wv    = (const float*)d_in[3];
  const float* Wpre  = (const float*)d_in[4];
  const float* Wpost = (const float*)d_in[5];
  const float* mk    = (const float*)d_in[6];
  const float* mv    = (const float*)d_in[7];
  const float* hsc   = (const float*)d_in[8];
  const float* Wg    = (const float*)d_in[9];
  const float* bg    = (const float*)d_in[10];
  const float* Wo    = (const float*)d_in[11];
  float* out = (float*)d_out;

  char* ws = (char*)d_ws;
  size_t off = 0;
  auto alloc = [&](size_t bytes) -> void* {
    void* p = ws + off; off += (bytes + 255) & ~(size_t)255; return p;
  };
  unsigned short* xb   = (unsigned short*)alloc((size_t)4096 * 1024 * 2);
  unsigned short* wcat = (unsigned short*)alloc((size_t)1024 * 4096 * 2);
  unsigned short* wob  = (unsigned short*)alloc((size_t)1024 * 1024 * 2);
  unsigned short* qn   = (unsigned short*)alloc((size_t)B_ * H_ * N_ * DH_ * 2);   // f16
  unsigned short* ktF  = (unsigned short*)alloc((size_t)B_ * H_ * KTF_BG * 2);     // frag-ordered K
  unsigned short* vtF  = (unsigned short*)alloc((size_t)B_ * H_ * KTF_BG * 2);     // frag-ordered V^T
  unsigned short* gate = (unsigned short*)alloc((size_t)4096 * 1024 * 2);          // f16
  unsigned short* aout = (unsigned short*)alloc((size_t)4096 * 1024 * 2);          // bf16

  k_cvtAll<<<2048, 256, 0, stream>>>(x, Wq, Wk, Wv, Wg, Wo, xb, wcat, wob);

  k_mem<<<4, 256, 0, stream>>>(mk, mv, ktF, vtF);

  // bg offset trick: gate epilogue indexes bgv[3*1024 + col]; pass bg - 3*1024 so it reads bg[col]
  k_gemmF<<<dim3(64, 32), 256, 0, stream>>>(xb, wcat, qn, ktF, vtF, gate, bg - 3 * 1024);

  k_attnM<<<1024, 1024, 0, stream>>>(qn, ktF, vtF, Wpre, Wpost, hsc, gate, aout);

  k_gemmO<<<dim3(16, 32), 256, 0, stream>>>(aout, wob, out);
}

// Round 13
// 368.374 us; speedup vs baseline: 1.8753x; 1.0793x over previous
//
#include <hip/hip_runtime.h>
#include <hip/hip_bf16.h>
#include <float.h>

#define B_ 4
#define N_ 1024
#define H_ 16
#define DH_ 64
#define NM_ 4
#define J_ 1028          // N_ + NM_
#define IT_ 4            // i rows per attention block
#define JST 1064         // sd row stride (halves)
#define TOPK_ 64
#define QKSCALE 10.0f
// fragment-ordered K: ktF[bg][jt(66)][f(2)][l(64)][e(8)]  halves; per-bg = 66*1024 = 67584
// fragment-ordered V^T: vtF[bg][dc(4)][jtE(33)][l(64)][e(8)]; per-bg = 4*33*512 = 67584
#define KTF_BG 67584
#define VTF_DC 16896     // 33*512

typedef __attribute__((ext_vector_type(8))) short short8;
typedef __attribute__((ext_vector_type(4))) float f32x4;
typedef __attribute__((ext_vector_type(8))) unsigned short ushort8;
typedef __attribute__((ext_vector_type(4))) unsigned int u32x4;
typedef __attribute__((ext_vector_type(2))) unsigned int u32x2;
typedef _Float16 half8 __attribute__((ext_vector_type(8)));

__device__ __forceinline__ unsigned short f2b(float f){
  union { float f; unsigned int i; } c; c.f = f;
  unsigned int r = c.i + 0x7FFFu + ((c.i >> 16) & 1u);   // RNE
  return (unsigned short)(r >> 16);
}
__device__ __forceinline__ unsigned short f2h(float f){
  return __builtin_bit_cast(unsigned short, (_Float16)f);
}
__device__ __forceinline__ float h2f(unsigned short u){
  return (float)__builtin_bit_cast(_Float16, u);
}
__device__ __forceinline__ unsigned int h2key(unsigned int u){
  return (u & 0x8000u) ? (~u & 0xFFFFu) : (u | 0x8000u);
}
__device__ __forceinline__ float key2f(unsigned int k){
  unsigned int u = (k & 0x8000u) ? (k & 0x7FFFu) : (~k & 0xFFFFu);
  return h2f((unsigned short)u);
}

// ---------------- fused f32 -> bf16 convert: x, [Wq|Wk|Wv|Wg] -> wcat (N=4096), Wo ----------------
__global__ void k_cvtAll(const float* __restrict__ x,  const float* __restrict__ wq,
                         const float* __restrict__ wk, const float* __restrict__ wv,
                         const float* __restrict__ wg, const float* __restrict__ wo,
                         unsigned short* __restrict__ xb, unsigned short* __restrict__ wcat,
                         unsigned short* __restrict__ wob){
  const int NX = 4096 * 1024, NW = 1024 * 1024;
  int i = blockIdx.x * 256 + threadIdx.x;
  int st = gridDim.x * 256;
  for (; i < NX + 5 * NW; i += st){
    if (i < NX){ xb[i] = f2b(x[i]); }
    else {
      int k = i - NX;
      int which = k >> 20, off = k & (NW - 1);
      if (which == 4){ wob[off] = f2b(wo[off]); }
      else {
        const float* s = which == 0 ? wq : which == 1 ? wk : which == 2 ? wv : wg;
        wcat[(size_t)(off >> 10) * 4096 + which * 1024 + (off & 1023)] = f2b(s[off]);
      }
    }
  }
}

// ---------------- memory slots into ktF/vtF + zero pad tiles ----------------
__global__ __launch_bounds__(256) void k_mem(const float* __restrict__ mk, const float* __restrict__ mv,
                                             unsigned short* __restrict__ ktF, unsigned short* __restrict__ vtF){
  int h = blockIdx.x * 4 + (threadIdx.x >> 6);   // 0..15
  int d = threadIdx.x & 63;
  unsigned short kh[4], vh[4];
  #pragma unroll
  for (int mm = 0; mm < 4; ++mm){
    float kv = mk[(h * 4 + mm) * 64 + d];
    float ss = kv * kv;
    #pragma unroll
    for (int off = 32; off; off >>= 1) ss += __shfl_xor(ss, off);
    kh[mm] = f2h(kv / fmaxf(sqrtf(ss), 1e-12f));
    vh[mm] = f2h(mv[(h * 4 + mm) * 64 + d]);
  }
  for (int b = 0; b < B_; ++b){
    int bg = b * 16 + h;
    #pragma unroll
    for (int mm = 0; mm < 4; ++mm)
      ktF[(size_t)bg * KTF_BG + (size_t)(d >> 5) * 512 + (mm + ((d >> 3) & 3) * 16) * 8 + (d & 7)] = kh[mm];
    #pragma unroll
    for (int mm = 0; mm < 4; ++mm)
      vtF[(size_t)bg * KTF_BG + (size_t)(d >> 4) * VTF_DC + (d & 15) * 8 + mm] = vh[mm];
    {
      unsigned int* kz = (unsigned int*)(ktF + (size_t)bg * KTF_BG + 64 * 1024);
      for (int c = d; c < 1024; c += 64) kz[c] = 0u;
    }
    #pragma unroll
    for (int dc = 0; dc < 4; ++dc){
      unsigned int* vz = (unsigned int*)(vtF + (size_t)bg * KTF_BG + (size_t)dc * VTF_DC + 32 * 512);
      for (int c = d; c < 256; c += 64) vz[c] = 0u;
    }
  }
}

// ---------------- fused QKVG GEMM: 4096x4096x1024 (wcat), 128x64 tile, per-which epilogue ----------------
__global__ __launch_bounds__(256) void k_gemmF(const unsigned short* __restrict__ A,
                                               const unsigned short* __restrict__ Wc,
                                               unsigned short* __restrict__ qn,
                                               unsigned short* __restrict__ ktF,
                                               unsigned short* __restrict__ vtF,
                                               unsigned short* __restrict__ gate,
                                               const float* __restrict__ bgv)
{
  __shared__ unsigned short As[128][40];
  __shared__ unsigned short Bs[64][40];
  const int t = threadIdx.x;
  const int m0 = blockIdx.y * 128, n0 = blockIdx.x * 64;
  const int l = t & 63, w = t >> 6;
  const int l15 = l & 15, l4 = l >> 4;

  f32x4 acc[2][4];
  #pragma unroll
  for (int a = 0; a < 2; ++a)
    #pragma unroll
    for (int b2 = 0; b2 < 4; ++b2) acc[a][b2] = (f32x4){0.f, 0.f, 0.f, 0.f};

  for (int k0 = 0; k0 < 1024; k0 += 32){
    #pragma unroll
    for (int cc = 0; cc < 2; ++cc){          // A tile: 128x32
      int c = t + cc * 256;
      int row = c >> 2, colc = (c & 3) * 8;
      *(ushort8*)&As[row][colc] = *(const ushort8*)&A[(m0 + row) * 1024 + k0 + colc];
    }
    {                                        // B tile: 32k x 64n from wcat (stride 4096)
      int kk = t >> 3, nc = (t & 7) * 8;
      ushort8 vb = *(const ushort8*)&Wc[(size_t)(k0 + kk) * 4096 + n0 + nc];
      #pragma unroll
      for (int e = 0; e < 8; ++e) Bs[nc + e][kk] = vb[e];
    }
    __syncthreads();
    short8 af[2], bfr[4];
    #pragma unroll
    for (int mf = 0; mf < 2; ++mf) af[mf]  = *(const short8*)&As[w * 32 + mf * 16 + l15][l4 * 8];
    #pragma unroll
    for (int nf = 0; nf < 4; ++nf) bfr[nf] = *(const short8*)&Bs[nf * 16 + l15][l4 * 8];
    #pragma unroll
    for (int mf = 0; mf < 2; ++mf)
      #pragma unroll
      for (int nf = 0; nf < 4; ++nf)
        acc[mf][nf] = __builtin_amdgcn_mfma_f32_16x16x32_bf16(af[mf], bfr[nf], acc[mf][nf], 0, 0, 0);
    __syncthreads();
  }

  const int which = n0 >> 10;        // 0=q 1=k 2=v 3=gate (uniform per block)
  const int ncol0 = n0 & 1023;
  const int hcol = ncol0 >> 6;
  #pragma unroll
  for (int mf = 0; mf < 2; ++mf){
    if (which == 2){
      int row0 = m0 + w * 32 + mf * 16 + l4 * 4;
      int bb = row0 >> 10;
      int j0 = (row0 & 1023) + NM_;
      int jtE = j0 >> 5, lj = (j0 & 31) >> 3, e0 = j0 & 7;
      #pragma unroll
      for (int nf = 0; nf < 4; ++nf){
        int col = ncol0 + nf * 16 + l15;
        int h = col >> 6, d = col & 63;
        unsigned int lo = (unsigned int)f2h(acc[mf][nf][0]) | ((unsigned int)f2h(acc[mf][nf][1]) << 16);
        unsigned int hi = (unsigned int)f2h(acc[mf][nf][2]) | ((unsigned int)f2h(acc[mf][nf][3]) << 16);
        unsigned short* dst = vtF + (size_t)(bb * 16 + h) * KTF_BG +
                              (size_t)(d >> 4) * VTF_DC + (size_t)jtE * 512 +
                              ((d & 15) + lj * 16) * 8 + e0;
        *(u32x2*)dst = (u32x2){lo, hi};
      }
    } else {
      #pragma unroll
      for (int r = 0; r < 4; ++r){
        int row = m0 + w * 32 + mf * 16 + l4 * 4 + r;
        float rn = 1.f;
        if (which <= 1){
          float ss = 0.f;
          #pragma unroll
          for (int nf = 0; nf < 4; ++nf) ss += acc[mf][nf][r] * acc[mf][nf][r];
          #pragma unroll
          for (int off = 1; off < 16; off <<= 1) ss += __shfl_xor(ss, off);
          rn = 1.f / fmaxf(sqrtf(ss), 1e-12f);
          if (which == 0) rn *= QKSCALE;
        }
        #pragma unroll
        for (int nf = 0; nf < 4; ++nf){
          int col = ncol0 + nf * 16 + l15;
          float v = acc[mf][nf][r];
          int bb = row >> 10, ii = row & 1023;
          if (which == 3){
            float g = v + bgv[3 * 1024 + col];
            gate[(size_t)row * 1024 + col] = f2h(1.f / (1.f + __expf(-g)));
          } else if (which == 0){
            int d = col & 63;
            qn[((size_t)(bb * H_ + hcol) * N_ + ii) * DH_ + d] = f2h(v * rn);
          } else { // which == 1: K -> ktF fragment order
            int j = ii + NM_;
            int d = col & 63;
            ktF[(size_t)(bb * 16 + hcol) * KTF_BG + (size_t)(j >> 4) * 1024 +
                (size_t)(d >> 5) * 512 + ((j & 15) + ((d >> 3) & 3) * 16) * 8 + (d & 7)]
              = f2h(v * rn);
          }
        }
      }
    }
  }
}

// ---------------- final GEMM aout x Wo -> f32 out, 128x64 tile ----------------
__global__ __launch_bounds__(256) void k_gemmO(const unsigned short* __restrict__ A,
                                               const unsigned short* __restrict__ W,
                                               float* __restrict__ outp)
{
  __shared__ unsigned short As[128][40];
  __shared__ unsigned short Bs[64][40];
  const int t = threadIdx.x;
  const int m0 = blockIdx.y * 128, n0 = blockIdx.x * 64;
  const int l = t & 63, w = t >> 6;
  const int l15 = l & 15, l4 = l >> 4;

  f32x4 acc[2][4];
  #pragma unroll
  for (int a = 0; a < 2; ++a)
    #pragma unroll
    for (int b2 = 0; b2 < 4; ++b2) acc[a][b2] = (f32x4){0.f, 0.f, 0.f, 0.f};

  for (int k0 = 0; k0 < 1024; k0 += 32){
    #pragma unroll
    for (int cc = 0; cc < 2; ++cc){
      int c = t + cc * 256;
      int row = c >> 2, colc = (c & 3) * 8;
      *(ushort8*)&As[row][colc] = *(const ushort8*)&A[(m0 + row) * 1024 + k0 + colc];
    }
    {
      int kk = t >> 3, nc = (t & 7) * 8;
      ushort8 vb = *(const ushort8*)&W[(k0 + kk) * 1024 + n0 + nc];
      #pragma unroll
      for (int e = 0; e < 8; ++e) Bs[nc + e][kk] = vb[e];
    }
    __syncthreads();
    short8 af[2], bfr[4];
    #pragma unroll
    for (int mf = 0; mf < 2; ++mf) af[mf]  = *(const short8*)&As[w * 32 + mf * 16 + l15][l4 * 8];
    #pragma unroll
    for (int nf = 0; nf < 4; ++nf) bfr[nf] = *(const short8*)&Bs[nf * 16 + l15][l4 * 8];
    #pragma unroll
    for (int mf = 0; mf < 2; ++mf)
      #pragma unroll
      for (int nf = 0; nf < 4; ++nf)
        acc[mf][nf] = __builtin_amdgcn_mfma_f32_16x16x32_bf16(af[mf], bfr[nf], acc[mf][nf], 0, 0, 0);
    __syncthreads();
  }

  #pragma unroll
  for (int mf = 0; mf < 2; ++mf)
    #pragma unroll
    for (int r = 0; r < 4; ++r){
      int row = m0 + w * 32 + mf * 16 + l4 * 4 + r;
      #pragma unroll
      for (int nf = 0; nf < 4; ++nf)
        outp[(size_t)row * 1024 + n0 + nf * 16 + l15] = acc[mf][nf][r];
    }
}

// ---------------- fused attention, all-MFMA, pipelined A/E ----------------
__global__ __launch_bounds__(1024) void k_attnM(
  const unsigned short* __restrict__ qn, const unsigned short* __restrict__ ktF,
  const unsigned short* __restrict__ vtF, const float* __restrict__ wpre,
  const float* __restrict__ wpost, const float* __restrict__ hsc,
  const unsigned short* __restrict__ gate, unsigned short* __restrict__ aout)
{
  __shared__ unsigned short sd[16 * IT_ * JST]; // 136,192 B: raw -> mixed -> attn
  __shared__ unsigned short qls[16 * 4 * 64];   // 8 KB staged q [g][ii][d]
  __shared__ unsigned short wpre16[16 * 32];
  __shared__ unsigned short wpost16[16 * 32];

  const int blk = blockIdx.x;
  const int b = (blk >> 1) & 3;
  const int idx = ((blk >> 3) << 1) | (blk & 1);
  const int it = 255 - idx;
  const int i0 = it * IT_;
  const int nAmax = i0 + IT_ + 4;
  const int nJtA = (nAmax + 15) >> 4;
  const int nJtE = (nAmax + 31) >> 5;
  const int nJtD = nJtE * 2;
  const int jc = nJtE * 32;            // processing bound for phase C (<= 1056)
  const int t = threadIdx.x;
  const int w = t >> 6, l = t & 63;
  const int l15 = l & 15, l4 = l >> 4;

  if (t < 256){
    int h = t >> 4, g = t & 15;
    wpre16[h * 32 + g]       = f2h(wpre[h * 16 + g]);
    wpre16[h * 32 + 16 + g]  = 0;
    wpost16[h * 32 + g]      = f2h(wpost[h * 16 + g]);
    wpost16[h * 32 + 16 + g] = 0;
  }
  for (int c = t; c < 2048; c += 1024){
    int d2 = c & 31, ii = (c >> 5) & 3, g = c >> 7;
    ((unsigned int*)qls)[c] =
      *(const unsigned int*)(qn + ((size_t)(b * 16 + g) * N_ + i0 + ii) * 64 + d2 * 2);
  }
  __syncthreads();

  // ---- phase A: raw dots, software-pipelined (2-task depth over flattened (jt,g)) ----
  {
    const int nw16 = (nJtA > w) ? ((nJtA - w + 15) >> 4) : 0;
    const int ntask = nw16 * 16;                    // multiple of 16 (even)
    if (ntask > 0){
      const int tmax = ntask - 1;
      const unsigned short* kl = ktF + (size_t)(b * 16) * KTF_BG + (size_t)l * 8;
      auto kp = [&](int task)->const unsigned short*{
        int tt = task > tmax ? tmax : task;
        int g = tt & 15, jti = tt >> 4;
        return kl + (size_t)g * KTF_BG + (((size_t)(w + jti * 16)) << 10);
      };
      const unsigned short* p0 = kp(0);
      const unsigned short* p1 = kp(1);
      half8 kA0 = *(const half8*)p0, kA1 = *(const half8*)(p0 + 512);
      half8 kB0 = *(const half8*)p1, kB1 = *(const half8*)(p1 + 512);
      for (int task = 0; task < ntask; task += 2){
        half8 cA0 = kA0, cA1 = kA1, cB0 = kB0, cB1 = kB1;
        const unsigned short* pa = kp(task + 2);
        const unsigned short* pb = kp(task + 3);
        kA0 = *(const half8*)pa; kA1 = *(const half8*)(pa + 512);
        kB0 = *(const half8*)pb; kB1 = *(const half8*)(pb + 512);
        #pragma unroll
        for (int s = 0; s < 2; ++s){
          const int tt = task + s;
          const int g = tt & 15, jt = w + ((tt >> 4) << 4);
          const unsigned short* qp = &qls[(g * 4 + (l15 & 3)) * 64 + l4 * 8];
          half8 qf0 = *(const half8*)(qp);
          half8 qf1 = *(const half8*)(qp + 32);
          f32x4 acc = (f32x4){0.f, 0.f, 0.f, 0.f};
          acc = __builtin_amdgcn_mfma_f32_16x16x32_f16(s ? cB0 : cA0, qf0, acc, 0, 0, 0);
          acc = __builtin_amdgcn_mfma_f32_16x16x32_f16(s ? cB1 : cA1, qf1, acc, 0, 0, 0);
          if (l15 < IT_){
            unsigned int pk0 = (unsigned int)f2h(acc[0]) | ((unsigned int)f2h(acc[1]) << 16);
            unsigned int pk1 = (unsigned int)f2h(acc[2]) | ((unsigned int)f2h(acc[3]) << 16);
            unsigned int* dst = (unsigned int*)&sd[(g * IT_ + l15) * JST + jt * 16 + l4 * 4];
            dst[0] = pk0; dst[1] = pk1;
          }
        }
      }
    }
  }
  __syncthreads();

  // ---- phase B: W_pre premix via MFMA, in-place per (ii, jt16) patch ----
  {
    half8 wa = *(const half8*)&wpre16[l15 * 32 + l4 * 8];
    const int ntask = IT_ * nJtA;
    for (int task = w; task < ntask; task += 16){
      const int ii = task & (IT_ - 1), jt = task >> 2;
      unsigned int fb[4] = {0u, 0u, 0u, 0u};
      if (l4 < 2){
        const unsigned short* src = &sd[((l4 * 8) * IT_ + ii) * JST + jt * 16 + l15];
        #pragma unroll
        for (int e = 0; e < 8; e += 2){
          unsigned int lo = src[(size_t)(e)     * IT_ * JST];
          unsigned int hi = src[(size_t)(e + 1) * IT_ * JST];
          fb[e >> 1] = (lo & 0xFFFFu) | (hi << 16);
        }
      }
      f32x4 acc = (f32x4){0.f, 0.f, 0.f, 0.f};
      acc = __builtin_amdgcn_mfma_f32_16x16x32_f16(wa, __builtin_bit_cast(half8, *(u32x4*)fb), acc, 0, 0, 0);
      #pragma unroll
      for (int r = 0; r < 4; ++r)
        sd[((l4 * 4 + r) * IT_ + ii) * JST + jt * 16 + l15] = f2h(acc[r]);
    }
  }
  __syncthreads();

  // ---- phase C: per-row top-64 threshold + softmax, causal-trimmed to jc ----
  for (int rr = 0; rr < 4; ++rr){
    const int row = w * 4 + rr;            // 0..63
    const int g = row >> 2, ii = row & 3;
    const int nA = i0 + ii + 5;
    unsigned short* rowp = &sd[(g * IT_ + ii) * JST];
    unsigned int kw[9];
    #pragma unroll
    for (int grp = 0; grp < 9; ++grp){
      kw[grp] = 0u;
      if (grp * 128 < jc){
        int j = grp * 128 + l * 2;
        unsigned int u = (j < JST) ? *(const unsigned int*)(rowp + j) : 0u;
        unsigned int klo = h2key(u & 0xFFFFu);
        unsigned int khi = h2key(u >> 16);
        if (j     >= nA) klo = 0u;
        if (j + 1 >= nA) khi = 0u;
        kw[grp] = klo | (khi << 16);
      }
    }
    unsigned int kmx = 0u;
    #pragma unroll
    for (int grp = 0; grp < 9; ++grp){
      if (grp * 128 < jc){
        unsigned int m2 = max(kw[grp] >> 16, kw[grp] & 0xFFFFu);
        kmx = max(kmx, m2);
      }
    }
    #pragma unroll
    for (int off = 32; off; off >>= 1) kmx = max(kmx, (unsigned int)__shfl_xor((int)kmx, off));
    const float mx = key2f(kmx);

    unsigned int T = 0u;
    if (nA > TOPK_){
      for (int bit = 15; bit >= 2; --bit){
        unsigned int Tc = T | (1u << bit);
        int c = 0;
        #pragma unroll
        for (int grp = 0; grp < 9; ++grp){
          if (grp * 128 < jc){
            c += __popcll(__ballot((kw[grp] & 0xFFFFu) >= Tc));
            c += __popcll(__ballot((kw[grp] >> 16) >= Tc));
          }
        }
        if (c >= TOPK_){
          T = Tc;
          if (c == TOPK_) break;
        }
      }
    }
    if (T == 0u) T = 1u;

    float s = 0.f;
    float ev[18];
    #pragma unroll
    for (int grp = 0; grp < 9; ++grp){
      if (grp * 128 < jc){
        unsigned int klo = kw[grp] & 0xFFFFu, khi = kw[grp] >> 16;
        float elo = (klo >= T) ? __expf(key2f(klo) - mx) : 0.f;
        float ehi = (khi >= T) ? __expf(key2f(khi) - mx) : 0.f;
        ev[grp * 2] = elo; ev[grp * 2 + 1] = ehi;
        s += elo + ehi;
      }
    }
    #pragma unroll
    for (int off = 32; off; off >>= 1) s += __shfl_xor(s, off);
    float inv = 1.f / s;
    #pragma unroll
    for (int grp = 0; grp < 9; ++grp){
      if (grp * 128 < jc){
        int j = grp * 128 + l * 2;
        if (j < JST)
          *(unsigned int*)(rowp + j) =
            (unsigned int)f2h(ev[grp * 2] * inv) | ((unsigned int)f2h(ev[grp * 2 + 1] * inv) << 16);
      }
    }
  }
  __syncthreads();

  // ---- phase D: postmix via MFMA (causal-trimmed) ----
  {
    const int ntask = IT_ * nJtD;
    for (int task = w; task < ntask; task += 16){
      const int ii = task & (IT_ - 1), jt = task >> 2;
      half8 wa = *(const half8*)&wpost16[l15 * 32 + l4 * 8];
      unsigned int fb[4] = {0u, 0u, 0u, 0u};
      if (l4 < 2){
        const unsigned short* src = &sd[((l4 * 8) * IT_ + ii) * JST + jt * 16 + l15];
        #pragma unroll
        for (int e = 0; e < 8; e += 2){
          unsigned int lo = src[(size_t)(e)     * IT_ * JST];
          unsigned int hi = src[(size_t)(e + 1) * IT_ * JST];
          fb[e >> 1] = (lo & 0xFFFFu) | (hi << 16);
        }
      }
      f32x4 acc = (f32x4){0.f, 0.f, 0.f, 0.f};
      acc = __builtin_amdgcn_mfma_f32_16x16x32_f16(wa, __builtin_bit_cast(half8, *(u32x4*)fb), acc, 0, 0, 0);
      #pragma unroll
      for (int r = 0; r < 4; ++r)
        sd[((l4 * 4 + r) * IT_ + ii) * JST + jt * 16 + l15] = f2h(acc[r]);
    }
  }
  __syncthreads();

  // ---- phase E: PV via MFMA, software-pipelined V prefetch (2-deep) ----
  for (int task = w; task < 64; task += 16){
    const int h = task >> 2, dc = task & 3;
    const int bg = b * 16 + h;
    const unsigned short* vbase = vtF + (size_t)bg * KTF_BG + (size_t)dc * VTF_DC + (size_t)l * 8;
    const unsigned short* arow = &sd[(h * IT_ + (l15 & 3)) * JST + l4 * 8];
    const int jm = nJtE - 1;
    auto vp_ = [&](int jt)->const half8*{
      int tt = jt > jm ? jm : jt;
      return (const half8*)(vbase + ((size_t)tt << 9));
    };
    half8 vA = *vp_(0), vB = *vp_(1);
    f32x4 acc = (f32x4){0.f, 0.f, 0.f, 0.f};
    int jt = 0;
    for (; jt + 2 <= nJtE; jt += 2){
      half8 cA = vA, cB = vB;
      vA = *vp_(jt + 2); vB = *vp_(jt + 3);
      half8 af0 = *(const half8*)(arow + jt * 32);
      half8 af1 = *(const half8*)(arow + jt * 32 + 32);
      acc = __builtin_amdgcn_mfma_f32_16x16x32_f16(af0, cA, acc, 0, 0, 0);
      acc = __builtin_amdgcn_mfma_f32_16x16x32_f16(af1, cB, acc, 0, 0, 0);
    }
    if (jt < nJtE){
      half8 af0 = *(const half8*)(arow + jt * 32);
      acc = __builtin_amdgcn_mfma_f32_16x16x32_f16(af0, vA, acc, 0, 0, 0);
    }
    if (l4 == 0){
      const float hs = hsc[h];
      #pragma unroll
      for (int r = 0; r < IT_; ++r){
        const int irow = (b << 10) | (i0 + r);
        const size_t o = (size_t)irow * 1024 + h * 64 + dc * 16 + l15;
        aout[o] = f2b(acc[r] * hs * h2f(gate[o]));
      }
    }
  }
}

// ---------------- host ----------------
extern "C" void kernel_launch(void* const* d_in, const int* in_sizes, int n_in,
                              void* d_out, int out_size, void* d_ws, size_t ws_size,
                              hipStream_t stream) {
  const float* x     = (const float*)d_in[0];
  const float* Wq    = (const float*)d_in[1];
  const float* Wk    = (const float*)d_in[2];
  const float* Wv    = (const float*)d_in[3];
  const float* Wpre  = (const float*)d_in[4];
  const float* Wpost = (const float*)d_in[5];
  const float* mk    = (const float*)d_in[6];
  const float* mv    = (const float*)d_in[7];
  const float* hsc   = (const float*)d_in[8];
  const float* Wg    = (const float*)d_in[9];
  const float* bg    = (const float*)d_in[10];
  const float* Wo    = (const float*)d_in[11];
  float* out = (float*)d_out;

  char* ws = (char*)d_ws;
  size_t off = 0;
  auto alloc = [&](size_t bytes) -> void* {
    void* p = ws + off; off += (bytes + 255) & ~(size_t)255; return p;
  };
  unsigned short* xb   = (unsigned short*)alloc((size_t)4096 * 1024 * 2);
  unsigned short* wcat = (unsigned short*)alloc((size_t)1024 * 4096 * 2);
  unsigned short* wob  = (unsigned short*)alloc((size_t)1024 * 1024 * 2);
  unsigned short* qn   = (unsigned short*)alloc((size_t)B_ * H_ * N_ * DH_ * 2);   // f16
  unsigned short* ktF  = (unsigned short*)alloc((size_t)B_ * H_ * KTF_BG * 2);     // frag-ordered K
  unsigned short* vtF  = (unsigned short*)alloc((size_t)B_ * H_ * KTF_BG * 2);     // frag-ordered V^T
  unsigned short* gate = (unsigned short*)alloc((size_t)4096 * 1024 * 2);          // f16
  unsigned short* aout = (unsigned short*)alloc((size_t)4096 * 1024 * 2);          // bf16

  k_cvtAll<<<2048, 256, 0, stream>>>(x, Wq, Wk, Wv, Wg, Wo, xb, wcat, wob);

  k_mem<<<4, 256, 0, stream>>>(mk, mv, ktF, vtF);

  // bg offset trick: gate epilogue indexes bgv[3*1024 + col]; pass bg - 3*1024 so it reads bg[col]
  k_gemmF<<<dim3(64, 32), 256, 0, stream>>>(xb, wcat, qn, ktF, vtF, gate, bg - 3 * 1024);

  k_attnM<<<1024, 1024, 0, stream>>>(qn, ktF, vtF, Wpre, Wpost, hsc, gate, aout);

  k_gemmO<<<dim3(16, 32), 256, 0, stream>>>(aout, wob, out);
}

// Round 14
// 360.152 us; speedup vs baseline: 1.9181x; 1.0228x over previous
//
#include <hip/hip_runtime.h>
#include <hip/hip_bf16.h>
#include <float.h>

#define B_ 4
#define N_ 1024
#define H_ 16
#define DH_ 64
#define NM_ 4
#define J_ 1028          // N_ + NM_
#define IT_ 4            // i rows per attention block
#define JST 1064         // sd row stride (halves)
#define TOPK_ 64
#define QKSCALE 10.0f
// fragment-ordered K: ktF[bg][jt(66)][f(2)][l(64)][e(8)]  halves; per-bg = 66*1024 = 67584
// fragment-ordered V^T: vtF[bg][dc(4)][jtE(33)][l(64)][e(8)]; per-bg = 4*33*512 = 67584
#define KTF_BG 67584
#define VTF_DC 16896     // 33*512

typedef __attribute__((ext_vector_type(8))) short short8;
typedef __attribute__((ext_vector_type(4))) float f32x4;
typedef __attribute__((ext_vector_type(8))) unsigned short ushort8;
typedef __attribute__((ext_vector_type(4))) unsigned int u32x4;
typedef __attribute__((ext_vector_type(2))) unsigned int u32x2;
typedef _Float16 half8 __attribute__((ext_vector_type(8)));

__device__ __forceinline__ unsigned short f2b(float f){
  union { float f; unsigned int i; } c; c.f = f;
  unsigned int r = c.i + 0x7FFFu + ((c.i >> 16) & 1u);   // RNE
  return (unsigned short)(r >> 16);
}
__device__ __forceinline__ unsigned short f2h(float f){
  return __builtin_bit_cast(unsigned short, (_Float16)f);
}
__device__ __forceinline__ float h2f(unsigned short u){
  return (float)__builtin_bit_cast(_Float16, u);
}
__device__ __forceinline__ unsigned int h2key(unsigned int u){
  return (u & 0x8000u) ? (~u & 0xFFFFu) : (u | 0x8000u);
}
__device__ __forceinline__ float key2f(unsigned int k){
  unsigned int u = (k & 0x8000u) ? (k & 0x7FFFu) : (~k & 0xFFFFu);
  return h2f((unsigned short)u);
}

// ---- fused f32 -> bf16 convert (x, [Wq|Wk|Wv|Wg] -> wcat, Wo) + memory-slot prep (tail blocks) ----
__global__ void k_cvtAll(const float* __restrict__ x,  const float* __restrict__ wq,
                         const float* __restrict__ wk, const float* __restrict__ wv,
                         const float* __restrict__ wg, const float* __restrict__ wo,
                         unsigned short* __restrict__ xb, unsigned short* __restrict__ wcat,
                         unsigned short* __restrict__ wob,
                         const float* __restrict__ mk, const float* __restrict__ mv,
                         unsigned short* __restrict__ ktF, unsigned short* __restrict__ vtF){
  const int NX = 4096 * 1024, NW = 1024 * 1024;
  if (blockIdx.x >= 2044){
    // ---- memory-slot prep: normalize mem_k, seed slots, zero pad tiles ----
    int h = (blockIdx.x - 2044) * 4 + (threadIdx.x >> 6);   // 0..15
    int d = threadIdx.x & 63;
    unsigned short kh[4], vh[4];
    #pragma unroll
    for (int mm = 0; mm < 4; ++mm){
      float kv = mk[(h * 4 + mm) * 64 + d];
      float ss = kv * kv;
      #pragma unroll
      for (int off = 32; off; off >>= 1) ss += __shfl_xor(ss, off);
      kh[mm] = f2h(kv / fmaxf(sqrtf(ss), 1e-12f));
      vh[mm] = f2h(mv[(h * 4 + mm) * 64 + d]);
    }
    for (int b = 0; b < B_; ++b){
      int bg = b * 16 + h;
      #pragma unroll
      for (int mm = 0; mm < 4; ++mm)
        ktF[(size_t)bg * KTF_BG + (size_t)(d >> 5) * 512 + (mm + ((d >> 3) & 3) * 16) * 8 + (d & 7)] = kh[mm];
      #pragma unroll
      for (int mm = 0; mm < 4; ++mm)
        vtF[(size_t)bg * KTF_BG + (size_t)(d >> 4) * VTF_DC + (d & 15) * 8 + mm] = vh[mm];
      {
        unsigned int* kz = (unsigned int*)(ktF + (size_t)bg * KTF_BG + 64 * 1024);
        for (int c = d; c < 1024; c += 64) kz[c] = 0u;
      }
      #pragma unroll
      for (int dc = 0; dc < 4; ++dc){
        unsigned int* vz = (unsigned int*)(vtF + (size_t)bg * KTF_BG + (size_t)dc * VTF_DC + 32 * 512);
        for (int c = d; c < 256; c += 64) vz[c] = 0u;
      }
    }
    return;
  }
  int i = blockIdx.x * 256 + threadIdx.x;
  const int st = 2044 * 256;
  for (; i < NX + 5 * NW; i += st){
    if (i < NX){ xb[i] = f2b(x[i]); }
    else {
      int k = i - NX;
      int which = k >> 20, off = k & (NW - 1);
      if (which == 4){ wob[off] = f2b(wo[off]); }
      else {
        const float* s = which == 0 ? wq : which == 1 ? wk : which == 2 ? wv : wg;
        wcat[(size_t)(off >> 10) * 4096 + which * 1024 + (off & 1023)] = f2b(s[off]);
      }
    }
  }
}

// ---------------- fused QKVG GEMM: 4096x4096x1024 (wcat), 128x64 tile, BK=64 ----------------
__global__ __launch_bounds__(256) void k_gemmF(const unsigned short* __restrict__ A,
                                               const unsigned short* __restrict__ Wc,
                                               unsigned short* __restrict__ qn,
                                               unsigned short* __restrict__ ktF,
                                               unsigned short* __restrict__ vtF,
                                               unsigned short* __restrict__ gate,
                                               const float* __restrict__ bgv)
{
  __shared__ unsigned short As[128][72];
  __shared__ unsigned short Bs[64][72];
  const int t = threadIdx.x;
  const int m0 = blockIdx.y * 128, n0 = blockIdx.x * 64;
  const int l = t & 63, w = t >> 6;
  const int l15 = l & 15, l4 = l >> 4;

  f32x4 acc[2][4];
  #pragma unroll
  for (int a = 0; a < 2; ++a)
    #pragma unroll
    for (int b2 = 0; b2 < 4; ++b2) acc[a][b2] = (f32x4){0.f, 0.f, 0.f, 0.f};

  for (int k0 = 0; k0 < 1024; k0 += 64){
    #pragma unroll
    for (int cc = 0; cc < 4; ++cc){          // A tile: 128x64
      int c = t + cc * 256;
      int row = c >> 3, colc = (c & 7) * 8;
      *(ushort8*)&As[row][colc] = *(const ushort8*)&A[(m0 + row) * 1024 + k0 + colc];
    }
    #pragma unroll
    for (int cc = 0; cc < 2; ++cc){          // B tile: 64k x 64n (transposed store)
      int c = t + cc * 256;
      int kk = c >> 3, nc = (c & 7) * 8;
      ushort8 vb = *(const ushort8*)&Wc[(size_t)(k0 + kk) * 4096 + n0 + nc];
      #pragma unroll
      for (int e = 0; e < 8; ++e) Bs[nc + e][kk] = vb[e];
    }
    __syncthreads();
    #pragma unroll
    for (int ks = 0; ks < 64; ks += 32){
      short8 af[2], bfr[4];
      #pragma unroll
      for (int mf = 0; mf < 2; ++mf) af[mf]  = *(const short8*)&As[w * 32 + mf * 16 + l15][ks + l4 * 8];
      #pragma unroll
      for (int nf = 0; nf < 4; ++nf) bfr[nf] = *(const short8*)&Bs[nf * 16 + l15][ks + l4 * 8];
      #pragma unroll
      for (int mf = 0; mf < 2; ++mf)
        #pragma unroll
        for (int nf = 0; nf < 4; ++nf)
          acc[mf][nf] = __builtin_amdgcn_mfma_f32_16x16x32_bf16(af[mf], bfr[nf], acc[mf][nf], 0, 0, 0);
    }
    __syncthreads();
  }

  const int which = n0 >> 10;        // 0=q 1=k 2=v 3=gate (uniform per block)
  const int ncol0 = n0 & 1023;
  const int hcol = ncol0 >> 6;
  #pragma unroll
  for (int mf = 0; mf < 2; ++mf){
    if (which == 2){
      int row0 = m0 + w * 32 + mf * 16 + l4 * 4;
      int bb = row0 >> 10;
      int j0 = (row0 & 1023) + NM_;
      int jtE = j0 >> 5, lj = (j0 & 31) >> 3, e0 = j0 & 7;
      #pragma unroll
      for (int nf = 0; nf < 4; ++nf){
        int col = ncol0 + nf * 16 + l15;
        int h = col >> 6, d = col & 63;
        unsigned int lo = (unsigned int)f2h(acc[mf][nf][0]) | ((unsigned int)f2h(acc[mf][nf][1]) << 16);
        unsigned int hi = (unsigned int)f2h(acc[mf][nf][2]) | ((unsigned int)f2h(acc[mf][nf][3]) << 16);
        unsigned short* dst = vtF + (size_t)(bb * 16 + h) * KTF_BG +
                              (size_t)(d >> 4) * VTF_DC + (size_t)jtE * 512 +
                              ((d & 15) + lj * 16) * 8 + e0;
        *(u32x2*)dst = (u32x2){lo, hi};
      }
    } else {
      #pragma unroll
      for (int r = 0; r < 4; ++r){
        int row = m0 + w * 32 + mf * 16 + l4 * 4 + r;
        float rn = 1.f;
        if (which <= 1){
          float ss = 0.f;
          #pragma unroll
          for (int nf = 0; nf < 4; ++nf) ss += acc[mf][nf][r] * acc[mf][nf][r];
          #pragma unroll
          for (int off = 1; off < 16; off <<= 1) ss += __shfl_xor(ss, off);
          rn = 1.f / fmaxf(sqrtf(ss), 1e-12f);
          if (which == 0) rn *= QKSCALE;
        }
        #pragma unroll
        for (int nf = 0; nf < 4; ++nf){
          int col = ncol0 + nf * 16 + l15;
          float v = acc[mf][nf][r];
          int bb = row >> 10, ii = row & 1023;
          if (which == 3){
            float g = v + bgv[3 * 1024 + col];
            gate[(size_t)row * 1024 + col] = f2h(1.f / (1.f + __expf(-g)));
          } else if (which == 0){
            int d = col & 63;
            qn[((size_t)(bb * H_ + hcol) * N_ + ii) * DH_ + d] = f2h(v * rn);
          } else { // which == 1: K -> ktF fragment order
            int j = ii + NM_;
            int d = col & 63;
            ktF[(size_t)(bb * 16 + hcol) * KTF_BG + (size_t)(j >> 4) * 1024 +
                (size_t)(d >> 5) * 512 + ((j & 15) + ((d >> 3) & 3) * 16) * 8 + (d & 7)]
              = f2h(v * rn);
          }
        }
      }
    }
  }
}

// ---------------- final GEMM aout x Wo -> f32 out, 128x64 tile, BK=64 ----------------
__global__ __launch_bounds__(256) void k_gemmO(const unsigned short* __restrict__ A,
                                               const unsigned short* __restrict__ W,
                                               float* __restrict__ outp)
{
  __shared__ unsigned short As[128][72];
  __shared__ unsigned short Bs[64][72];
  const int t = threadIdx.x;
  const int m0 = blockIdx.y * 128, n0 = blockIdx.x * 64;
  const int l = t & 63, w = t >> 6;
  const int l15 = l & 15, l4 = l >> 4;

  f32x4 acc[2][4];
  #pragma unroll
  for (int a = 0; a < 2; ++a)
    #pragma unroll
    for (int b2 = 0; b2 < 4; ++b2) acc[a][b2] = (f32x4){0.f, 0.f, 0.f, 0.f};

  for (int k0 = 0; k0 < 1024; k0 += 64){
    #pragma unroll
    for (int cc = 0; cc < 4; ++cc){
      int c = t + cc * 256;
      int row = c >> 3, colc = (c & 7) * 8;
      *(ushort8*)&As[row][colc] = *(const ushort8*)&A[(m0 + row) * 1024 + k0 + colc];
    }
    #pragma unroll
    for (int cc = 0; cc < 2; ++cc){
      int c = t + cc * 256;
      int kk = c >> 3, nc = (c & 7) * 8;
      ushort8 vb = *(const ushort8*)&W[(size_t)(k0 + kk) * 1024 + n0 + nc];
      #pragma unroll
      for (int e = 0; e < 8; ++e) Bs[nc + e][kk] = vb[e];
    }
    __syncthreads();
    #pragma unroll
    for (int ks = 0; ks < 64; ks += 32){
      short8 af[2], bfr[4];
      #pragma unroll
      for (int mf = 0; mf < 2; ++mf) af[mf]  = *(const short8*)&As[w * 32 + mf * 16 + l15][ks + l4 * 8];
      #pragma unroll
      for (int nf = 0; nf < 4; ++nf) bfr[nf] = *(const short8*)&Bs[nf * 16 + l15][ks + l4 * 8];
      #pragma unroll
      for (int mf = 0; mf < 2; ++mf)
        #pragma unroll
        for (int nf = 0; nf < 4; ++nf)
          acc[mf][nf] = __builtin_amdgcn_mfma_f32_16x16x32_bf16(af[mf], bfr[nf], acc[mf][nf], 0, 0, 0);
    }
    __syncthreads();
  }

  #pragma unroll
  for (int mf = 0; mf < 2; ++mf)
    #pragma unroll
    for (int r = 0; r < 4; ++r){
      int row = m0 + w * 32 + mf * 16 + l4 * 4 + r;
      #pragma unroll
      for (int nf = 0; nf < 4; ++nf)
        outp[(size_t)row * 1024 + n0 + nf * 16 + l15] = acc[mf][nf][r];
    }
}

// ---------------- fused attention, all-MFMA, pipelined A/E, balanced CU mapping ----------------
__global__ __launch_bounds__(1024) void k_attnM(
  const unsigned short* __restrict__ qn, const unsigned short* __restrict__ ktF,
  const unsigned short* __restrict__ vtF, const float* __restrict__ wpre,
  const float* __restrict__ wpost, const float* __restrict__ hsc,
  const unsigned short* __restrict__ gate, unsigned short* __restrict__ aout)
{
  __shared__ unsigned short sd[16 * IT_ * JST]; // 136,192 B: raw -> mixed -> attn
  __shared__ unsigned short qls[16 * 4 * 64];   // 8 KB staged q [g][ii][d]
  __shared__ unsigned short wpre16[16 * 32];
  __shared__ unsigned short wpost16[16 * 32];

  const int blk = blockIdx.x;
  const int b = (blk >> 1) & 3;                  // fixed per XCD pair (blk%8 -> XCD)
  const int idx = ((blk >> 3) << 1) | (blk & 1); // 0..255 within pair
  // boustrophedon rounds: per-CU it sums are constant (= 510)
  const int rd = idx >> 6, jj = idx & 63;
  const int it = (rd == 0) ? (255 - jj) : (rd == 1) ? (128 + jj) : (rd == 2) ? (127 - jj) : jj;
  const int i0 = it * IT_;
  const int nAmax = i0 + IT_ + 4;
  const int nJtA = (nAmax + 15) >> 4;
  const int nJtE = (nAmax + 31) >> 5;
  const int nJtD = nJtE * 2;
  const int jc = nJtE * 32;            // processing bound for phase C (<= 1056)
  const int t = threadIdx.x;
  const int w = t >> 6, l = t & 63;
  const int l15 = l & 15, l4 = l >> 4;

  if (t < 256){
    int h = t >> 4, g = t & 15;
    wpre16[h * 32 + g]       = f2h(wpre[h * 16 + g]);
    wpre16[h * 32 + 16 + g]  = 0;
    wpost16[h * 32 + g]      = f2h(wpost[h * 16 + g]);
    wpost16[h * 32 + 16 + g] = 0;
  }
  for (int c = t; c < 2048; c += 1024){
    int d2 = c & 31, ii = (c >> 5) & 3, g = c >> 7;
    ((unsigned int*)qls)[c] =
      *(const unsigned int*)(qn + ((size_t)(b * 16 + g) * N_ + i0 + ii) * 64 + d2 * 2);
  }
  __syncthreads();

  // ---- phase A: raw dots, software-pipelined (2-task depth over flattened (jt,g)) ----
  {
    const int nw16 = (nJtA > w) ? ((nJtA - w + 15) >> 4) : 0;
    const int ntask = nw16 * 16;                    // multiple of 16 (even)
    if (ntask > 0){
      const int tmax = ntask - 1;
      const unsigned short* kl = ktF + (size_t)(b * 16) * KTF_BG + (size_t)l * 8;
      auto kp = [&](int task)->const unsigned short*{
        int tt = task > tmax ? tmax : task;
        int g = tt & 15, jti = tt >> 4;
        return kl + (size_t)g * KTF_BG + (((size_t)(w + jti * 16)) << 10);
      };
      const unsigned short* p0 = kp(0);
      const unsigned short* p1 = kp(1);
      half8 kA0 = *(const half8*)p0, kA1 = *(const half8*)(p0 + 512);
      half8 kB0 = *(const half8*)p1, kB1 = *(const half8*)(p1 + 512);
      for (int task = 0; task < ntask; task += 2){
        half8 cA0 = kA0, cA1 = kA1, cB0 = kB0, cB1 = kB1;
        const unsigned short* pa = kp(task + 2);
        const unsigned short* pb = kp(task + 3);
        kA0 = *(const half8*)pa; kA1 = *(const half8*)(pa + 512);
        kB0 = *(const half8*)pb; kB1 = *(const half8*)(pb + 512);
        #pragma unroll
        for (int s = 0; s < 2; ++s){
          const int tt = task + s;
          const int g = tt & 15, jt = w + ((tt >> 4) << 4);
          const unsigned short* qp = &qls[(g * 4 + (l15 & 3)) * 64 + l4 * 8];
          half8 qf0 = *(const half8*)(qp);
          half8 qf1 = *(const half8*)(qp + 32);
          f32x4 acc = (f32x4){0.f, 0.f, 0.f, 0.f};
          acc = __builtin_amdgcn_mfma_f32_16x16x32_f16(s ? cB0 : cA0, qf0, acc, 0, 0, 0);
          acc = __builtin_amdgcn_mfma_f32_16x16x32_f16(s ? cB1 : cA1, qf1, acc, 0, 0, 0);
          if (l15 < IT_){
            unsigned int pk0 = (unsigned int)f2h(acc[0]) | ((unsigned int)f2h(acc[1]) << 16);
            unsigned int pk1 = (unsigned int)f2h(acc[2]) | ((unsigned int)f2h(acc[3]) << 16);
            unsigned int* dst = (unsigned int*)&sd[(g * IT_ + l15) * JST + jt * 16 + l4 * 4];
            dst[0] = pk0; dst[1] = pk1;
          }
        }
      }
    }
  }
  __syncthreads();

  // ---- phase B: W_pre premix via MFMA, in-place per (ii, jt16) patch ----
  {
    half8 wa = *(const half8*)&wpre16[l15 * 32 + l4 * 8];
    const int ntask = IT_ * nJtA;
    for (int task = w; task < ntask; task += 16){
      const int ii = task & (IT_ - 1), jt = task >> 2;
      unsigned int fb[4] = {0u, 0u, 0u, 0u};
      if (l4 < 2){
        const unsigned short* src = &sd[((l4 * 8) * IT_ + ii) * JST + jt * 16 + l15];
        #pragma unroll
        for (int e = 0; e < 8; e += 2){
          unsigned int lo = src[(size_t)(e)     * IT_ * JST];
          unsigned int hi = src[(size_t)(e + 1) * IT_ * JST];
          fb[e >> 1] = (lo & 0xFFFFu) | (hi << 16);
        }
      }
      f32x4 acc = (f32x4){0.f, 0.f, 0.f, 0.f};
      acc = __builtin_amdgcn_mfma_f32_16x16x32_f16(wa, __builtin_bit_cast(half8, *(u32x4*)fb), acc, 0, 0, 0);
      #pragma unroll
      for (int r = 0; r < 4; ++r)
        sd[((l4 * 4 + r) * IT_ + ii) * JST + jt * 16 + l15] = f2h(acc[r]);
    }
  }
  __syncthreads();

  // ---- phase C: per-row top-64 threshold + softmax, causal-trimmed to jc ----
  for (int rr = 0; rr < 4; ++rr){
    const int row = w * 4 + rr;            // 0..63
    const int g = row >> 2, ii = row & 3;
    const int nA = i0 + ii + 5;
    unsigned short* rowp = &sd[(g * IT_ + ii) * JST];
    unsigned int kw[9];
    #pragma unroll
    for (int grp = 0; grp < 9; ++grp){
      kw[grp] = 0u;
      if (grp * 128 < jc){
        int j = grp * 128 + l * 2;
        unsigned int u = (j < JST) ? *(const unsigned int*)(rowp + j) : 0u;
        unsigned int klo = h2key(u & 0xFFFFu);
        unsigned int khi = h2key(u >> 16);
        if (j     >= nA) klo = 0u;
        if (j + 1 >= nA) khi = 0u;
        kw[grp] = klo | (khi << 16);
      }
    }
    unsigned int kmx = 0u;
    #pragma unroll
    for (int grp = 0; grp < 9; ++grp){
      if (grp * 128 < jc){
        unsigned int m2 = max(kw[grp] >> 16, kw[grp] & 0xFFFFu);
        kmx = max(kmx, m2);
      }
    }
    #pragma unroll
    for (int off = 32; off; off >>= 1) kmx = max(kmx, (unsigned int)__shfl_xor((int)kmx, off));
    const float mx = key2f(kmx);

    unsigned int T = 0u;
    if (nA > TOPK_){
      for (int bit = 15; bit >= 2; --bit){
        unsigned int Tc = T | (1u << bit);
        int c = 0;
        #pragma unroll
        for (int grp = 0; grp < 9; ++grp){
          if (grp * 128 < jc){
            c += __popcll(__ballot((kw[grp] & 0xFFFFu) >= Tc));
            c += __popcll(__ballot((kw[grp] >> 16) >= Tc));
          }
        }
        if (c >= TOPK_){
          T = Tc;
          if (c == TOPK_) break;
        }
      }
    }
    if (T == 0u) T = 1u;

    float s = 0.f;
    float ev[18];
    #pragma unroll
    for (int grp = 0; grp < 9; ++grp){
      if (grp * 128 < jc){
        unsigned int klo = kw[grp] & 0xFFFFu, khi = kw[grp] >> 16;
        float elo = (klo >= T) ? __expf(key2f(klo) - mx) : 0.f;
        float ehi = (khi >= T) ? __expf(key2f(khi) - mx) : 0.f;
        ev[grp * 2] = elo; ev[grp * 2 + 1] = ehi;
        s += elo + ehi;
      }
    }
    #pragma unroll
    for (int off = 32; off; off >>= 1) s += __shfl_xor(s, off);
    float inv = 1.f / s;
    #pragma unroll
    for (int grp = 0; grp < 9; ++grp){
      if (grp * 128 < jc){
        int j = grp * 128 + l * 2;
        if (j < JST)
          *(unsigned int*)(rowp + j) =
            (unsigned int)f2h(ev[grp * 2] * inv) | ((unsigned int)f2h(ev[grp * 2 + 1] * inv) << 16);
      }
    }
  }
  __syncthreads();

  // ---- phase D: postmix via MFMA (causal-trimmed) ----
  {
    const int ntask = IT_ * nJtD;
    for (int task = w; task < ntask; task += 16){
      const int ii = task & (IT_ - 1), jt = task >> 2;
      half8 wa = *(const half8*)&wpost16[l15 * 32 + l4 * 8];
      unsigned int fb[4] = {0u, 0u, 0u, 0u};
      if (l4 < 2){
        const unsigned short* src = &sd[((l4 * 8) * IT_ + ii) * JST + jt * 16 + l15];
        #pragma unroll
        for (int e = 0; e < 8; e += 2){
          unsigned int lo = src[(size_t)(e)     * IT_ * JST];
          unsigned int hi = src[(size_t)(e + 1) * IT_ * JST];
          fb[e >> 1] = (lo & 0xFFFFu) | (hi << 16);
        }
      }
      f32x4 acc = (f32x4){0.f, 0.f, 0.f, 0.f};
      acc = __builtin_amdgcn_mfma_f32_16x16x32_f16(wa, __builtin_bit_cast(half8, *(u32x4*)fb), acc, 0, 0, 0);
      #pragma unroll
      for (int r = 0; r < 4; ++r)
        sd[((l4 * 4 + r) * IT_ + ii) * JST + jt * 16 + l15] = f2h(acc[r]);
    }
  }
  __syncthreads();

  // ---- phase E: PV via MFMA, software-pipelined V prefetch (2-deep) ----
  for (int task = w; task < 64; task += 16){
    const int h = task >> 2, dc = task & 3;
    const int bg = b * 16 + h;
    const unsigned short* vbase = vtF + (size_t)bg * KTF_BG + (size_t)dc * VTF_DC + (size_t)l * 8;
    const unsigned short* arow = &sd[(h * IT_ + (l15 & 3)) * JST + l4 * 8];
    const int jm = nJtE - 1;
    auto vp_ = [&](int jt)->const half8*{
      int tt = jt > jm ? jm : jt;
      return (const half8*)(vbase + ((size_t)tt << 9));
    };
    half8 vA = *vp_(0), vB = *vp_(1);
    f32x4 acc = (f32x4){0.f, 0.f, 0.f, 0.f};
    int jt = 0;
    for (; jt + 2 <= nJtE; jt += 2){
      half8 cA = vA, cB = vB;
      vA = *vp_(jt + 2); vB = *vp_(jt + 3);
      half8 af0 = *(const half8*)(arow + jt * 32);
      half8 af1 = *(const half8*)(arow + jt * 32 + 32);
      acc = __builtin_amdgcn_mfma_f32_16x16x32_f16(af0, cA, acc, 0, 0, 0);
      acc = __builtin_amdgcn_mfma_f32_16x16x32_f16(af1, cB, acc, 0, 0, 0);
    }
    if (jt < nJtE){
      half8 af0 = *(const half8*)(arow + jt * 32);
      acc = __builtin_amdgcn_mfma_f32_16x16x32_f16(af0, vA, acc, 0, 0, 0);
    }
    if (l4 == 0){
      const float hs = hsc[h];
      #pragma unroll
      for (int r = 0; r < IT_; ++r){
        const int irow = (b << 10) | (i0 + r);
        const size_t o = (size_t)irow * 1024 + h * 64 + dc * 16 + l15;
        aout[o] = f2b(acc[r] * hs * h2f(gate[o]));
      }
    }
  }
}

// ---------------- host ----------------
extern "C" void kernel_launch(void* const* d_in, const int* in_sizes, int n_in,
                              void* d_out, int out_size, void* d_ws, size_t ws_size,
                              hipStream_t stream) {
  const float* x     = (const float*)d_in[0];
  const float* Wq    = (const float*)d_in[1];
  const float* Wk    = (const float*)d_in[2];
  const float* Wv    = (const float*)d_in[3];
  const float* Wpre  = (const float*)d_in[4];
  const float* Wpost = (const float*)d_in[5];
  const float* mk    = (const float*)d_in[6];
  const float* mv    = (const float*)d_in[7];
  const float* hsc   = (const float*)d_in[8];
  const float* Wg    = (const float*)d_in[9];
  const float* bg    = (const float*)d_in[10];
  const float* Wo    = (const float*)d_in[11];
  float* out = (float*)d_out;

  char* ws = (char*)d_ws;
  size_t off = 0;
  auto alloc = [&](size_t bytes) -> void* {
    void* p = ws + off; off += (bytes + 255) & ~(size_t)255; return p;
  };
  unsigned short* xb   = (unsigned short*)alloc((size_t)4096 * 1024 * 2);
  unsigned short* wcat = (unsigned short*)alloc((size_t)1024 * 4096 * 2);
  unsigned short* wob  = (unsigned short*)alloc((size_t)1024 * 1024 * 2);
  unsigned short* qn   = (unsigned short*)alloc((size_t)B_ * H_ * N_ * DH_ * 2);   // f16
  unsigned short* ktF  = (unsigned short*)alloc((size_t)B_ * H_ * KTF_BG * 2);     // frag-ordered K
  unsigned short* vtF  = (unsigned short*)alloc((size_t)B_ * H_ * KTF_BG * 2);     // frag-ordered V^T
  unsigned short* gate = (unsigned short*)alloc((size_t)4096 * 1024 * 2);          // f16
  unsigned short* aout = (unsigned short*)alloc((size_t)4096 * 1024 * 2);          // bf16

  k_cvtAll<<<2048, 256, 0, stream>>>(x, Wq, Wk, Wv, Wg, Wo, xb, wcat, wob,
                                     mk, mv, ktF, vtF);

  // bg offset trick: gate epilogue indexes bgv[3*1024 + col]; pass bg - 3*1024 so it reads bg[col]
  k_gemmF<<<dim3(64, 32), 256, 0, stream>>>(xb, wcat, qn, ktF, vtF, gate, bg - 3 * 1024);

  k_attnM<<<1024, 1024, 0, stream>>>(qn, ktF, vtF, Wpre, Wpost, hsc, gate, aout);

  k_gemmO<<<dim3(16, 32), 256, 0, stream>>>(aout, wob, out);
}

// Round 15
// 318.562 us; speedup vs baseline: 2.1685x; 1.1306x over previous
//
#include <hip/hip_runtime.h>
#include <hip/hip_bf16.h>
#include <float.h>

#define B_ 4
#define N_ 1024
#define H_ 16
#define DH_ 64
#define NM_ 4
#define J_ 1028          // N_ + NM_
#define IT_ 4            // i rows per attention block
#define TOPK_ 64
#define QKSCALE 10.0f
// fragment-ordered K: ktF[bg][jt(66)][f(2)][l(64)][e(8)]  halves; per-bg = 66*1024 = 67584
// fragment-ordered V^T: vtF[bg][dc(4)][jtE(33)][l(64)][e(8)]; per-bg = 4*33*512 = 67584
#define KTF_BG 67584
#define VTF_DC 16896     // 33*512

typedef __attribute__((ext_vector_type(8))) short short8;
typedef __attribute__((ext_vector_type(4))) float f32x4;
typedef __attribute__((ext_vector_type(8))) unsigned short ushort8;
typedef __attribute__((ext_vector_type(4))) unsigned int u32x4;
typedef __attribute__((ext_vector_type(2))) unsigned int u32x2;
typedef _Float16 half8 __attribute__((ext_vector_type(8)));

__device__ __forceinline__ unsigned short f2b(float f){
  union { float f; unsigned int i; } c; c.f = f;
  unsigned int r = c.i + 0x7FFFu + ((c.i >> 16) & 1u);   // RNE
  return (unsigned short)(r >> 16);
}
__device__ __forceinline__ unsigned short f2h(float f){
  return __builtin_bit_cast(unsigned short, (_Float16)f);
}
__device__ __forceinline__ float h2f(unsigned short u){
  return (float)__builtin_bit_cast(_Float16, u);
}
__device__ __forceinline__ unsigned int h2key(unsigned int u){
  return (u & 0x8000u) ? (~u & 0xFFFFu) : (u | 0x8000u);
}
__device__ __forceinline__ float key2f(unsigned int k){
  unsigned int u = (k & 0x8000u) ? (k & 0x7FFFu) : (~k & 0xFFFFu);
  return h2f((unsigned short)u);
}

// ---- fused prep: weight TRANSPOSE+convert (bf16 [n][k]), x convert, memory-slot seed ----
__global__ __launch_bounds__(256) void k_cvtAll(
    const float* __restrict__ x,  const float* __restrict__ wq,
    const float* __restrict__ wk, const float* __restrict__ wv,
    const float* __restrict__ wg, const float* __restrict__ wo,
    unsigned short* __restrict__ xb, unsigned short* __restrict__ wcatT,
    unsigned short* __restrict__ wobT,
    const float* __restrict__ mk, const float* __restrict__ mv,
    unsigned short* __restrict__ ktF, unsigned short* __restrict__ vtF){
  const int t = threadIdx.x;
  const unsigned bid = blockIdx.x;
  if (bid < 1280){
    // ---- weight transpose: 64x64 tile, src [k][n] f32 -> dst [n][k] bf16 ----
    __shared__ unsigned short tile[64][70];
    const int which = bid >> 8;          // 0..4 (q,k,v,g,o)
    const int tl = bid & 255;
    const int tr = tl >> 4, tc = tl & 15;   // k-tile, n-tile
    const float* src = which == 0 ? wq : which == 1 ? wk : which == 2 ? wv : which == 3 ? wg : wo;
    {
      int r = t >> 2, c0 = (t & 3) * 16;
      const float* sp = src + (size_t)(tr * 64 + r) * 1024 + tc * 64 + c0;
      #pragma unroll
      for (int e = 0; e < 16; ++e) tile[r][c0 + e] = f2b(sp[e]);
    }
    __syncthreads();
    {
      int rn = t >> 2, k0 = (t & 3) * 16;
      int n = tc * 64 + rn;
      unsigned short* dp = (which == 4)
        ? wobT + (size_t)n * 1024 + tr * 64 + k0
        : wcatT + ((size_t)which * 1024 + n) * 1024 + tr * 64 + k0;
      ushort8 v0, v1;
      #pragma unroll
      for (int e = 0; e < 8; ++e) v0[e] = tile[k0 + e][rn];
      #pragma unroll
      for (int e = 0; e < 8; ++e) v1[e] = tile[k0 + 8 + e][rn];
      *(ushort8*)dp = v0;
      *(ushort8*)(dp + 8) = v1;
    }
    return;
  }
  if (bid >= 1280 && bid < 1284){
    // ---- memory-slot prep: normalize mem_k, seed slots, zero pad tiles ----
    int h = (bid - 1280) * 4 + (t >> 6);   // 0..15
    int d = t & 63;
    unsigned short kh[4], vh[4];
    #pragma unroll
    for (int mm = 0; mm < 4; ++mm){
      float kv = mk[(h * 4 + mm) * 64 + d];
      float ss = kv * kv;
      #pragma unroll
      for (int off = 32; off; off >>= 1) ss += __shfl_xor(ss, off);
      kh[mm] = f2h(kv / fmaxf(sqrtf(ss), 1e-12f));
      vh[mm] = f2h(mv[(h * 4 + mm) * 64 + d]);
    }
    for (int b = 0; b < B_; ++b){
      int bg = b * 16 + h;
      #pragma unroll
      for (int mm = 0; mm < 4; ++mm)
        ktF[(size_t)bg * KTF_BG + (size_t)(d >> 5) * 512 + (mm + ((d >> 3) & 3) * 16) * 8 + (d & 7)] = kh[mm];
      #pragma unroll
      for (int mm = 0; mm < 4; ++mm)
        vtF[(size_t)bg * KTF_BG + (size_t)(d >> 4) * VTF_DC + (d & 15) * 8 + mm] = vh[mm];
      {
        unsigned int* kz = (unsigned int*)(ktF + (size_t)bg * KTF_BG + 64 * 1024);
        for (int c = d; c < 1024; c += 64) kz[c] = 0u;
      }
      #pragma unroll
      for (int dc = 0; dc < 4; ++dc){
        unsigned int* vz = (unsigned int*)(vtF + (size_t)bg * KTF_BG + (size_t)dc * VTF_DC + 32 * 512);
        for (int c = d; c < 256; c += 64) vz[c] = 0u;
      }
    }
    return;
  }
  // ---- x convert ----
  int i = (bid - 1284) * 256 + t;
  const int st = (3072 - 1284) * 256;
  for (; i < 4096 * 1024; i += st) xb[i] = f2b(x[i]);
}

// ---------------- fused QKVG GEMM: 4096x4096x1024 (wcatT [n][k]), 128x64 tile, BK=64 ----------------
__global__ __launch_bounds__(256) void k_gemmF(const unsigned short* __restrict__ A,
                                               const unsigned short* __restrict__ WcT,
                                               unsigned short* __restrict__ qn,
                                               unsigned short* __restrict__ ktF,
                                               unsigned short* __restrict__ vtF,
                                               unsigned short* __restrict__ gate,
                                               const float* __restrict__ bgv)
{
  __shared__ unsigned short As[128][72];
  __shared__ unsigned short Bs[64][72];
  const int t = threadIdx.x;
  const int m0 = blockIdx.y * 128, n0 = blockIdx.x * 64;
  const int l = t & 63, w = t >> 6;
  const int l15 = l & 15, l4 = l >> 4;

  f32x4 acc[2][4];
  #pragma unroll
  for (int a = 0; a < 2; ++a)
    #pragma unroll
    for (int b2 = 0; b2 < 4; ++b2) acc[a][b2] = (f32x4){0.f, 0.f, 0.f, 0.f};

  for (int k0 = 0; k0 < 1024; k0 += 64){
    #pragma unroll
    for (int cc = 0; cc < 4; ++cc){          // A tile: 128x64
      int c = t + cc * 256;
      int row = c >> 3, colc = (c & 7) * 8;
      *(ushort8*)&As[row][colc] = *(const ushort8*)&A[(m0 + row) * 1024 + k0 + colc];
    }
    #pragma unroll
    for (int cc = 0; cc < 2; ++cc){          // B tile: 64n x 64k, direct row copy
      int c = t + cc * 256;
      int row = c >> 3, colc = (c & 7) * 8;
      *(ushort8*)&Bs[row][colc] = *(const ushort8*)&WcT[(size_t)(n0 + row) * 1024 + k0 + colc];
    }
    __syncthreads();
    #pragma unroll
    for (int ks = 0; ks < 64; ks += 32){
      short8 af[2], bfr[4];
      #pragma unroll
      for (int mf = 0; mf < 2; ++mf) af[mf]  = *(const short8*)&As[w * 32 + mf * 16 + l15][ks + l4 * 8];
      #pragma unroll
      for (int nf = 0; nf < 4; ++nf) bfr[nf] = *(const short8*)&Bs[nf * 16 + l15][ks + l4 * 8];
      #pragma unroll
      for (int mf = 0; mf < 2; ++mf)
        #pragma unroll
        for (int nf = 0; nf < 4; ++nf)
          acc[mf][nf] = __builtin_amdgcn_mfma_f32_16x16x32_bf16(af[mf], bfr[nf], acc[mf][nf], 0, 0, 0);
    }
    __syncthreads();
  }

  const int which = n0 >> 10;        // 0=q 1=k 2=v 3=gate (uniform per block)
  const int ncol0 = n0 & 1023;
  const int hcol = ncol0 >> 6;
  #pragma unroll
  for (int mf = 0; mf < 2; ++mf){
    if (which == 2){
      int row0 = m0 + w * 32 + mf * 16 + l4 * 4;
      int bb = row0 >> 10;
      int j0 = (row0 & 1023) + NM_;
      int jtE = j0 >> 5, lj = (j0 & 31) >> 3, e0 = j0 & 7;
      #pragma unroll
      for (int nf = 0; nf < 4; ++nf){
        int col = ncol0 + nf * 16 + l15;
        int h = col >> 6, d = col & 63;
        unsigned int lo = (unsigned int)f2h(acc[mf][nf][0]) | ((unsigned int)f2h(acc[mf][nf][1]) << 16);
        unsigned int hi = (unsigned int)f2h(acc[mf][nf][2]) | ((unsigned int)f2h(acc[mf][nf][3]) << 16);
        unsigned short* dst = vtF + (size_t)(bb * 16 + h) * KTF_BG +
                              (size_t)(d >> 4) * VTF_DC + (size_t)jtE * 512 +
                              ((d & 15) + lj * 16) * 8 + e0;
        *(u32x2*)dst = (u32x2){lo, hi};
      }
    } else {
      #pragma unroll
      for (int r = 0; r < 4; ++r){
        int row = m0 + w * 32 + mf * 16 + l4 * 4 + r;
        float rn = 1.f;
        if (which <= 1){
          float ss = 0.f;
          #pragma unroll
          for (int nf = 0; nf < 4; ++nf) ss += acc[mf][nf][r] * acc[mf][nf][r];
          #pragma unroll
          for (int off = 1; off < 16; off <<= 1) ss += __shfl_xor(ss, off);
          rn = 1.f / fmaxf(sqrtf(ss), 1e-12f);
          if (which == 0) rn *= QKSCALE;
        }
        #pragma unroll
        for (int nf = 0; nf < 4; ++nf){
          int col = ncol0 + nf * 16 + l15;
          float v = acc[mf][nf][r];
          int bb = row >> 10, ii = row & 1023;
          if (which == 3){
            float g = v + bgv[3 * 1024 + col];
            gate[(size_t)row * 1024 + col] = f2h(1.f / (1.f + __expf(-g)));
          } else if (which == 0){
            int d = col & 63;
            qn[((size_t)(bb * H_ + hcol) * N_ + ii) * DH_ + d] = f2h(v * rn);
          } else { // which == 1: K -> ktF fragment order
            int j = ii + NM_;
            int d = col & 63;
            ktF[(size_t)(bb * 16 + hcol) * KTF_BG + (size_t)(j >> 4) * 1024 +
                (size_t)(d >> 5) * 512 + ((j & 15) + ((d >> 3) & 3) * 16) * 8 + (d & 7)]
              = f2h(v * rn);
          }
        }
      }
    }
  }
}

// ---------------- final GEMM aout x WoT -> f32 out, 128x64 tile, BK=64 ----------------
__global__ __launch_bounds__(256) void k_gemmO(const unsigned short* __restrict__ A,
                                               const unsigned short* __restrict__ WT,
                                               float* __restrict__ outp)
{
  __shared__ unsigned short As[128][72];
  __shared__ unsigned short Bs[64][72];
  const int t = threadIdx.x;
  const int m0 = blockIdx.y * 128, n0 = blockIdx.x * 64;
  const int l = t & 63, w = t >> 6;
  const int l15 = l & 15, l4 = l >> 4;

  f32x4 acc[2][4];
  #pragma unroll
  for (int a = 0; a < 2; ++a)
    #pragma unroll
    for (int b2 = 0; b2 < 4; ++b2) acc[a][b2] = (f32x4){0.f, 0.f, 0.f, 0.f};

  for (int k0 = 0; k0 < 1024; k0 += 64){
    #pragma unroll
    for (int cc = 0; cc < 4; ++cc){
      int c = t + cc * 256;
      int row = c >> 3, colc = (c & 7) * 8;
      *(ushort8*)&As[row][colc] = *(const ushort8*)&A[(m0 + row) * 1024 + k0 + colc];
    }
    #pragma unroll
    for (int cc = 0; cc < 2; ++cc){
      int c = t + cc * 256;
      int row = c >> 3, colc = (c & 7) * 8;
      *(ushort8*)&Bs[row][colc] = *(const ushort8*)&WT[(size_t)(n0 + row) * 1024 + k0 + colc];
    }
    __syncthreads();
    #pragma unroll
    for (int ks = 0; ks < 64; ks += 32){
      short8 af[2], bfr[4];
      #pragma unroll
      for (int mf = 0; mf < 2; ++mf) af[mf]  = *(const short8*)&As[w * 32 + mf * 16 + l15][ks + l4 * 8];
      #pragma unroll
      for (int nf = 0; nf < 4; ++nf) bfr[nf] = *(const short8*)&Bs[nf * 16 + l15][ks + l4 * 8];
      #pragma unroll
      for (int mf = 0; mf < 2; ++mf)
        #pragma unroll
        for (int nf = 0; nf < 4; ++nf)
          acc[mf][nf] = __builtin_amdgcn_mfma_f32_16x16x32_bf16(af[mf], bfr[nf], acc[mf][nf], 0, 0, 0);
    }
    __syncthreads();
  }

  #pragma unroll
  for (int mf = 0; mf < 2; ++mf)
    #pragma unroll
    for (int r = 0; r < 4; ++r){
      int row = m0 + w * 32 + mf * 16 + l4 * 4 + r;
      #pragma unroll
      for (int nf = 0; nf < 4; ++nf)
        outp[(size_t)row * 1024 + n0 + nf * 16 + l15] = acc[mf][nf][r];
    }
}

// ---------------- fused attention, all-MFMA, pipelined A/E, LDS-tiered ----------------
// NJTE_MAX: 33 (it 128..255, ~146KB LDS, 1 blk/CU) or 17 (it 0..127, ~81KB, 2 blk/CU)
template<int NJTE_MAX>
__global__ __launch_bounds__(1024) void k_attnM(
  const unsigned short* __restrict__ qn, const unsigned short* __restrict__ ktF,
  const unsigned short* __restrict__ vtF, const float* __restrict__ wpre,
  const float* __restrict__ wpost, const float* __restrict__ hsc,
  const unsigned short* __restrict__ gate, unsigned short* __restrict__ aout,
  int itBase)
{
  constexpr int JSTT = NJTE_MAX * 32 + 8;      // sd row stride (halves)
  constexpr int NG = (JSTT + 127) / 128;       // phase-C 128-col groups
  __shared__ unsigned short sd[16 * IT_ * JSTT];
  __shared__ unsigned short qls[16 * 4 * 64];
  __shared__ unsigned short wpre16[16 * 32];
  __shared__ unsigned short wpost16[16 * 32];

  const int blk = blockIdx.x;
  const int b = (blk >> 1) & 3;                  // fixed per XCD pair (blk%8 -> XCD)
  const int idx = ((blk >> 3) << 1) | (blk & 1); // 0..127 within tier
  const int it = itBase - idx;                   // big tiles first within tier
  const int i0 = it * IT_;
  const int nAmax = i0 + IT_ + 4;
  const int nJtA = (nAmax + 15) >> 4;
  const int nJtE = (nAmax + 31) >> 5;
  const int nJtD = nJtE * 2;
  const int jc = nJtE * 32;            // processing bound for phase C
  const int t = threadIdx.x;
  const int w = t >> 6, l = t & 63;
  const int l15 = l & 15, l4 = l >> 4;

  if (t < 256){
    int h = t >> 4, g = t & 15;
    wpre16[h * 32 + g]       = f2h(wpre[h * 16 + g]);
    wpre16[h * 32 + 16 + g]  = 0;
    wpost16[h * 32 + g]      = f2h(wpost[h * 16 + g]);
    wpost16[h * 32 + 16 + g] = 0;
  }
  for (int c = t; c < 2048; c += 1024){
    int d2 = c & 31, ii = (c >> 5) & 3, g = c >> 7;
    ((unsigned int*)qls)[c] =
      *(const unsigned int*)(qn + ((size_t)(b * 16 + g) * N_ + i0 + ii) * 64 + d2 * 2);
  }
  __syncthreads();

  // ---- phase A: raw dots, software-pipelined (2-task depth over flattened (jt,g)) ----
  {
    const int nw16 = (nJtA > w) ? ((nJtA - w + 15) >> 4) : 0;
    const int ntask = nw16 * 16;
    if (ntask > 0){
      const int tmax = ntask - 1;
      const unsigned short* kl = ktF + (size_t)(b * 16) * KTF_BG + (size_t)l * 8;
      auto kp = [&](int task)->const unsigned short*{
        int tt = task > tmax ? tmax : task;
        int g = tt & 15, jti = tt >> 4;
        return kl + (size_t)g * KTF_BG + (((size_t)(w + jti * 16)) << 10);
      };
      const unsigned short* p0 = kp(0);
      const unsigned short* p1 = kp(1);
      half8 kA0 = *(const half8*)p0, kA1 = *(const half8*)(p0 + 512);
      half8 kB0 = *(const half8*)p1, kB1 = *(const half8*)(p1 + 512);
      for (int task = 0; task < ntask; task += 2){
        half8 cA0 = kA0, cA1 = kA1, cB0 = kB0, cB1 = kB1;
        const unsigned short* pa = kp(task + 2);
        const unsigned short* pb = kp(task + 3);
        kA0 = *(const half8*)pa; kA1 = *(const half8*)(pa + 512);
        kB0 = *(const half8*)pb; kB1 = *(const half8*)(pb + 512);
        #pragma unroll
        for (int s = 0; s < 2; ++s){
          const int tt = task + s;
          const int g = tt & 15, jt = w + ((tt >> 4) << 4);
          const unsigned short* qp = &qls[(g * 4 + (l15 & 3)) * 64 + l4 * 8];
          half8 qf0 = *(const half8*)(qp);
          half8 qf1 = *(const half8*)(qp + 32);
          f32x4 acc = (f32x4){0.f, 0.f, 0.f, 0.f};
          acc = __builtin_amdgcn_mfma_f32_16x16x32_f16(s ? cB0 : cA0, qf0, acc, 0, 0, 0);
          acc = __builtin_amdgcn_mfma_f32_16x16x32_f16(s ? cB1 : cA1, qf1, acc, 0, 0, 0);
          if (l15 < IT_){
            unsigned int pk0 = (unsigned int)f2h(acc[0]) | ((unsigned int)f2h(acc[1]) << 16);
            unsigned int pk1 = (unsigned int)f2h(acc[2]) | ((unsigned int)f2h(acc[3]) << 16);
            unsigned int* dst = (unsigned int*)&sd[(g * IT_ + l15) * JSTT + jt * 16 + l4 * 4];
            dst[0] = pk0; dst[1] = pk1;
          }
        }
      }
    }
  }
  __syncthreads();

  // ---- phase B: W_pre premix via MFMA, in-place per (ii, jt16) patch ----
  {
    half8 wa = *(const half8*)&wpre16[l15 * 32 + l4 * 8];
    const int ntask = IT_ * nJtA;
    for (int task = w; task < ntask; task += 16){
      const int ii = task & (IT_ - 1), jt = task >> 2;
      unsigned int fb[4] = {0u, 0u, 0u, 0u};
      if (l4 < 2){
        const unsigned short* src = &sd[((l4 * 8) * IT_ + ii) * JSTT + jt * 16 + l15];
        #pragma unroll
        for (int e = 0; e < 8; e += 2){
          unsigned int lo = src[(size_t)(e)     * IT_ * JSTT];
          unsigned int hi = src[(size_t)(e + 1) * IT_ * JSTT];
          fb[e >> 1] = (lo & 0xFFFFu) | (hi << 16);
        }
      }
      f32x4 acc = (f32x4){0.f, 0.f, 0.f, 0.f};
      acc = __builtin_amdgcn_mfma_f32_16x16x32_f16(wa, __builtin_bit_cast(half8, *(u32x4*)fb), acc, 0, 0, 0);
      #pragma unroll
      for (int r = 0; r < 4; ++r)
        sd[((l4 * 4 + r) * IT_ + ii) * JSTT + jt * 16 + l15] = f2h(acc[r]);
    }
  }
  __syncthreads();

  // ---- phase C: per-row top-64 threshold + softmax, causal-trimmed to jc ----
  for (int rr = 0; rr < 4; ++rr){
    const int row = w * 4 + rr;            // 0..63
    const int g = row >> 2, ii = row & 3;
    const int nA = i0 + ii + 5;
    unsigned short* rowp = &sd[(g * IT_ + ii) * JSTT];
    unsigned int kw[NG];
    #pragma unroll
    for (int grp = 0; grp < NG; ++grp){
      kw[grp] = 0u;
      if (grp * 128 < jc){
        int j = grp * 128 + l * 2;
        unsigned int u = (j < JSTT) ? *(const unsigned int*)(rowp + j) : 0u;
        unsigned int klo = h2key(u & 0xFFFFu);
        unsigned int khi = h2key(u >> 16);
        if (j     >= nA) klo = 0u;
        if (j + 1 >= nA) khi = 0u;
        kw[grp] = klo | (khi << 16);
      }
    }
    unsigned int kmx = 0u;
    #pragma unroll
    for (int grp = 0; grp < NG; ++grp){
      if (grp * 128 < jc){
        unsigned int m2 = max(kw[grp] >> 16, kw[grp] & 0xFFFFu);
        kmx = max(kmx, m2);
      }
    }
    #pragma unroll
    for (int off = 32; off; off >>= 1) kmx = max(kmx, (unsigned int)__shfl_xor((int)kmx, off));
    const float mx = key2f(kmx);

    unsigned int T = 0u;
    if (nA > TOPK_){
      for (int bit = 15; bit >= 2; --bit){
        unsigned int Tc = T | (1u << bit);
        int c = 0;
        #pragma unroll
        for (int grp = 0; grp < NG; ++grp){
          if (grp * 128 < jc){
            c += __popcll(__ballot((kw[grp] & 0xFFFFu) >= Tc));
            c += __popcll(__ballot((kw[grp] >> 16) >= Tc));
          }
        }
        if (c >= TOPK_){
          T = Tc;
          if (c == TOPK_) break;
        }
      }
    }
    if (T == 0u) T = 1u;

    float s = 0.f;
    float ev[2 * NG];
    #pragma unroll
    for (int grp = 0; grp < NG; ++grp){
      if (grp * 128 < jc){
        unsigned int klo = kw[grp] & 0xFFFFu, khi = kw[grp] >> 16;
        float elo = (klo >= T) ? __expf(key2f(klo) - mx) : 0.f;
        float ehi = (khi >= T) ? __expf(key2f(khi) - mx) : 0.f;
        ev[grp * 2] = elo; ev[grp * 2 + 1] = ehi;
        s += elo + ehi;
      }
    }
    #pragma unroll
    for (int off = 32; off; off >>= 1) s += __shfl_xor(s, off);
    float inv = 1.f / s;
    #pragma unroll
    for (int grp = 0; grp < NG; ++grp){
      if (grp * 128 < jc){
        int j = grp * 128 + l * 2;
        if (j < JSTT)
          *(unsigned int*)(rowp + j) =
            (unsigned int)f2h(ev[grp * 2] * inv) | ((unsigned int)f2h(ev[grp * 2 + 1] * inv) << 16);
      }
    }
  }
  __syncthreads();

  // ---- phase D: postmix via MFMA (causal-trimmed) ----
  {
    const int ntask = IT_ * nJtD;
    for (int task = w; task < ntask; task += 16){
      const int ii = task & (IT_ - 1), jt = task >> 2;
      half8 wa = *(const half8*)&wpost16[l15 * 32 + l4 * 8];
      unsigned int fb[4] = {0u, 0u, 0u, 0u};
      if (l4 < 2){
        const unsigned short* src = &sd[((l4 * 8) * IT_ + ii) * JSTT + jt * 16 + l15];
        #pragma unroll
        for (int e = 0; e < 8; e += 2){
          unsigned int lo = src[(size_t)(e)     * IT_ * JSTT];
          unsigned int hi = src[(size_t)(e + 1) * IT_ * JSTT];
          fb[e >> 1] = (lo & 0xFFFFu) | (hi << 16);
        }
      }
      f32x4 acc = (f32x4){0.f, 0.f, 0.f, 0.f};
      acc = __builtin_amdgcn_mfma_f32_16x16x32_f16(wa, __builtin_bit_cast(half8, *(u32x4*)fb), acc, 0, 0, 0);
      #pragma unroll
      for (int r = 0; r < 4; ++r)
        sd[((l4 * 4 + r) * IT_ + ii) * JSTT + jt * 16 + l15] = f2h(acc[r]);
    }
  }
  __syncthreads();

  // ---- phase E: PV via MFMA, software-pipelined V prefetch (2-deep) ----
  for (int task = w; task < 64; task += 16){
    const int h = task >> 2, dc = task & 3;
    const int bg = b * 16 + h;
    const unsigned short* vbase = vtF + (size_t)bg * KTF_BG + (size_t)dc * VTF_DC + (size_t)l * 8;
    const unsigned short* arow = &sd[(h * IT_ + (l15 & 3)) * JSTT + l4 * 8];
    const int jm = nJtE - 1;
    auto vp_ = [&](int jt)->const half8*{
      int tt = jt > jm ? jm : jt;
      return (const half8*)(vbase + ((size_t)tt << 9));
    };
    half8 vA = *vp_(0), vB = *vp_(1);
    f32x4 acc = (f32x4){0.f, 0.f, 0.f, 0.f};
    int jt = 0;
    for (; jt + 2 <= nJtE; jt += 2){
      half8 cA = vA, cB = vB;
      vA = *vp_(jt + 2); vB = *vp_(jt + 3);
      half8 af0 = *(const half8*)(arow + jt * 32);
      half8 af1 = *(const half8*)(arow + jt * 32 + 32);
      acc = __builtin_amdgcn_mfma_f32_16x16x32_f16(af0, cA, acc, 0, 0, 0);
      acc = __builtin_amdgcn_mfma_f32_16x16x32_f16(af1, cB, acc, 0, 0, 0);
    }
    if (jt < nJtE){
      half8 af0 = *(const half8*)(arow + jt * 32);
      acc = __builtin_amdgcn_mfma_f32_16x16x32_f16(af0, vA, acc, 0, 0, 0);
    }
    if (l4 == 0){
      const float hs = hsc[h];
      #pragma unroll
      for (int r = 0; r < IT_; ++r){
        const int irow = (b << 10) | (i0 + r);
        const size_t o = (size_t)irow * 1024 + h * 64 + dc * 16 + l15;
        aout[o] = f2b(acc[r] * hs * h2f(gate[o]));
      }
    }
  }
}

// ---------------- host ----------------
extern "C" void kernel_launch(void* const* d_in, const int* in_sizes, int n_in,
                              void* d_out, int out_size, void* d_ws, size_t ws_size,
                              hipStream_t stream) {
  const float* x     = (const float*)d_in[0];
  const float* Wq    = (const float*)d_in[1];
  const float* Wk    = (const float*)d_in[2];
  const float* Wv    = (const float*)d_in[3];
  const float* Wpre  = (const float*)d_in[4];
  const float* Wpost = (const float*)d_in[5];
  const float* mk    = (const float*)d_in[6];
  const float* mv    = (const float*)d_in[7];
  const float* hsc   = (const float*)d_in[8];
  const float* Wg    = (const float*)d_in[9];
  const float* bg    = (const float*)d_in[10];
  const float* Wo    = (const float*)d_in[11];
  float* out = (float*)d_out;

  char* ws = (char*)d_ws;
  size_t off = 0;
  auto alloc = [&](size_t bytes) -> void* {
    void* p = ws + off; off += (bytes + 255) & ~(size_t)255; return p;
  };
  unsigned short* xb    = (unsigned short*)alloc((size_t)4096 * 1024 * 2);
  unsigned short* wcatT = (unsigned short*)alloc((size_t)4096 * 1024 * 2);   // [n][k] bf16
  unsigned short* wobT  = (unsigned short*)alloc((size_t)1024 * 1024 * 2);   // [n][k] bf16
  unsigned short* qn    = (unsigned short*)alloc((size_t)B_ * H_ * N_ * DH_ * 2);  // f16
  unsigned short* ktF   = (unsigned short*)alloc((size_t)B_ * H_ * KTF_BG * 2);    // frag-ordered K
  unsigned short* vtF   = (unsigned short*)alloc((size_t)B_ * H_ * KTF_BG * 2);    // frag-ordered V^T
  unsigned short* gate  = (unsigned short*)alloc((size_t)4096 * 1024 * 2);         // f16
  unsigned short* aout  = (unsigned short*)alloc((size_t)4096 * 1024 * 2);         // bf16

  k_cvtAll<<<3072, 256, 0, stream>>>(x, Wq, Wk, Wv, Wg, Wo, xb, wcatT, wobT,
                                     mk, mv, ktF, vtF);

  // bg offset trick: gate epilogue indexes bgv[3*1024 + col]; pass bg - 3*1024 so it reads bg[col]
  k_gemmF<<<dim3(64, 32), 256, 0, stream>>>(xb, wcatT, qn, ktF, vtF, gate, bg - 3 * 1024);

  // big tier first (it 128..255, 1 blk/CU), then small tier (it 0..127, 2 blk/CU)
  k_attnM<33><<<512, 1024, 0, stream>>>(qn, ktF, vtF, Wpre, Wpost, hsc, gate, aout, 255);
  k_attnM<17><<<512, 1024, 0, stream>>>(qn, ktF, vtF, Wpre, Wpost, hsc, gate, aout, 127);

  k_gemmO<<<dim3(16, 32), 256, 0, stream>>>(aout, wobT, out);
}

// Round 16
// 312.002 us; speedup vs baseline: 2.2141x; 1.0210x over previous
//
#include <hip/hip_runtime.h>
#include <hip/hip_bf16.h>
#include <float.h>

#define B_ 4
#define N_ 1024
#define H_ 16
#define DH_ 64
#define NM_ 4
#define J_ 1028          // N_ + NM_
#define IT_ 4            // i rows per attention block
#define TOPK_ 64
#define QKSCALE 10.0f
// fragment-ordered K: ktF[bg][jt(66)][f(2)][l(64)][e(8)]  halves; per-bg = 66*1024 = 67584
// fragment-ordered V^T: vtF[bg][dc(4)][jtE(33)][l(64)][e(8)]; per-bg = 4*33*512 = 67584
#define KTF_BG 67584
#define VTF_DC 16896     // 33*512

typedef __attribute__((ext_vector_type(8))) short short8;
typedef __attribute__((ext_vector_type(4))) float f32x4;
typedef __attribute__((ext_vector_type(8))) unsigned short ushort8;
typedef __attribute__((ext_vector_type(4))) unsigned int u32x4;
typedef __attribute__((ext_vector_type(2))) unsigned int u32x2;
typedef _Float16 half8 __attribute__((ext_vector_type(8)));

__device__ __forceinline__ unsigned short f2b(float f){
  union { float f; unsigned int i; } c; c.f = f;
  unsigned int r = c.i + 0x7FFFu + ((c.i >> 16) & 1u);   // RNE
  return (unsigned short)(r >> 16);
}
__device__ __forceinline__ unsigned short f2h(float f){
  return __builtin_bit_cast(unsigned short, (_Float16)f);
}
__device__ __forceinline__ float h2f(unsigned short u){
  return (float)__builtin_bit_cast(_Float16, u);
}
__device__ __forceinline__ unsigned int h2key(unsigned int u){
  return (u & 0x8000u) ? (~u & 0xFFFFu) : (u | 0x8000u);
}
__device__ __forceinline__ float key2f(unsigned int k){
  unsigned int u = (k & 0x8000u) ? (k & 0x7FFFu) : (~k & 0xFFFFu);
  return h2f((unsigned short)u);
}

// ---- fused prep: weight TRANSPOSE+convert (bf16 [n][k]), x convert, memory-slot seed ----
__global__ __launch_bounds__(256) void k_cvtAll(
    const float* __restrict__ x,  const float* __restrict__ wq,
    const float* __restrict__ wk, const float* __restrict__ wv,
    const float* __restrict__ wg, const float* __restrict__ wo,
    unsigned short* __restrict__ xb, unsigned short* __restrict__ wcatT,
    unsigned short* __restrict__ wobT,
    const float* __restrict__ mk, const float* __restrict__ mv,
    unsigned short* __restrict__ ktF, unsigned short* __restrict__ vtF){
  const int t = threadIdx.x;
  const unsigned bid = blockIdx.x;
  if (bid < 1280){
    // ---- weight transpose: 64x64 tile, src [k][n] f32 -> dst [n][k] bf16 ----
    __shared__ unsigned short tile[64][70];
    const int which = bid >> 8;          // 0..4 (q,k,v,g,o)
    const int tl = bid & 255;
    const int tr = tl >> 4, tc = tl & 15;   // k-tile, n-tile
    const float* src = which == 0 ? wq : which == 1 ? wk : which == 2 ? wv : which == 3 ? wg : wo;
    {
      int r = t >> 2, c0 = (t & 3) * 16;
      const float* sp = src + (size_t)(tr * 64 + r) * 1024 + tc * 64 + c0;
      #pragma unroll
      for (int e = 0; e < 16; ++e) tile[r][c0 + e] = f2b(sp[e]);
    }
    __syncthreads();
    {
      int rn = t >> 2, k0 = (t & 3) * 16;
      int n = tc * 64 + rn;
      unsigned short* dp = (which == 4)
        ? wobT + (size_t)n * 1024 + tr * 64 + k0
        : wcatT + ((size_t)which * 1024 + n) * 1024 + tr * 64 + k0;
      ushort8 v0, v1;
      #pragma unroll
      for (int e = 0; e < 8; ++e) v0[e] = tile[k0 + e][rn];
      #pragma unroll
      for (int e = 0; e < 8; ++e) v1[e] = tile[k0 + 8 + e][rn];
      *(ushort8*)dp = v0;
      *(ushort8*)(dp + 8) = v1;
    }
    return;
  }
  if (bid >= 1280 && bid < 1284){
    // ---- memory-slot prep: normalize mem_k, seed slots, zero pad tiles ----
    int h = (bid - 1280) * 4 + (t >> 6);   // 0..15
    int d = t & 63;
    unsigned short kh[4], vh[4];
    #pragma unroll
    for (int mm = 0; mm < 4; ++mm){
      float kv = mk[(h * 4 + mm) * 64 + d];
      float ss = kv * kv;
      #pragma unroll
      for (int off = 32; off; off >>= 1) ss += __shfl_xor(ss, off);
      kh[mm] = f2h(kv / fmaxf(sqrtf(ss), 1e-12f));
      vh[mm] = f2h(mv[(h * 4 + mm) * 64 + d]);
    }
    for (int b = 0; b < B_; ++b){
      int bg = b * 16 + h;
      #pragma unroll
      for (int mm = 0; mm < 4; ++mm)
        ktF[(size_t)bg * KTF_BG + (size_t)(d >> 5) * 512 + (mm + ((d >> 3) & 3) * 16) * 8 + (d & 7)] = kh[mm];
      #pragma unroll
      for (int mm = 0; mm < 4; ++mm)
        vtF[(size_t)bg * KTF_BG + (size_t)(d >> 4) * VTF_DC + (d & 15) * 8 + mm] = vh[mm];
      {
        unsigned int* kz = (unsigned int*)(ktF + (size_t)bg * KTF_BG + 64 * 1024);
        for (int c = d; c < 1024; c += 64) kz[c] = 0u;
      }
      #pragma unroll
      for (int dc = 0; dc < 4; ++dc){
        unsigned int* vz = (unsigned int*)(vtF + (size_t)bg * KTF_BG + (size_t)dc * VTF_DC + 32 * 512);
        for (int c = d; c < 256; c += 64) vz[c] = 0u;
      }
    }
    return;
  }
  // ---- x convert ----
  int i = (bid - 1284) * 256 + t;
  const int st = (3072 - 1284) * 256;
  for (; i < 4096 * 1024; i += st) xb[i] = f2b(x[i]);
}

// ---------------- fused QKVG GEMM: 4096x4096x1024 (wcatT [n][k]), 128x64 tile, BK=64 ----------------
__global__ __launch_bounds__(256) void k_gemmF(const unsigned short* __restrict__ A,
                                               const unsigned short* __restrict__ WcT,
                                               unsigned short* __restrict__ qn,
                                               unsigned short* __restrict__ ktF,
                                               unsigned short* __restrict__ vtF,
                                               unsigned short* __restrict__ gate,
                                               const float* __restrict__ bgv)
{
  __shared__ unsigned short As[128][72];
  __shared__ unsigned short Bs[64][72];
  const int t = threadIdx.x;
  const int m0 = blockIdx.y * 128, n0 = blockIdx.x * 64;
  const int l = t & 63, w = t >> 6;
  const int l15 = l & 15, l4 = l >> 4;

  f32x4 acc[2][4];
  #pragma unroll
  for (int a = 0; a < 2; ++a)
    #pragma unroll
    for (int b2 = 0; b2 < 4; ++b2) acc[a][b2] = (f32x4){0.f, 0.f, 0.f, 0.f};

  for (int k0 = 0; k0 < 1024; k0 += 64){
    #pragma unroll
    for (int cc = 0; cc < 4; ++cc){          // A tile: 128x64
      int c = t + cc * 256;
      int row = c >> 3, colc = (c & 7) * 8;
      *(ushort8*)&As[row][colc] = *(const ushort8*)&A[(m0 + row) * 1024 + k0 + colc];
    }
    #pragma unroll
    for (int cc = 0; cc < 2; ++cc){          // B tile: 64n x 64k, direct row copy
      int c = t + cc * 256;
      int row = c >> 3, colc = (c & 7) * 8;
      *(ushort8*)&Bs[row][colc] = *(const ushort8*)&WcT[(size_t)(n0 + row) * 1024 + k0 + colc];
    }
    __syncthreads();
    #pragma unroll
    for (int ks = 0; ks < 64; ks += 32){
      short8 af[2], bfr[4];
      #pragma unroll
      for (int mf = 0; mf < 2; ++mf) af[mf]  = *(const short8*)&As[w * 32 + mf * 16 + l15][ks + l4 * 8];
      #pragma unroll
      for (int nf = 0; nf < 4; ++nf) bfr[nf] = *(const short8*)&Bs[nf * 16 + l15][ks + l4 * 8];
      #pragma unroll
      for (int mf = 0; mf < 2; ++mf)
        #pragma unroll
        for (int nf = 0; nf < 4; ++nf)
          acc[mf][nf] = __builtin_amdgcn_mfma_f32_16x16x32_bf16(af[mf], bfr[nf], acc[mf][nf], 0, 0, 0);
    }
    __syncthreads();
  }

  const int which = n0 >> 10;        // 0=q 1=k 2=v 3=gate (uniform per block)
  const int ncol0 = n0 & 1023;
  const int hcol = ncol0 >> 6;
  #pragma unroll
  for (int mf = 0; mf < 2; ++mf){
    if (which == 2){
      int row0 = m0 + w * 32 + mf * 16 + l4 * 4;
      int bb = row0 >> 10;
      int j0 = (row0 & 1023) + NM_;
      int jtE = j0 >> 5, lj = (j0 & 31) >> 3, e0 = j0 & 7;
      #pragma unroll
      for (int nf = 0; nf < 4; ++nf){
        int col = ncol0 + nf * 16 + l15;
        int h = col >> 6, d = col & 63;
        unsigned int lo = (unsigned int)f2h(acc[mf][nf][0]) | ((unsigned int)f2h(acc[mf][nf][1]) << 16);
        unsigned int hi = (unsigned int)f2h(acc[mf][nf][2]) | ((unsigned int)f2h(acc[mf][nf][3]) << 16);
        unsigned short* dst = vtF + (size_t)(bb * 16 + h) * KTF_BG +
                              (size_t)(d >> 4) * VTF_DC + (size_t)jtE * 512 +
                              ((d & 15) + lj * 16) * 8 + e0;
        *(u32x2*)dst = (u32x2){lo, hi};
      }
    } else {
      #pragma unroll
      for (int r = 0; r < 4; ++r){
        int row = m0 + w * 32 + mf * 16 + l4 * 4 + r;
        float rn = 1.f;
        if (which <= 1){
          float ss = 0.f;
          #pragma unroll
          for (int nf = 0; nf < 4; ++nf) ss += acc[mf][nf][r] * acc[mf][nf][r];
          #pragma unroll
          for (int off = 1; off < 16; off <<= 1) ss += __shfl_xor(ss, off);
          rn = 1.f / fmaxf(sqrtf(ss), 1e-12f);
          if (which == 0) rn *= QKSCALE;
        }
        #pragma unroll
        for (int nf = 0; nf < 4; ++nf){
          int col = ncol0 + nf * 16 + l15;
          float v = acc[mf][nf][r];
          int bb = row >> 10, ii = row & 1023;
          if (which == 3){
            float g = v + bgv[3 * 1024 + col];
            gate[(size_t)row * 1024 + col] = f2h(1.f / (1.f + __expf(-g)));
          } else if (which == 0){
            int d = col & 63;
            qn[((size_t)(bb * H_ + hcol) * N_ + ii) * DH_ + d] = f2h(v * rn);
          } else { // which == 1: K -> ktF fragment order
            int j = ii + NM_;
            int d = col & 63;
            ktF[(size_t)(bb * 16 + hcol) * KTF_BG + (size_t)(j >> 4) * 1024 +
                (size_t)(d >> 5) * 512 + ((j & 15) + ((d >> 3) & 3) * 16) * 8 + (d & 7)]
              = f2h(v * rn);
          }
        }
      }
    }
  }
}

// ---------------- final GEMM aout x WoT -> f32 out, 128x64 tile, BK=64 ----------------
__global__ __launch_bounds__(256) void k_gemmO(const unsigned short* __restrict__ A,
                                               const unsigned short* __restrict__ WT,
                                               float* __restrict__ outp)
{
  __shared__ unsigned short As[128][72];
  __shared__ unsigned short Bs[64][72];
  const int t = threadIdx.x;
  const int m0 = blockIdx.y * 128, n0 = blockIdx.x * 64;
  const int l = t & 63, w = t >> 6;
  const int l15 = l & 15, l4 = l >> 4;

  f32x4 acc[2][4];
  #pragma unroll
  for (int a = 0; a < 2; ++a)
    #pragma unroll
    for (int b2 = 0; b2 < 4; ++b2) acc[a][b2] = (f32x4){0.f, 0.f, 0.f, 0.f};

  for (int k0 = 0; k0 < 1024; k0 += 64){
    #pragma unroll
    for (int cc = 0; cc < 4; ++cc){
      int c = t + cc * 256;
      int row = c >> 3, colc = (c & 7) * 8;
      *(ushort8*)&As[row][colc] = *(const ushort8*)&A[(m0 + row) * 1024 + k0 + colc];
    }
    #pragma unroll
    for (int cc = 0; cc < 2; ++cc){
      int c = t + cc * 256;
      int row = c >> 3, colc = (c & 7) * 8;
      *(ushort8*)&Bs[row][colc] = *(const ushort8*)&WT[(size_t)(n0 + row) * 1024 + k0 + colc];
    }
    __syncthreads();
    #pragma unroll
    for (int ks = 0; ks < 64; ks += 32){
      short8 af[2], bfr[4];
      #pragma unroll
      for (int mf = 0; mf < 2; ++mf) af[mf]  = *(const short8*)&As[w * 32 + mf * 16 + l15][ks + l4 * 8];
      #pragma unroll
      for (int nf = 0; nf < 4; ++nf) bfr[nf] = *(const short8*)&Bs[nf * 16 + l15][ks + l4 * 8];
      #pragma unroll
      for (int mf = 0; mf < 2; ++mf)
        #pragma unroll
        for (int nf = 0; nf < 4; ++nf)
          acc[mf][nf] = __builtin_amdgcn_mfma_f32_16x16x32_bf16(af[mf], bfr[nf], acc[mf][nf], 0, 0, 0);
    }
    __syncthreads();
  }

  #pragma unroll
  for (int mf = 0; mf < 2; ++mf)
    #pragma unroll
    for (int r = 0; r < 4; ++r){
      int row = m0 + w * 32 + mf * 16 + l4 * 4 + r;
      #pragma unroll
      for (int nf = 0; nf < 4; ++nf)
        outp[(size_t)row * 1024 + n0 + nf * 16 + l15] = acc[mf][nf][r];
    }
}

// ---------------- fused attention, all-MFMA, pipelined A/E, LDS-tiered ----------------
// NJTE_MAX 33: it 128..255 (~146KB LDS, 1 blk/CU, MINW=4 -> 128 VGPR cap, A+B fused)
// NJTE_MAX 17: it 0..127   (~81KB, 2 blk/CU, MINW=8 -> 64 VGPR cap, separate B)
template<int NJTE_MAX, int MINW, bool FUSE_AB>
__global__ __launch_bounds__(1024, MINW) void k_attnM(
  const unsigned short* __restrict__ qn, const unsigned short* __restrict__ ktF,
  const unsigned short* __restrict__ vtF, const float* __restrict__ wpre,
  const float* __restrict__ wpost, const float* __restrict__ hsc,
  const unsigned short* __restrict__ gate, unsigned short* __restrict__ aout,
  int itBase)
{
  constexpr int JSTT = NJTE_MAX * 32 + 8;      // sd row stride (halves)
  constexpr int NG = (JSTT + 127) / 128;       // phase-C 128-col groups
  __shared__ unsigned short sd[16 * IT_ * JSTT];
  __shared__ unsigned short qls[16 * 4 * 64];
  __shared__ unsigned short wpre16[16 * 32];
  __shared__ unsigned short wpost16[16 * 32];

  const int blk = blockIdx.x;
  const int b = (blk >> 1) & 3;                  // fixed per XCD pair (blk%8 -> XCD)
  const int idx = ((blk >> 3) << 1) | (blk & 1); // 0..127 within tier
  const int it = itBase - idx;                   // big tiles first within tier
  const int i0 = it * IT_;
  const int nAmax = i0 + IT_ + 4;
  const int nJtA = (nAmax + 15) >> 4;
  const int nJtE = (nAmax + 31) >> 5;
  const int nJtD = nJtE * 2;
  const int jc = nJtE * 32;            // processing bound for phase C
  const int t = threadIdx.x;
  const int w = t >> 6, l = t & 63;
  const int l15 = l & 15, l4 = l >> 4;

  if (t < 256){
    int h = t >> 4, g = t & 15;
    wpre16[h * 32 + g]       = f2h(wpre[h * 16 + g]);
    wpre16[h * 32 + 16 + g]  = 0;
    wpost16[h * 32 + g]      = f2h(wpost[h * 16 + g]);
    wpost16[h * 32 + 16 + g] = 0;
  }
  for (int c = t; c < 2048; c += 1024){
    int d2 = c & 31, ii = (c >> 5) & 3, g = c >> 7;
    ((unsigned int*)qls)[c] =
      *(const unsigned int*)(qn + ((size_t)(b * 16 + g) * N_ + i0 + ii) * 64 + d2 * 2);
  }
  __syncthreads();

  // ---- phase A: raw dots, software-pipelined; FUSE_AB: premix per-jt in-wave ----
  {
    half8 wa = *(const half8*)&wpre16[l15 * 32 + l4 * 8];
    const int nw16 = (nJtA > w) ? ((nJtA - w + 15) >> 4) : 0;
    const int ntask = nw16 * 16;
    if (ntask > 0){
      const int tmax = ntask - 1;
      const unsigned short* kl = ktF + (size_t)(b * 16) * KTF_BG + (size_t)l * 8;
      auto kp = [&](int task)->const unsigned short*{
        int tt = task > tmax ? tmax : task;
        int g = tt & 15, jti = tt >> 4;
        return kl + (size_t)g * KTF_BG + (((size_t)(w + jti * 16)) << 10);
      };
      const unsigned short* p0 = kp(0);
      const unsigned short* p1 = kp(1);
      half8 kA0 = *(const half8*)p0, kA1 = *(const half8*)(p0 + 512);
      half8 kB0 = *(const half8*)p1, kB1 = *(const half8*)(p1 + 512);
      for (int task = 0; task < ntask; task += 2){
        half8 cA0 = kA0, cA1 = kA1, cB0 = kB0, cB1 = kB1;
        const unsigned short* pa = kp(task + 2);
        const unsigned short* pb = kp(task + 3);
        kA0 = *(const half8*)pa; kA1 = *(const half8*)(pa + 512);
        kB0 = *(const half8*)pb; kB1 = *(const half8*)(pb + 512);
        #pragma unroll
        for (int s = 0; s < 2; ++s){
          const int tt = task + s;
          const int g = tt & 15, jt = w + ((tt >> 4) << 4);
          const unsigned short* qp = &qls[(g * 4 + (l15 & 3)) * 64 + l4 * 8];
          half8 qf0 = *(const half8*)(qp);
          half8 qf1 = *(const half8*)(qp + 32);
          f32x4 acc = (f32x4){0.f, 0.f, 0.f, 0.f};
          acc = __builtin_amdgcn_mfma_f32_16x16x32_f16(s ? cB0 : cA0, qf0, acc, 0, 0, 0);
          acc = __builtin_amdgcn_mfma_f32_16x16x32_f16(s ? cB1 : cA1, qf1, acc, 0, 0, 0);
          if (l15 < IT_){
            unsigned int pk0 = (unsigned int)f2h(acc[0]) | ((unsigned int)f2h(acc[1]) << 16);
            unsigned int pk1 = (unsigned int)f2h(acc[2]) | ((unsigned int)f2h(acc[3]) << 16);
            unsigned int* dst = (unsigned int*)&sd[(g * IT_ + l15) * JSTT + jt * 16 + l4 * 4];
            dst[0] = pk0; dst[1] = pk1;
          }
        }
        if constexpr (FUSE_AB){
          if ((task & 15) == 14){
            // all 16 g of this jt written by THIS wave; premix in place, no barrier
            const int jt = w + ((task >> 4) << 4);
            asm volatile("s_waitcnt lgkmcnt(0)" ::: "memory");
            #pragma unroll
            for (int ii = 0; ii < IT_; ++ii){
              unsigned int fb[4] = {0u, 0u, 0u, 0u};
              if (l4 < 2){
                const unsigned short* src = &sd[((l4 * 8) * IT_ + ii) * JSTT + jt * 16 + l15];
                #pragma unroll
                for (int e = 0; e < 8; e += 2){
                  unsigned int lo = src[(size_t)(e)     * IT_ * JSTT];
                  unsigned int hi = src[(size_t)(e + 1) * IT_ * JSTT];
                  fb[e >> 1] = (lo & 0xFFFFu) | (hi << 16);
                }
              }
              f32x4 pacc = (f32x4){0.f, 0.f, 0.f, 0.f};
              pacc = __builtin_amdgcn_mfma_f32_16x16x32_f16(wa, __builtin_bit_cast(half8, *(u32x4*)fb), pacc, 0, 0, 0);
              asm volatile("s_waitcnt lgkmcnt(0)" ::: "memory");
              #pragma unroll
              for (int r = 0; r < 4; ++r)
                sd[((l4 * 4 + r) * IT_ + ii) * JSTT + jt * 16 + l15] = f2h(pacc[r]);
            }
          }
        }
      }
    }
    __syncthreads();
    if constexpr (!FUSE_AB){
      // ---- phase B: W_pre premix via MFMA, task loop ----
      const int ntaskB = IT_ * nJtA;
      for (int task = w; task < ntaskB; task += 16){
        const int ii = task & (IT_ - 1), jt = task >> 2;
        unsigned int fb[4] = {0u, 0u, 0u, 0u};
        if (l4 < 2){
          const unsigned short* src = &sd[((l4 * 8) * IT_ + ii) * JSTT + jt * 16 + l15];
          #pragma unroll
          for (int e = 0; e < 8; e += 2){
            unsigned int lo = src[(size_t)(e)     * IT_ * JSTT];
            unsigned int hi = src[(size_t)(e + 1) * IT_ * JSTT];
            fb[e >> 1] = (lo & 0xFFFFu) | (hi << 16);
          }
        }
        f32x4 acc = (f32x4){0.f, 0.f, 0.f, 0.f};
        acc = __builtin_amdgcn_mfma_f32_16x16x32_f16(wa, __builtin_bit_cast(half8, *(u32x4*)fb), acc, 0, 0, 0);
        #pragma unroll
        for (int r = 0; r < 4; ++r)
          sd[((l4 * 4 + r) * IT_ + ii) * JSTT + jt * 16 + l15] = f2h(acc[r]);
      }
      __syncthreads();
    }
  }

  // ---- phase C: per-row top-64 threshold + softmax, causal-trimmed to jc ----
  for (int rr = 0; rr < 4; ++rr){
    const int row = w * 4 + rr;            // 0..63
    const int g = row >> 2, ii = row & 3;
    const int nA = i0 + ii + 5;
    unsigned short* rowp = &sd[(g * IT_ + ii) * JSTT];
    unsigned int kw[NG];
    #pragma unroll
    for (int grp = 0; grp < NG; ++grp){
      kw[grp] = 0u;
      if (grp * 128 < jc){
        int j = grp * 128 + l * 2;
        unsigned int u = (j < JSTT) ? *(const unsigned int*)(rowp + j) : 0u;
        unsigned int klo = h2key(u & 0xFFFFu);
        unsigned int khi = h2key(u >> 16);
        if (j     >= nA) klo = 0u;
        if (j + 1 >= nA) khi = 0u;
        kw[grp] = klo | (khi << 16);
      }
    }
    unsigned int kmx = 0u;
    #pragma unroll
    for (int grp = 0; grp < NG; ++grp){
      if (grp * 128 < jc){
        unsigned int m2 = max(kw[grp] >> 16, kw[grp] & 0xFFFFu);
        kmx = max(kmx, m2);
      }
    }
    #pragma unroll
    for (int off = 32; off; off >>= 1) kmx = max(kmx, (unsigned int)__shfl_xor((int)kmx, off));
    const float mx = key2f(kmx);

    unsigned int T = 0u;
    if (nA > TOPK_){
      for (int bit = 15; bit >= 2; --bit){
        unsigned int Tc = T | (1u << bit);
        int c = 0;
        #pragma unroll
        for (int grp = 0; grp < NG; ++grp){
          if (grp * 128 < jc){
            c += __popcll(__ballot((kw[grp] & 0xFFFFu) >= Tc));
            c += __popcll(__ballot((kw[grp] >> 16) >= Tc));
          }
        }
        if (c >= TOPK_){
          T = Tc;
          if (c == TOPK_) break;
        }
      }
    }
    if (T == 0u) T = 1u;

    float s = 0.f;
    float ev[2 * NG];
    #pragma unroll
    for (int grp = 0; grp < NG; ++grp){
      if (grp * 128 < jc){
        unsigned int klo = kw[grp] & 0xFFFFu, khi = kw[grp] >> 16;
        float elo = (klo >= T) ? __expf(key2f(klo) - mx) : 0.f;
        float ehi = (khi >= T) ? __expf(key2f(khi) - mx) : 0.f;
        ev[grp * 2] = elo; ev[grp * 2 + 1] = ehi;
        s += elo + ehi;
      }
    }
    #pragma unroll
    for (int off = 32; off; off >>= 1) s += __shfl_xor(s, off);
    float inv = 1.f / s;
    #pragma unroll
    for (int grp = 0; grp < NG; ++grp){
      if (grp * 128 < jc){
        int j = grp * 128 + l * 2;
        if (j < JSTT)
          *(unsigned int*)(rowp + j) =
            (unsigned int)f2h(ev[grp * 2] * inv) | ((unsigned int)f2h(ev[grp * 2 + 1] * inv) << 16);
      }
    }
  }
  __syncthreads();

  // ---- phase D: postmix via MFMA (causal-trimmed) ----
  {
    const int ntask = IT_ * nJtD;
    for (int task = w; task < ntask; task += 16){
      const int ii = task & (IT_ - 1), jt = task >> 2;
      half8 wa = *(const half8*)&wpost16[l15 * 32 + l4 * 8];
      unsigned int fb[4] = {0u, 0u, 0u, 0u};
      if (l4 < 2){
        const unsigned short* src = &sd[((l4 * 8) * IT_ + ii) * JSTT + jt * 16 + l15];
        #pragma unroll
        for (int e = 0; e < 8; e += 2){
          unsigned int lo = src[(size_t)(e)     * IT_ * JSTT];
          unsigned int hi = src[(size_t)(e + 1) * IT_ * JSTT];
          fb[e >> 1] = (lo & 0xFFFFu) | (hi << 16);
        }
      }
      f32x4 acc = (f32x4){0.f, 0.f, 0.f, 0.f};
      acc = __builtin_amdgcn_mfma_f32_16x16x32_f16(wa, __builtin_bit_cast(half8, *(u32x4*)fb), acc, 0, 0, 0);
      #pragma unroll
      for (int r = 0; r < 4; ++r)
        sd[((l4 * 4 + r) * IT_ + ii) * JSTT + jt * 16 + l15] = f2h(acc[r]);
    }
  }
  __syncthreads();

  // ---- phase E: PV via MFMA, software-pipelined V prefetch (2-deep) ----
  for (int task = w; task < 64; task += 16){
    const int h = task >> 2, dc = task & 3;
    const int bg = b * 16 + h;
    const unsigned short* vbase = vtF + (size_t)bg * KTF_BG + (size_t)dc * VTF_DC + (size_t)l * 8;
    const unsigned short* arow = &sd[(h * IT_ + (l15 & 3)) * JSTT + l4 * 8];
    const int jm = nJtE - 1;
    auto vp_ = [&](int jt)->const half8*{
      int tt = jt > jm ? jm : jt;
      return (const half8*)(vbase + ((size_t)tt << 9));
    };
    half8 vA = *vp_(0), vB = *vp_(1);
    f32x4 acc = (f32x4){0.f, 0.f, 0.f, 0.f};
    int jt = 0;
    for (; jt + 2 <= nJtE; jt += 2){
      half8 cA = vA, cB = vB;
      vA = *vp_(jt + 2); vB = *vp_(jt + 3);
      half8 af0 = *(const half8*)(arow + jt * 32);
      half8 af1 = *(const half8*)(arow + jt * 32 + 32);
      acc = __builtin_amdgcn_mfma_f32_16x16x32_f16(af0, cA, acc, 0, 0, 0);
      acc = __builtin_amdgcn_mfma_f32_16x16x32_f16(af1, cB, acc, 0, 0, 0);
    }
    if (jt < nJtE){
      half8 af0 = *(const half8*)(arow + jt * 32);
      acc = __builtin_amdgcn_mfma_f32_16x16x32_f16(af0, vA, acc, 0, 0, 0);
    }
    if (l4 == 0){
      const float hs = hsc[h];
      #pragma unroll
      for (int r = 0; r < IT_; ++r){
        const int irow = (b << 10) | (i0 + r);
        const size_t o = (size_t)irow * 1024 + h * 64 + dc * 16 + l15;
        aout[o] = f2b(acc[r] * hs * h2f(gate[o]));
      }
    }
  }
}

// ---------------- host ----------------
extern "C" void kernel_launch(void* const* d_in, const int* in_sizes, int n_in,
                              void* d_out, int out_size, void* d_ws, size_t ws_size,
                              hipStream_t stream) {
  const float* x     = (const float*)d_in[0];
  const float* Wq    = (const float*)d_in[1];
  const float* Wk    = (const float*)d_in[2];
  const float* Wv    = (const float*)d_in[3];
  const float* Wpre  = (const float*)d_in[4];
  const float* Wpost = (const float*)d_in[5];
  const float* mk    = (const float*)d_in[6];
  const float* mv    = (const float*)d_in[7];
  const float* hsc   = (const float*)d_in[8];
  const float* Wg    = (const float*)d_in[9];
  const float* bg    = (const float*)d_in[10];
  const float* Wo    = (const float*)d_in[11];
  float* out = (float*)d_out;

  char* ws = (char*)d_ws;
  size_t off = 0;
  auto alloc = [&](size_t bytes) -> void* {
    void* p = ws + off; off += (bytes + 255) & ~(size_t)255; return p;
  };
  unsigned short* xb    = (unsigned short*)alloc((size_t)4096 * 1024 * 2);
  unsigned short* wcatT = (unsigned short*)alloc((size_t)4096 * 1024 * 2);   // [n][k] bf16
  unsigned short* wobT  = (unsigned short*)alloc((size_t)1024 * 1024 * 2);   // [n][k] bf16
  unsigned short* qn    = (unsigned short*)alloc((size_t)B_ * H_ * N_ * DH_ * 2);  // f16
  unsigned short* ktF   = (unsigned short*)alloc((size_t)B_ * H_ * KTF_BG * 2);    // frag-ordered K
  unsigned short* vtF   = (unsigned short*)alloc((size_t)B_ * H_ * KTF_BG * 2);    // frag-ordered V^T
  unsigned short* gate  = (unsigned short*)alloc((size_t)4096 * 1024 * 2);         // f16
  unsigned short* aout  = (unsigned short*)alloc((size_t)4096 * 1024 * 2);         // bf16

  k_cvtAll<<<3072, 256, 0, stream>>>(x, Wq, Wk, Wv, Wg, Wo, xb, wcatT, wobT,
                                     mk, mv, ktF, vtF);

  // bg offset trick: gate epilogue indexes bgv[3*1024 + col]; pass bg - 3*1024 so it reads bg[col]
  k_gemmF<<<dim3(64, 32), 256, 0, stream>>>(xb, wcatT, qn, ktF, vtF, gate, bg - 3 * 1024);

  // big tier first (it 128..255, 1 blk/CU, A+B fused), then small tier (it 0..127, 2 blk/CU)
  k_attnM<33, 4, true><<<512, 1024, 0, stream>>>(qn, ktF, vtF, Wpre, Wpost, hsc, gate, aout, 255);
  k_attnM<17, 8, false><<<512, 1024, 0, stream>>>(qn, ktF, vtF, Wpre, Wpost, hsc, gate, aout, 127);

  k_gemmO<<<dim3(16, 32), 256, 0, stream>>>(aout, wobT, out);
}

// Round 17
// 306.685 us; speedup vs baseline: 2.2525x; 1.0173x over previous
//
#include <hip/hip_runtime.h>
#include <hip/hip_bf16.h>
#include <float.h>

#define B_ 4
#define N_ 1024
#define H_ 16
#define DH_ 64
#define NM_ 4
#define J_ 1028          // N_ + NM_
#define IT_ 4            // i rows per attention block
#define TOPK_ 64
#define QKSCALE 10.0f
// fragment-ordered K: ktF[bg][jt(66)][f(2)][l(64)][e(8)]  halves; per-bg = 66*1024 = 67584
// fragment-ordered V^T: vtF[bg][dc(4)][jtE(33)][l(64)][e(8)]; per-bg = 4*33*512 = 67584
#define KTF_BG 67584
#define VTF_DC 16896     // 33*512

typedef __attribute__((ext_vector_type(8))) short short8;
typedef __attribute__((ext_vector_type(4))) float f32x4;
typedef __attribute__((ext_vector_type(8))) unsigned short ushort8;
typedef __attribute__((ext_vector_type(4))) unsigned int u32x4;
typedef __attribute__((ext_vector_type(2))) unsigned int u32x2;
typedef _Float16 half8 __attribute__((ext_vector_type(8)));

__device__ __forceinline__ unsigned short f2b(float f){
  union { float f; unsigned int i; } c; c.f = f;
  unsigned int r = c.i + 0x7FFFu + ((c.i >> 16) & 1u);   // RNE
  return (unsigned short)(r >> 16);
}
__device__ __forceinline__ unsigned short f2h(float f){
  return __builtin_bit_cast(unsigned short, (_Float16)f);
}
__device__ __forceinline__ float h2f(unsigned short u){
  return (float)__builtin_bit_cast(_Float16, u);
}
__device__ __forceinline__ unsigned int h2key(unsigned int u){
  return (u & 0x8000u) ? (~u & 0xFFFFu) : (u | 0x8000u);
}
__device__ __forceinline__ float key2f(unsigned int k){
  unsigned int u = (k & 0x8000u) ? (k & 0x7FFFu) : (~k & 0xFFFFu);
  return h2f((unsigned short)u);
}

// ---- fused prep: weight TRANSPOSE+convert (bf16 [n][k]), x convert, memory-slot seed ----
__global__ __launch_bounds__(256) void k_cvtAll(
    const float* __restrict__ x,  const float* __restrict__ wq,
    const float* __restrict__ wk, const float* __restrict__ wv,
    const float* __restrict__ wg, const float* __restrict__ wo,
    unsigned short* __restrict__ xb, unsigned short* __restrict__ wcatT,
    unsigned short* __restrict__ wobT,
    const float* __restrict__ mk, const float* __restrict__ mv,
    unsigned short* __restrict__ ktF, unsigned short* __restrict__ vtF){
  const int t = threadIdx.x;
  const unsigned bid = blockIdx.x;
  if (bid < 1280){
    // ---- weight transpose: 64x64 tile, src [k][n] f32 -> dst [n][k] bf16 ----
    __shared__ unsigned short tile[64][70];
    const int which = bid >> 8;          // 0..4 (q,k,v,g,o)
    const int tl = bid & 255;
    const int tr = tl >> 4, tc = tl & 15;   // k-tile, n-tile
    const float* src = which == 0 ? wq : which == 1 ? wk : which == 2 ? wv : which == 3 ? wg : wo;
    {
      int r = t >> 2, c0 = (t & 3) * 16;
      const float* sp = src + (size_t)(tr * 64 + r) * 1024 + tc * 64 + c0;
      #pragma unroll
      for (int e = 0; e < 16; ++e) tile[r][c0 + e] = f2b(sp[e]);
    }
    __syncthreads();
    {
      int rn = t >> 2, k0 = (t & 3) * 16;
      int n = tc * 64 + rn;
      unsigned short* dp = (which == 4)
        ? wobT + (size_t)n * 1024 + tr * 64 + k0
        : wcatT + ((size_t)which * 1024 + n) * 1024 + tr * 64 + k0;
      ushort8 v0, v1;
      #pragma unroll
      for (int e = 0; e < 8; ++e) v0[e] = tile[k0 + e][rn];
      #pragma unroll
      for (int e = 0; e < 8; ++e) v1[e] = tile[k0 + 8 + e][rn];
      *(ushort8*)dp = v0;
      *(ushort8*)(dp + 8) = v1;
    }
    return;
  }
  if (bid >= 1280 && bid < 1284){
    // ---- memory-slot prep: normalize mem_k, seed slots, zero pad tiles ----
    int h = (bid - 1280) * 4 + (t >> 6);   // 0..15
    int d = t & 63;
    unsigned short kh[4], vh[4];
    #pragma unroll
    for (int mm = 0; mm < 4; ++mm){
      float kv = mk[(h * 4 + mm) * 64 + d];
      float ss = kv * kv;
      #pragma unroll
      for (int off = 32; off; off >>= 1) ss += __shfl_xor(ss, off);
      kh[mm] = f2h(kv / fmaxf(sqrtf(ss), 1e-12f));
      vh[mm] = f2h(mv[(h * 4 + mm) * 64 + d]);
    }
    for (int b = 0; b < B_; ++b){
      int bg = b * 16 + h;
      #pragma unroll
      for (int mm = 0; mm < 4; ++mm)
        ktF[(size_t)bg * KTF_BG + (size_t)(d >> 5) * 512 + (mm + ((d >> 3) & 3) * 16) * 8 + (d & 7)] = kh[mm];
      #pragma unroll
      for (int mm = 0; mm < 4; ++mm)
        vtF[(size_t)bg * KTF_BG + (size_t)(d >> 4) * VTF_DC + (d & 15) * 8 + mm] = vh[mm];
      {
        unsigned int* kz = (unsigned int*)(ktF + (size_t)bg * KTF_BG + 64 * 1024);
        for (int c = d; c < 1024; c += 64) kz[c] = 0u;
      }
      #pragma unroll
      for (int dc = 0; dc < 4; ++dc){
        unsigned int* vz = (unsigned int*)(vtF + (size_t)bg * KTF_BG + (size_t)dc * VTF_DC + 32 * 512);
        for (int c = d; c < 256; c += 64) vz[c] = 0u;
      }
    }
    return;
  }
  // ---- x convert ----
  int i = (bid - 1284) * 256 + t;
  const int st = (3072 - 1284) * 256;
  for (; i < 4096 * 1024; i += st) xb[i] = f2b(x[i]);
}

// ---------------- fused QKVG GEMM: 4096x4096x1024 (wcatT [n][k]), 128x128 tile, BK=64 ----------------
__global__ __launch_bounds__(256) void k_gemmF(const unsigned short* __restrict__ A,
                                               const unsigned short* __restrict__ WcT,
                                               unsigned short* __restrict__ qn,
                                               unsigned short* __restrict__ ktF,
                                               unsigned short* __restrict__ vtF,
                                               unsigned short* __restrict__ gate,
                                               const float* __restrict__ bgv)
{
  __shared__ unsigned short As[128][72];
  __shared__ unsigned short Bs[128][72];
  const int t = threadIdx.x;
  const int m0 = blockIdx.y * 128, n0 = blockIdx.x * 128;
  const int l = t & 63, w = t >> 6, wr = w >> 1, wc = w & 1;
  const int l15 = l & 15, l4 = l >> 4;

  f32x4 acc[4][4];
  #pragma unroll
  for (int a = 0; a < 4; ++a)
    #pragma unroll
    for (int b2 = 0; b2 < 4; ++b2) acc[a][b2] = (f32x4){0.f, 0.f, 0.f, 0.f};

  for (int k0 = 0; k0 < 1024; k0 += 64){
    #pragma unroll
    for (int cc = 0; cc < 4; ++cc){          // A tile: 128x64
      int c = t + cc * 256;
      int row = c >> 3, colc = (c & 7) * 8;
      *(ushort8*)&As[row][colc] = *(const ushort8*)&A[(m0 + row) * 1024 + k0 + colc];
    }
    #pragma unroll
    for (int cc = 0; cc < 4; ++cc){          // B tile: 128n x 64k, direct row copy
      int c = t + cc * 256;
      int row = c >> 3, colc = (c & 7) * 8;
      *(ushort8*)&Bs[row][colc] = *(const ushort8*)&WcT[(size_t)(n0 + row) * 1024 + k0 + colc];
    }
    __syncthreads();
    #pragma unroll
    for (int ks = 0; ks < 64; ks += 32){
      short8 af[4], bfr[4];
      #pragma unroll
      for (int mf = 0; mf < 4; ++mf) af[mf]  = *(const short8*)&As[wr * 64 + mf * 16 + l15][ks + l4 * 8];
      #pragma unroll
      for (int nf = 0; nf < 4; ++nf) bfr[nf] = *(const short8*)&Bs[wc * 64 + nf * 16 + l15][ks + l4 * 8];
      #pragma unroll
      for (int mf = 0; mf < 4; ++mf)
        #pragma unroll
        for (int nf = 0; nf < 4; ++nf)
          acc[mf][nf] = __builtin_amdgcn_mfma_f32_16x16x32_bf16(af[mf], bfr[nf], acc[mf][nf], 0, 0, 0);
    }
    __syncthreads();
  }

  const int which = n0 >> 10;        // 0=q 1=k 2=v 3=gate (uniform per block; 128-tile never straddles)
  const int ncol0 = (n0 & 1023) + wc * 64;
  const int hcol = ncol0 >> 6;
  #pragma unroll
  for (int mf = 0; mf < 4; ++mf){
    if (which == 2){
      int row0 = m0 + wr * 64 + mf * 16 + l4 * 4;
      int bb = row0 >> 10;
      int j0 = (row0 & 1023) + NM_;
      int jtE = j0 >> 5, lj = (j0 & 31) >> 3, e0 = j0 & 7;
      #pragma unroll
      for (int nf = 0; nf < 4; ++nf){
        int col = ncol0 + nf * 16 + l15;
        int h = col >> 6, d = col & 63;
        unsigned int lo = (unsigned int)f2h(acc[mf][nf][0]) | ((unsigned int)f2h(acc[mf][nf][1]) << 16);
        unsigned int hi = (unsigned int)f2h(acc[mf][nf][2]) | ((unsigned int)f2h(acc[mf][nf][3]) << 16);
        unsigned short* dst = vtF + (size_t)(bb * 16 + h) * KTF_BG +
                              (size_t)(d >> 4) * VTF_DC + (size_t)jtE * 512 +
                              ((d & 15) + lj * 16) * 8 + e0;
        *(u32x2*)dst = (u32x2){lo, hi};
      }
    } else {
      #pragma unroll
      for (int r = 0; r < 4; ++r){
        int row = m0 + wr * 64 + mf * 16 + l4 * 4 + r;
        float rn = 1.f;
        if (which <= 1){
          float ss = 0.f;
          #pragma unroll
          for (int nf = 0; nf < 4; ++nf) ss += acc[mf][nf][r] * acc[mf][nf][r];
          #pragma unroll
          for (int off = 1; off < 16; off <<= 1) ss += __shfl_xor(ss, off);
          rn = 1.f / fmaxf(sqrtf(ss), 1e-12f);
          if (which == 0) rn *= QKSCALE;
        }
        #pragma unroll
        for (int nf = 0; nf < 4; ++nf){
          int col = ncol0 + nf * 16 + l15;
          float v = acc[mf][nf][r];
          int bb = row >> 10, ii = row & 1023;
          if (which == 3){
            float g = v + bgv[3 * 1024 + col];
            gate[(size_t)row * 1024 + col] = f2h(1.f / (1.f + __expf(-g)));
          } else if (which == 0){
            int d = col & 63;
            qn[((size_t)(bb * H_ + hcol) * N_ + ii) * DH_ + d] = f2h(v * rn);
          } else { // which == 1: K -> ktF fragment order
            int j = ii + NM_;
            int d = col & 63;
            ktF[(size_t)(bb * 16 + hcol) * KTF_BG + (size_t)(j >> 4) * 1024 +
                (size_t)(d >> 5) * 512 + ((j & 15) + ((d >> 3) & 3) * 16) * 8 + (d & 7)]
              = f2h(v * rn);
          }
        }
      }
    }
  }
}

// ---------------- final GEMM aout x WoT -> f32 out, 128x128 tile, BK=64 ----------------
__global__ __launch_bounds__(256) void k_gemmO(const unsigned short* __restrict__ A,
                                               const unsigned short* __restrict__ WT,
                                               float* __restrict__ outp)
{
  __shared__ unsigned short As[128][72];
  __shared__ unsigned short Bs[128][72];
  const int t = threadIdx.x;
  const int m0 = blockIdx.y * 128, n0 = blockIdx.x * 128;
  const int l = t & 63, w = t >> 6, wr = w >> 1, wc = w & 1;
  const int l15 = l & 15, l4 = l >> 4;

  f32x4 acc[4][4];
  #pragma unroll
  for (int a = 0; a < 4; ++a)
    #pragma unroll
    for (int b2 = 0; b2 < 4; ++b2) acc[a][b2] = (f32x4){0.f, 0.f, 0.f, 0.f};

  for (int k0 = 0; k0 < 1024; k0 += 64){
    #pragma unroll
    for (int cc = 0; cc < 4; ++cc){
      int c = t + cc * 256;
      int row = c >> 3, colc = (c & 7) * 8;
      *(ushort8*)&As[row][colc] = *(const ushort8*)&A[(m0 + row) * 1024 + k0 + colc];
    }
    #pragma unroll
    for (int cc = 0; cc < 4; ++cc){
      int c = t + cc * 256;
      int row = c >> 3, colc = (c & 7) * 8;
      *(ushort8*)&Bs[row][colc] = *(const ushort8*)&WT[(size_t)(n0 + row) * 1024 + k0 + colc];
    }
    __syncthreads();
    #pragma unroll
    for (int ks = 0; ks < 64; ks += 32){
      short8 af[4], bfr[4];
      #pragma unroll
      for (int mf = 0; mf < 4; ++mf) af[mf]  = *(const short8*)&As[wr * 64 + mf * 16 + l15][ks + l4 * 8];
      #pragma unroll
      for (int nf = 0; nf < 4; ++nf) bfr[nf] = *(const short8*)&Bs[wc * 64 + nf * 16 + l15][ks + l4 * 8];
      #pragma unroll
      for (int mf = 0; mf < 4; ++mf)
        #pragma unroll
        for (int nf = 0; nf < 4; ++nf)
          acc[mf][nf] = __builtin_amdgcn_mfma_f32_16x16x32_bf16(af[mf], bfr[nf], acc[mf][nf], 0, 0, 0);
    }
    __syncthreads();
  }

  #pragma unroll
  for (int mf = 0; mf < 4; ++mf)
    #pragma unroll
    for (int r = 0; r < 4; ++r){
      int row = m0 + wr * 64 + mf * 16 + l4 * 4 + r;
      #pragma unroll
      for (int nf = 0; nf < 4; ++nf)
        outp[(size_t)row * 1024 + n0 + wc * 64 + nf * 16 + l15] = acc[mf][nf][r];
    }
}

// ---------------- fused attention, all-MFMA, pipelined A/E, LDS-tiered ----------------
// NJTE_MAX 33: it 128..255 (~146KB LDS, 1 blk/CU, MINW=4 -> 128 VGPR cap, A+B fused)
// NJTE_MAX 17: it 0..127   (~81KB, 2 blk/CU, MINW=8 -> 64 VGPR cap, separate B)
template<int NJTE_MAX, int MINW, bool FUSE_AB>
__global__ __launch_bounds__(1024, MINW) void k_attnM(
  const unsigned short* __restrict__ qn, const unsigned short* __restrict__ ktF,
  const unsigned short* __restrict__ vtF, const float* __restrict__ wpre,
  const float* __restrict__ wpost, const float* __restrict__ hsc,
  const unsigned short* __restrict__ gate, unsigned short* __restrict__ aout,
  int itBase)
{
  constexpr int JSTT = NJTE_MAX * 32 + 8;      // sd row stride (halves)
  constexpr int NG = (JSTT + 127) / 128;       // phase-C 128-col groups
  __shared__ unsigned short sd[16 * IT_ * JSTT];
  __shared__ unsigned short qls[16 * 4 * 64];
  __shared__ unsigned short wpre16[16 * 32];
  __shared__ unsigned short wpost16[16 * 32];

  const int blk = blockIdx.x;
  const int b = (blk >> 1) & 3;                  // fixed per XCD pair (blk%8 -> XCD)
  const int idx = ((blk >> 3) << 1) | (blk & 1); // 0..127 within tier
  const int it = itBase - idx;                   // big tiles first within tier
  const int i0 = it * IT_;
  const int nAmax = i0 + IT_ + 4;
  const int nJtA = (nAmax + 15) >> 4;
  const int nJtE = (nAmax + 31) >> 5;
  const int nJtD = nJtE * 2;
  const int jc = nJtE * 32;            // processing bound for phase C
  const int t = threadIdx.x;
  const int w = t >> 6, l = t & 63;
  const int l15 = l & 15, l4 = l >> 4;

  if (t < 256){
    int h = t >> 4, g = t & 15;
    wpre16[h * 32 + g]       = f2h(wpre[h * 16 + g]);
    wpre16[h * 32 + 16 + g]  = 0;
    wpost16[h * 32 + g]      = f2h(wpost[h * 16 + g]);
    wpost16[h * 32 + 16 + g] = 0;
  }
  for (int c = t; c < 2048; c += 1024){
    int d2 = c & 31, ii = (c >> 5) & 3, g = c >> 7;
    ((unsigned int*)qls)[c] =
      *(const unsigned int*)(qn + ((size_t)(b * 16 + g) * N_ + i0 + ii) * 64 + d2 * 2);
  }
  __syncthreads();

  // ---- phase A: raw dots, software-pipelined; FUSE_AB: premix per-jt in-wave ----
  {
    half8 wa = *(const half8*)&wpre16[l15 * 32 + l4 * 8];
    const int nw16 = (nJtA > w) ? ((nJtA - w + 15) >> 4) : 0;
    const int ntask = nw16 * 16;
    if (ntask > 0){
      const int tmax = ntask - 1;
      const unsigned short* kl = ktF + (size_t)(b * 16) * KTF_BG + (size_t)l * 8;
      auto kp = [&](int task)->const unsigned short*{
        int tt = task > tmax ? tmax : task;
        int g = tt & 15, jti = tt >> 4;
        return kl + (size_t)g * KTF_BG + (((size_t)(w + jti * 16)) << 10);
      };
      const unsigned short* p0 = kp(0);
      const unsigned short* p1 = kp(1);
      half8 kA0 = *(const half8*)p0, kA1 = *(const half8*)(p0 + 512);
      half8 kB0 = *(const half8*)p1, kB1 = *(const half8*)(p1 + 512);
      for (int task = 0; task < ntask; task += 2){
        half8 cA0 = kA0, cA1 = kA1, cB0 = kB0, cB1 = kB1;
        const unsigned short* pa = kp(task + 2);
        const unsigned short* pb = kp(task + 3);
        kA0 = *(const half8*)pa; kA1 = *(const half8*)(pa + 512);
        kB0 = *(const half8*)pb; kB1 = *(const half8*)(pb + 512);
        __builtin_amdgcn_s_setprio(1);
        #pragma unroll
        for (int s = 0; s < 2; ++s){
          const int tt = task + s;
          const int g = tt & 15, jt = w + ((tt >> 4) << 4);
          const unsigned short* qp = &qls[(g * 4 + (l15 & 3)) * 64 + l4 * 8];
          half8 qf0 = *(const half8*)(qp);
          half8 qf1 = *(const half8*)(qp + 32);
          f32x4 acc = (f32x4){0.f, 0.f, 0.f, 0.f};
          acc = __builtin_amdgcn_mfma_f32_16x16x32_f16(s ? cB0 : cA0, qf0, acc, 0, 0, 0);
          acc = __builtin_amdgcn_mfma_f32_16x16x32_f16(s ? cB1 : cA1, qf1, acc, 0, 0, 0);
          if (l15 < IT_){
            unsigned int pk0 = (unsigned int)f2h(acc[0]) | ((unsigned int)f2h(acc[1]) << 16);
            unsigned int pk1 = (unsigned int)f2h(acc[2]) | ((unsigned int)f2h(acc[3]) << 16);
            unsigned int* dst = (unsigned int*)&sd[(g * IT_ + l15) * JSTT + jt * 16 + l4 * 4];
            dst[0] = pk0; dst[1] = pk1;
          }
        }
        __builtin_amdgcn_s_setprio(0);
        if constexpr (FUSE_AB){
          if ((task & 15) == 14){
            // all 16 g of this jt written by THIS wave; premix in place, no barrier
            const int jt = w + ((task >> 4) << 4);
            asm volatile("s_waitcnt lgkmcnt(0)" ::: "memory");
            #pragma unroll
            for (int ii = 0; ii < IT_; ++ii){
              unsigned int fb[4] = {0u, 0u, 0u, 0u};
              if (l4 < 2){
                const unsigned short* src = &sd[((l4 * 8) * IT_ + ii) * JSTT + jt * 16 + l15];
                #pragma unroll
                for (int e = 0; e < 8; e += 2){
                  unsigned int lo = src[(size_t)(e)     * IT_ * JSTT];
                  unsigned int hi = src[(size_t)(e + 1) * IT_ * JSTT];
                  fb[e >> 1] = (lo & 0xFFFFu) | (hi << 16);
                }
              }
              f32x4 pacc = (f32x4){0.f, 0.f, 0.f, 0.f};
              pacc = __builtin_amdgcn_mfma_f32_16x16x32_f16(wa, __builtin_bit_cast(half8, *(u32x4*)fb), pacc, 0, 0, 0);
              asm volatile("s_waitcnt lgkmcnt(0)" ::: "memory");
              #pragma unroll
              for (int r = 0; r < 4; ++r)
                sd[((l4 * 4 + r) * IT_ + ii) * JSTT + jt * 16 + l15] = f2h(pacc[r]);
            }
          }
        }
      }
    }
    __syncthreads();
    if constexpr (!FUSE_AB){
      // ---- phase B: W_pre premix via MFMA, task loop ----
      const int ntaskB = IT_ * nJtA;
      for (int task = w; task < ntaskB; task += 16){
        const int ii = task & (IT_ - 1), jt = task >> 2;
        unsigned int fb[4] = {0u, 0u, 0u, 0u};
        if (l4 < 2){
          const unsigned short* src = &sd[((l4 * 8) * IT_ + ii) * JSTT + jt * 16 + l15];
          #pragma unroll
          for (int e = 0; e < 8; e += 2){
            unsigned int lo = src[(size_t)(e)     * IT_ * JSTT];
            unsigned int hi = src[(size_t)(e + 1) * IT_ * JSTT];
            fb[e >> 1] = (lo & 0xFFFFu) | (hi << 16);
          }
        }
        f32x4 acc = (f32x4){0.f, 0.f, 0.f, 0.f};
        acc = __builtin_amdgcn_mfma_f32_16x16x32_f16(wa, __builtin_bit_cast(half8, *(u32x4*)fb), acc, 0, 0, 0);
        #pragma unroll
        for (int r = 0; r < 4; ++r)
          sd[((l4 * 4 + r) * IT_ + ii) * JSTT + jt * 16 + l15] = f2h(acc[r]);
      }
      __syncthreads();
    }
  }

  // ---- phase C: per-row top-64 threshold + softmax, causal-trimmed to jc ----
  for (int rr = 0; rr < 4; ++rr){
    const int row = w * 4 + rr;            // 0..63
    const int g = row >> 2, ii = row & 3;
    const int nA = i0 + ii + 5;
    unsigned short* rowp = &sd[(g * IT_ + ii) * JSTT];
    unsigned int kw[NG];
    #pragma unroll
    for (int grp = 0; grp < NG; ++grp){
      kw[grp] = 0u;
      if (grp * 128 < jc){
        int j = grp * 128 + l * 2;
        unsigned int u = (j < JSTT) ? *(const unsigned int*)(rowp + j) : 0u;
        unsigned int klo = h2key(u & 0xFFFFu);
        unsigned int khi = h2key(u >> 16);
        if (j     >= nA) klo = 0u;
        if (j + 1 >= nA) khi = 0u;
        kw[grp] = klo | (khi << 16);
      }
    }
    unsigned int kmx = 0u;
    #pragma unroll
    for (int grp = 0; grp < NG; ++grp){
      if (grp * 128 < jc){
        unsigned int m2 = max(kw[grp] >> 16, kw[grp] & 0xFFFFu);
        kmx = max(kmx, m2);
      }
    }
    #pragma unroll
    for (int off = 32; off; off >>= 1) kmx = max(kmx, (unsigned int)__shfl_xor((int)kmx, off));
    const float mx = key2f(kmx);

    unsigned int T = 0u;
    if (nA > TOPK_){
      for (int bit = 15; bit >= 2; --bit){
        unsigned int Tc = T | (1u << bit);
        int c = 0;
        #pragma unroll
        for (int grp = 0; grp < NG; ++grp){
          if (grp * 128 < jc){
            c += __popcll(__ballot((kw[grp] & 0xFFFFu) >= Tc));
            c += __popcll(__ballot((kw[grp] >> 16) >= Tc));
          }
        }
        if (c >= TOPK_){
          T = Tc;
          if (c == TOPK_) break;
        }
      }
    }
    if (T == 0u) T = 1u;

    float s = 0.f;
    float ev[2 * NG];
    #pragma unroll
    for (int grp = 0; grp < NG; ++grp){
      if (grp * 128 < jc){
        unsigned int klo = kw[grp] & 0xFFFFu, khi = kw[grp] >> 16;
        float elo = (klo >= T) ? __expf(key2f(klo) - mx) : 0.f;
        float ehi = (khi >= T) ? __expf(key2f(khi) - mx) : 0.f;
        ev[grp * 2] = elo; ev[grp * 2 + 1] = ehi;
        s += elo + ehi;
      }
    }
    #pragma unroll
    for (int off = 32; off; off >>= 1) s += __shfl_xor(s, off);
    float inv = 1.f / s;
    #pragma unroll
    for (int grp = 0; grp < NG; ++grp){
      if (grp * 128 < jc){
        int j = grp * 128 + l * 2;
        if (j < JSTT)
          *(unsigned int*)(rowp + j) =
            (unsigned int)f2h(ev[grp * 2] * inv) | ((unsigned int)f2h(ev[grp * 2 + 1] * inv) << 16);
      }
    }
  }
  __syncthreads();

  // ---- phase D: postmix via MFMA (causal-trimmed) ----
  {
    const int ntask = IT_ * nJtD;
    for (int task = w; task < ntask; task += 16){
      const int ii = task & (IT_ - 1), jt = task >> 2;
      half8 wa = *(const half8*)&wpost16[l15 * 32 + l4 * 8];
      unsigned int fb[4] = {0u, 0u, 0u, 0u};
      if (l4 < 2){
        const unsigned short* src = &sd[((l4 * 8) * IT_ + ii) * JSTT + jt * 16 + l15];
        #pragma unroll
        for (int e = 0; e < 8; e += 2){
          unsigned int lo = src[(size_t)(e)     * IT_ * JSTT];
          unsigned int hi = src[(size_t)(e + 1) * IT_ * JSTT];
          fb[e >> 1] = (lo & 0xFFFFu) | (hi << 16);
        }
      }
      f32x4 acc = (f32x4){0.f, 0.f, 0.f, 0.f};
      acc = __builtin_amdgcn_mfma_f32_16x16x32_f16(wa, __builtin_bit_cast(half8, *(u32x4*)fb), acc, 0, 0, 0);
      #pragma unroll
      for (int r = 0; r < 4; ++r)
        sd[((l4 * 4 + r) * IT_ + ii) * JSTT + jt * 16 + l15] = f2h(acc[r]);
    }
  }
  __syncthreads();

  // ---- phase E: PV via MFMA, software-pipelined V prefetch (2-deep) ----
  for (int task = w; task < 64; task += 16){
    const int h = task >> 2, dc = task & 3;
    const int bg = b * 16 + h;
    const unsigned short* vbase = vtF + (size_t)bg * KTF_BG + (size_t)dc * VTF_DC + (size_t)l * 8;
    const unsigned short* arow = &sd[(h * IT_ + (l15 & 3)) * JSTT + l4 * 8];
    const int jm = nJtE - 1;
    auto vp_ = [&](int jt)->const half8*{
      int tt = jt > jm ? jm : jt;
      return (const half8*)(vbase + ((size_t)tt << 9));
    };
    half8 vA = *vp_(0), vB = *vp_(1);
    f32x4 acc = (f32x4){0.f, 0.f, 0.f, 0.f};
    int jt = 0;
    for (; jt + 2 <= nJtE; jt += 2){
      half8 cA = vA, cB = vB;
      vA = *vp_(jt + 2); vB = *vp_(jt + 3);
      half8 af0 = *(const half8*)(arow + jt * 32);
      half8 af1 = *(const half8*)(arow + jt * 32 + 32);
      __builtin_amdgcn_s_setprio(1);
      acc = __builtin_amdgcn_mfma_f32_16x16x32_f16(af0, cA, acc, 0, 0, 0);
      acc = __builtin_amdgcn_mfma_f32_16x16x32_f16(af1, cB, acc, 0, 0, 0);
      __builtin_amdgcn_s_setprio(0);
    }
    if (jt < nJtE){
      half8 af0 = *(const half8*)(arow + jt * 32);
      acc = __builtin_amdgcn_mfma_f32_16x16x32_f16(af0, vA, acc, 0, 0, 0);
    }
    if (l4 == 0){
      const float hs = hsc[h];
      #pragma unroll
      for (int r = 0; r < IT_; ++r){
        const int irow = (b << 10) | (i0 + r);
        const size_t o = (size_t)irow * 1024 + h * 64 + dc * 16 + l15;
        aout[o] = f2b(acc[r] * hs * h2f(gate[o]));
      }
    }
  }
}

// ---------------- host ----------------
extern "C" void kernel_launch(void* const* d_in, const int* in_sizes, int n_in,
                              void* d_out, int out_size, void* d_ws, size_t ws_size,
                              hipStream_t stream) {
  const float* x     = (const float*)d_in[0];
  const float* Wq    = (const float*)d_in[1];
  const float* Wk    = (const float*)d_in[2];
  const float* Wv    = (const float*)d_in[3];
  const float* Wpre  = (const float*)d_in[4];
  const float* Wpost = (const float*)d_in[5];
  const float* mk    = (const float*)d_in[6];
  const float* mv    = (const float*)d_in[7];
  const float* hsc   = (const float*)d_in[8];
  const float* Wg    = (const float*)d_in[9];
  const float* bg    = (const float*)d_in[10];
  const float* Wo    = (const float*)d_in[11];
  float* out = (float*)d_out;

  char* ws = (char*)d_ws;
  size_t off = 0;
  auto alloc = [&](size_t bytes) -> void* {
    void* p = ws + off; off += (bytes + 255) & ~(size_t)255; return p;
  };
  unsigned short* xb    = (unsigned short*)alloc((size_t)4096 * 1024 * 2);
  unsigned short* wcatT = (unsigned short*)alloc((size_t)4096 * 1024 * 2);   // [n][k] bf16
  unsigned short* wobT  = (unsigned short*)alloc((size_t)1024 * 1024 * 2);   // [n][k] bf16
  unsigned short* qn    = (unsigned short*)alloc((size_t)B_ * H_ * N_ * DH_ * 2);  // f16
  unsigned short* ktF   = (unsigned short*)alloc((size_t)B_ * H_ * KTF_BG * 2);    // frag-ordered K
  unsigned short* vtF   = (unsigned short*)alloc((size_t)B_ * H_ * KTF_BG * 2);    // frag-ordered V^T
  unsigned short* gate  = (unsigned short*)alloc((size_t)4096 * 1024 * 2);         // f16
  unsigned short* aout  = (unsigned short*)alloc((size_t)4096 * 1024 * 2);         // bf16

  k_cvtAll<<<3072, 256, 0, stream>>>(x, Wq, Wk, Wv, Wg, Wo, xb, wcatT, wobT,
                                     mk, mv, ktF, vtF);

  // bg offset trick: gate epilogue indexes bgv[3*1024 + col]; pass bg - 3*1024 so it reads bg[col]
  k_gemmF<<<dim3(32, 32), 256, 0, stream>>>(xb, wcatT, qn, ktF, vtF, gate, bg - 3 * 1024);

  // big tier first (it 128..255, 1 blk/CU, A+B fused), then small tier (it 0..127, 2 blk/CU)
  k_attnM<33, 4, true><<<512, 1024, 0, stream>>>(qn, ktF, vtF, Wpre, Wpost, hsc, gate, aout, 255);
  k_attnM<17, 8, false><<<512, 1024, 0, stream>>>(qn, ktF, vtF, Wpre, Wpost, hsc, gate, aout, 127);

  k_gemmO<<<dim3(8, 32), 256, 0, stream>>>(aout, wobT, out);
}